// Round 7
// baseline (1001.596 us; speedup 1.0000x reference)
//
#include <hip/hip_runtime.h>
#include <hip/hip_fp16.h>

#define NSENS 4
#define NB    64
#define LIN   2048
#define C1N   32
#define LP1   512
#define C2N   64
#define SEQ   256
#define DM    64
#define H1S   516

__device__ __forceinline__ float fast_exp2(float x) {
#if __has_builtin(__builtin_amdgcn_exp2f)
  return __builtin_amdgcn_exp2f(x);
#else
  return exp2f(x);
#endif
}

// 8 fp16 values <-> 8 floats through one 16B LDS transaction
__device__ __forceinline__ void rchunk8(const char* p, float* o) {
  const uint4 w = *(const uint4*)p;
  float2 f;
  f = __half22float2(*(const __half2*)&w.x); o[0]=f.x; o[1]=f.y;
  f = __half22float2(*(const __half2*)&w.y); o[2]=f.x; o[3]=f.y;
  f = __half22float2(*(const __half2*)&w.z); o[4]=f.x; o[5]=f.y;
  f = __half22float2(*(const __half2*)&w.w); o[6]=f.x; o[7]=f.y;
}
__device__ __forceinline__ void wchunk8(char* p, const float* v) {
  __half2 h0 = __floats2half2_rn(v[0],v[1]);
  __half2 h1 = __floats2half2_rn(v[2],v[3]);
  __half2 h2 = __floats2half2_rn(v[4],v[5]);
  __half2 h3 = __floats2half2_rn(v[6],v[7]);
  uint4 w;
  w.x = *(const unsigned*)&h0; w.y = *(const unsigned*)&h1;
  w.z = *(const unsigned*)&h2; w.w = *(const unsigned*)&h3;
  *(uint4*)p = w;
}

// acc[0..7] += row . W[i][:], processed in 16-element quarters.
// Peak live: acc8 + rh16 + addressing ~ 28 VGPR.
#define GROUP8_ACC(acc, xbase, Wbase, ldw) { \
  _Pragma("unroll") \
  for (int _qt = 0; _qt < 4; ++_qt) { \
    float _rh[16]; \
    rchunk8((xbase) + (((_qt*2  )*16) ^ rs), _rh); \
    rchunk8((xbase) + (((_qt*2+1)*16) ^ rs), _rh+8); \
    _Pragma("unroll") \
    for (int _i = 0; _i < 8; ++_i) { \
      const float* _w = (Wbase) + _i*(ldw) + _qt*16; \
      float _a = (acc)[_i]; \
      _Pragma("unroll") \
      for (int _c = 0; _c < 16; ++_c) _a = fmaf(_rh[_c], _w[_c], _a); \
      (acc)[_i] = _a; \
    } \
  } \
}

// ------------------------- conv branch kernel (unchanged) -------------------------
__global__ __launch_bounds__(256) void conv_kernel(
    const float* __restrict__ sens,
    const float* __restrict__ c1w, const float* __restrict__ c1b,
    const float* __restrict__ bn1g, const float* __restrict__ bn1b,
    const float* __restrict__ c2w, const float* __restrict__ c2b,
    const float* __restrict__ bn2g, const float* __restrict__ bn2b,
    float* __restrict__ x0)
{
  const int bid = blockIdx.x;
  const int s = bid >> 6, b = bid & 63;
  const int tid = threadIdx.x;
  __shared__ __half h1p[C1N][H1S];
  __shared__ float w2s[C1N*3*C2N];

  for (int i = tid; i < C1N*3*C2N; i += 256) {
    int co = i & 63; int rem = i >> 6; int k = rem % 3; int ci = rem / 3;
    w2s[(ci*3 + k)*64 + co] = c2w[((s*C2N + co)*C1N + ci)*3 + k];
  }

  const float* xg = sens + (size_t)(s*NB + b)*LIN;
  const float bnr = rsqrtf(1.0f + 1e-5f);

  {
    const int c = tid & 31;
    const int l0 = tid >> 5;
    const float w0 = c1w[(s*C1N + c)*5 + 0];
    const float w1 = c1w[(s*C1N + c)*5 + 1];
    const float w2 = c1w[(s*C1N + c)*5 + 2];
    const float w3 = c1w[(s*C1N + c)*5 + 3];
    const float w4 = c1w[(s*C1N + c)*5 + 4];
    const float cb = c1b[s*C1N + c];
    const float sc = bn1g[s*C1N + c]*bnr;
    const float bt = bn1b[s*C1N + c];
    for (int l = l0; l < LP1; l += 8) {
      const int base = 4*l;
      float xm2 = (base-2 >= 0) ? xg[base-2] : 0.f;
      float xm1 = (base-1 >= 0) ? xg[base-1] : 0.f;
      float x0v = xg[base+0];
      float x1v = xg[base+1];
      float x2v = xg[base+2];
      float x3v = xg[base+3];
      float x4v = (base+4 < LIN) ? xg[base+4] : 0.f;
      float y0 = w0*xm2 + w1*xm1 + w2*x0v + w3*x1v + w4*x2v;
      float y1 = w0*x0v + w1*x1v + w2*x2v + w3*x3v + w4*x4v;
      y0 = (y0 + cb)*sc + bt;
      y1 = (y1 + cb)*sc + bt;
      h1p[c][l+1] = __float2half(fmaxf(fmaxf(y0, y1), 0.f));
      if (l == 0)      h1p[c][0]      = __float2half(0.f);
      if (l == LP1-1)  h1p[c][LP1+1]  = __float2half(0.f);
    }
  }
  __syncthreads();

  const int rg = tid & 31, cg = tid >> 5;
  const int c0 = cg*8;
  float cb2[8], sc2[8], bt2[8];
  #pragma unroll
  for (int cc = 0; cc < 8; ++cc) {
    cb2[cc] = c2b[s*C2N + c0 + cc];
    sc2[cc] = bn2g[s*C2N + c0 + cc]*bnr;
    bt2[cc] = bn2b[s*C2N + c0 + cc];
  }
  for (int it = 0; it < 4; ++it) {
    const int rA = 64*it + rg;
    const int rB = rA + 32;
    float acc[2][2][8] = {};
    for (int ci = 0; ci < C1N; ++ci) {
      const __half2 a01 = *(const __half2*)&h1p[ci][2*rA];
      const __half2 a23 = *(const __half2*)&h1p[ci][2*rA+2];
      const __half2 b01 = *(const __half2*)&h1p[ci][2*rB];
      const __half2 b23 = *(const __half2*)&h1p[ci][2*rB+2];
      const float hA[4] = { __low2float(a01), __high2float(a01), __low2float(a23), __high2float(a23) };
      const float hB[4] = { __low2float(b01), __high2float(b01), __low2float(b23), __high2float(b23) };
      #pragma unroll
      for (int k = 0; k < 3; ++k) {
        const float4 wv0 = *(const float4*)&w2s[(ci*3+k)*64 + c0];
        const float4 wv1 = *(const float4*)&w2s[(ci*3+k)*64 + c0 + 4];
        const float wr[8] = {wv0.x, wv0.y, wv0.z, wv0.w, wv1.x, wv1.y, wv1.z, wv1.w};
        #pragma unroll
        for (int p = 0; p < 2; ++p) {
          const float xa = hA[k+p];
          const float xb = hB[k+p];
          #pragma unroll
          for (int cc = 0; cc < 8; ++cc) {
            acc[0][p][cc] = fmaf(wr[cc], xa, acc[0][p][cc]);
            acc[1][p][cc] = fmaf(wr[cc], xb, acc[1][p][cc]);
          }
        }
      }
    }
    #pragma unroll
    for (int rr = 0; rr < 2; ++rr) {
      const int r = rr ? rB : rA;
      float* outp = x0 + ((size_t)bid*SEQ + r)*DM + c0;
      #pragma unroll
      for (int cc = 0; cc < 8; ++cc) {
        float v0 = (acc[rr][0][cc] + cb2[cc])*sc2[cc] + bt2[cc];
        float v1 = (acc[rr][1][cc] + cb2[cc])*sc2[cc] + bt2[cc];
        float v = fmaxf(fmaxf(v0, v1), 0.f);
        const int d = c0 + cc;
        const float ang = (float)r * __expf(-0.14391156463f*(float)(d & ~1));
        const float pe = (d & 1) ? cosf(ang) : sinf(ang);
        outp[cc] = v + pe;
      }
    }
  }
}

// ---------- transformer kernel v7: every phase <= ~50 live VGPR ----------
// LDS map (136 KiB):
//   [0   , 32K )  xs  : __half [256 rows][64] packed, row=128B, XOR ((r&7)<<4)
//   [32K , 40K )  lnb : float  [4][256][2]
//   [40K , 72K )  Ks  : __half [j][h*8] packed, row=128B, XOR ((j&7)<<4)
//   [72K , 136K)  Vs  : float  [j][h*8], row=256B, XOR per 16B
//   attv buf (fp16 [256][64]) and FF hidden (fp16 [256][128]) overlay [40K,..)
__global__ __attribute__((amdgpu_waves_per_eu(4,4))) __launch_bounds__(1024) void tx_kernel(
  const float* __restrict__ x0, float* __restrict__ nf,
  const float* __restrict__ wqkv, const float* __restrict__ bqkv,
  const float* __restrict__ wo, const float* __restrict__ bo,
  const float* __restrict__ ln1g, const float* __restrict__ ln1b,
  const float* __restrict__ fw1, const float* __restrict__ fb1,
  const float* __restrict__ fw2, const float* __restrict__ fb2,
  const float* __restrict__ ln2g, const float* __restrict__ ln2b)
{
  __shared__ char smem[139264];
  __half* xs  = (__half*)(smem);
  float*  lnb = (float*)(smem + 32768);
  char*   Ksb = smem + 40960;
  char*   Vsb = smem + 73728;
  char*   ffb = smem + 40960;

  const int bid = blockIdx.x;
  const int s = bid >> 6, b = bid & 63;
  const int t = threadIdx.x;
  const int r = t & 255;
  const int sub = __builtin_amdgcn_readfirstlane(t >> 8);
  const int db = sub*16;
  const int rs = (r & 7) << 4;
  char* xrb = (char*)xs + r*128;

  // ---- load x0 row r, dims db..db+15, pack to fp16 ----
  {
    const float* xp = x0 + ((size_t)bid*SEQ + r)*DM + db;
    float v[16];
    #pragma unroll
    for (int i = 0; i < 16; i += 4) {
      float4 q4 = *(const float4*)(xp + i);
      v[i]=q4.x; v[i+1]=q4.y; v[i+2]=q4.z; v[i+3]=q4.w;
    }
    wchunk8(xrb + (((2*sub  )*16) ^ rs), v);
    wchunk8(xrb + (((2*sub+1)*16) ^ rs), v+8);
  }
  __syncthreads();

  const float qs = 0.35355339059327373f * 1.4426950408889634f; // 1/sqrt(8)*log2(e)

  for (int layer = 0; layer < 2; ++layer) {
    const int wi = s*2 + layer;
    const float* Wq  = wqkv + (size_t)wi*192*64;
    const float* Bq  = bqkv + wi*192;
    const float* Wo  = wo   + (size_t)wi*64*64;
    const float* Bo  = bo   + wi*64;
    const float* G1  = ln1g + wi*64;  const float* B1 = ln1b + wi*64;
    const float* W1  = fw1  + (size_t)wi*256*64;  const float* Bf1 = fb1 + wi*256;
    const float* W2  = fw2  + (size_t)wi*64*256;  const float* Bf2 = fb2 + wi*64;
    const float* G2  = ln2g + wi*64;  const float* B2 = ln2b + wi*64;

    // ---- K: 2 groups of 8 outputs ----
    {
      char* kb = Ksb + r*128;
      #pragma unroll
      for (int g = 0; g < 2; ++g) {
        float acc[8];
        #pragma unroll
        for (int i = 0; i < 8; ++i) acc[i] = Bq[64+db+g*8+i];
        GROUP8_ACC(acc, xrb, Wq + (64+db+g*8)*64, 64);
        wchunk8(kb + (((2*sub+g)*16) ^ rs), acc);
      }
    }
    // ---- V: 2 groups of 8 ----
    {
      char* vb = Vsb + r*256;
      #pragma unroll
      for (int g = 0; g < 2; ++g) {
        float acc[8];
        #pragma unroll
        for (int i = 0; i < 8; ++i) acc[i] = Bq[128+db+g*8+i];
        GROUP8_ACC(acc, xrb, Wq + (128+db+g*8)*64, 64);
        const int so = (2*sub+g)*32;
        *(float4*)(vb + ((so     ) ^ rs)) = make_float4(acc[0],acc[1],acc[2],acc[3]);
        *(float4*)(vb + ((so + 16) ^ rs)) = make_float4(acc[4],acc[5],acc[6],acc[7]);
      }
    }
    // ---- Q: 2 groups of 8, stays in registers ----
    float q[16];
    #pragma unroll
    for (int g = 0; g < 2; ++g) {
      float acc[8];
      #pragma unroll
      for (int i = 0; i < 8; ++i) acc[i] = Bq[db+g*8+i];
      GROUP8_ACC(acc, xrb, Wq + (db+g*8)*64, 64);
      #pragma unroll
      for (int i = 0; i < 8; ++i) q[g*8+i] = acc[i]*qs;
    }
    __syncthreads();

    // ---- attention: one head at a time; K/V reads wave-uniform (broadcast) ----
    float attv[16];
    #pragma unroll
    for (int hf = 0; hf < 2; ++hf) {
      const int h = 2*sub + hf;
      const float q0=q[hf*8+0],q1=q[hf*8+1],q2=q[hf*8+2],q3=q[hf*8+3];
      const float q4=q[hf*8+4],q5=q[hf*8+5],q6=q[hf*8+6],q7=q[hf*8+7];
      float a0=0.f,a1=0.f,a2=0.f,a3=0.f,a4=0.f,a5=0.f,a6=0.f,a7=0.f,lsum=0.f;
      #pragma unroll 2
      for (int j = 0; j < SEQ; ++j) {
        const int jsw = (j&7)<<4;
        const uint4 kw = *(const uint4*)(Ksb + j*128 + ((h*16) ^ jsw));
        float2 f0 = __half22float2(*(const __half2*)&kw.x);
        float2 f1 = __half22float2(*(const __half2*)&kw.y);
        float2 f2 = __half22float2(*(const __half2*)&kw.z);
        float2 f3 = __half22float2(*(const __half2*)&kw.w);
        float sA = fmaf(q0,f0.x, q1*f0.y) + fmaf(q2,f1.x, q3*f1.y);
        float sB = fmaf(q4,f2.x, q5*f2.y) + fmaf(q6,f3.x, q7*f3.y);
        float p = fast_exp2(sA + sB);       // bounded scores -> max-free softmax
        const char* vb = Vsb + j*256;
        float4 v0 = *(const float4*)(vb + ((h*32     ) ^ jsw));
        float4 v1 = *(const float4*)(vb + ((h*32 + 16) ^ jsw));
        lsum += p;
        a0 = fmaf(p, v0.x, a0); a1 = fmaf(p, v0.y, a1);
        a2 = fmaf(p, v0.z, a2); a3 = fmaf(p, v0.w, a3);
        a4 = fmaf(p, v1.x, a4); a5 = fmaf(p, v1.y, a5);
        a6 = fmaf(p, v1.z, a6); a7 = fmaf(p, v1.w, a7);
      }
      const float inv = 1.0f / lsum;
      attv[hf*8+0]=a0*inv; attv[hf*8+1]=a1*inv; attv[hf*8+2]=a2*inv; attv[hf*8+3]=a3*inv;
      attv[hf*8+4]=a4*inv; attv[hf*8+5]=a5*inv; attv[hf*8+6]=a6*inv; attv[hf*8+7]=a7*inv;
    }
    __syncthreads();                       // all Ks/Vs reads done
    {
      char* ab = ffb + r*128;              // attv buffer overlays dead Ks
      wchunk8(ab + (((2*sub  )*16) ^ rs), attv);
      wchunk8(ab + (((2*sub+1)*16) ^ rs), attv+8);
    }
    __syncthreads();

    // ---- O-projection + residual; stash y (fp16) into own xs chunks ----
    {
      const char* ab = ffb + r*128;
      float p1 = 0.f, p2 = 0.f;
      #pragma unroll
      for (int g = 0; g < 2; ++g) {
        float acc[8];
        #pragma unroll
        for (int i = 0; i < 8; ++i) acc[i] = Bo[db+g*8+i];
        GROUP8_ACC(acc, ab, Wo + (db+g*8)*64, 64);
        float res[8];
        rchunk8(xrb + (((2*sub+g)*16) ^ rs), res);
        #pragma unroll
        for (int i = 0; i < 8; ++i) {
          float y = acc[i] + res[i];
          p1 += y; p2 = fmaf(y, y, p2);
          acc[i] = y;
        }
        wchunk8(xrb + (((2*sub+g)*16) ^ rs), acc);   // own chunks only: no race
      }
      lnb[(sub*SEQ + r)*2    ] = p1;
      lnb[(sub*SEQ + r)*2 + 1] = p2;
    }
    __syncthreads();
    {
      float t1 = lnb[(0*SEQ+r)*2] + lnb[(1*SEQ+r)*2] + lnb[(2*SEQ+r)*2] + lnb[(3*SEQ+r)*2];
      float t2 = lnb[(0*SEQ+r)*2+1] + lnb[(1*SEQ+r)*2+1] + lnb[(2*SEQ+r)*2+1] + lnb[(3*SEQ+r)*2+1];
      const float mean = t1 * (1.0f/64.0f);
      const float var  = t2 * (1.0f/64.0f) - mean*mean;
      const float rstd = rsqrtf(var + 1e-5f);
      #pragma unroll
      for (int g = 0; g < 2; ++g) {
        float y8[8];
        rchunk8(xrb + (((2*sub+g)*16) ^ rs), y8);
        #pragma unroll
        for (int i = 0; i < 8; ++i)
          y8[i] = (y8[i]-mean)*rstd*G1[db+g*8+i] + B1[db+g*8+i];
        wchunk8(xrb + (((2*sub+g)*16) ^ rs), y8);
      }
    }
    __syncthreads();

    // ---- FF: 64->256 gelu ->64, two 128-hidden passes ----
    float out16[16] = {0.f,0.f,0.f,0.f,0.f,0.f,0.f,0.f,0.f,0.f,0.f,0.f,0.f,0.f,0.f,0.f};
    char* frb = ffb + r*256;
    for (int pass = 0; pass < 2; ++pass) {
      #pragma unroll
      for (int g = 0; g < 4; ++g) {        // 8 hidden units per group
        const int hi0 = pass*128 + sub*32 + g*8;
        float acc[8];
        #pragma unroll
        for (int i = 0; i < 8; ++i) acc[i] = Bf1[hi0+i];
        GROUP8_ACC(acc, xrb, W1 + hi0*64, 64);
        #pragma unroll
        for (int i = 0; i < 8; ++i)
          acc[i] = 0.5f*acc[i]*(1.0f + erff(acc[i]*0.70710678118654752f));
        wchunk8(frb + (((sub*4+g)*16) ^ rs), acc);
      }
      __syncthreads();
      #pragma unroll
      for (int cc = 0; cc < 16; ++cc) {
        float gv[8]; rchunk8(frb + ((cc*16) ^ rs), gv);
        #pragma unroll
        for (int i = 0; i < 16; ++i) {
          const float* w = W2 + (db+i)*256 + pass*128 + cc*8;
          float acc = out16[i];
          acc = fmaf(gv[0], w[0], acc); acc = fmaf(gv[1], w[1], acc);
          acc = fmaf(gv[2], w[2], acc); acc = fmaf(gv[3], w[3], acc);
          acc = fmaf(gv[4], w[4], acc); acc = fmaf(gv[5], w[5], acc);
          acc = fmaf(gv[6], w[6], acc); acc = fmaf(gv[7], w[7], acc);
          out16[i] = acc;
        }
      }
      __syncthreads();
    }
    // ---- residual + LN2 (same xs-stash trick) ----
    {
      float p1 = 0.f, p2 = 0.f;
      #pragma unroll
      for (int g = 0; g < 2; ++g) {
        float res[8];
        rchunk8(xrb + (((2*sub+g)*16) ^ rs), res);
        float y8[8];
        #pragma unroll
        for (int i = 0; i < 8; ++i) {
          y8[i] = out16[g*8+i] + Bf2[db+g*8+i] + res[i];
          p1 += y8[i]; p2 = fmaf(y8[i], y8[i], p2);
        }
        wchunk8(xrb + (((2*sub+g)*16) ^ rs), y8);
      }
      lnb[(sub*SEQ + r)*2    ] = p1;
      lnb[(sub*SEQ + r)*2 + 1] = p2;
      __syncthreads();
      float s1 = lnb[(0*SEQ+r)*2] + lnb[(1*SEQ+r)*2] + lnb[(2*SEQ+r)*2] + lnb[(3*SEQ+r)*2];
      float s2 = lnb[(0*SEQ+r)*2+1] + lnb[(1*SEQ+r)*2+1] + lnb[(2*SEQ+r)*2+1] + lnb[(3*SEQ+r)*2+1];
      const float mean = s1 * (1.0f/64.0f);
      const float var  = s2 * (1.0f/64.0f) - mean*mean;
      const float rstd = rsqrtf(var + 1e-5f);
      #pragma unroll
      for (int g = 0; g < 2; ++g) {
        float y8[8];
        rchunk8(xrb + (((2*sub+g)*16) ^ rs), y8);
        #pragma unroll
        for (int i = 0; i < 8; ++i)
          y8[i] = (y8[i]-mean)*rstd*G2[db+g*8+i] + B2[db+g*8+i];
        wchunk8(xrb + (((2*sub+g)*16) ^ rs), y8);
      }
    }
    __syncthreads();
  }

  // ---- mean over sequence -> nf[b][s][d] ----
  if (t < 256) {
    const int d = t & 63, qu = t >> 6;
    const int coff = ((d>>3)<<4);
    const int lo = (d&7)<<1;
    float sm = 0.f;
    for (int rr = qu*64; rr < qu*64 + 64; ++rr) {
      const char* p = (const char*)xs + rr*128 + ((coff ^ ((rr&7)<<4)) + lo);
      sm += __half2float(*(const __half*)p);
    }
    lnb[qu*64 + d] = sm;
  }
  __syncthreads();
  if (t < 64) {
    float sm = lnb[t] + lnb[64+t] + lnb[128+t] + lnb[192+t];
    nf[((size_t)b*4 + s)*64 + t] = sm * (1.0f/256.0f);
  }
}

// ------------------------- graph head kernel (unchanged) -------------------------
__global__ __launch_bounds__(128) void head_kernel(
  const float* __restrict__ nf,
  const float* __restrict__ ws_w, const float* __restrict__ ws_b,
  const float* __restrict__ b_s,  const float* __restrict__ lambda_init,
  const float* __restrict__ mc_w1, const float* __restrict__ mc_b1,
  const float* __restrict__ mc_w2, const float* __restrict__ mc_b2,
  const float* __restrict__ g1w, const float* __restrict__ g1b,
  const float* __restrict__ g2w, const float* __restrict__ g2b,
  const float* __restrict__ cw1, const float* __restrict__ cb1,
  const float* __restrict__ cw2, const float* __restrict__ cb2,
  float* __restrict__ out)
{
  const int b = blockIdx.x, t = threadIdx.x;
  __shared__ float nfb[256];
  __shared__ float meannf[64];
  __shared__ float fafb[8];
  __shared__ float z1[32];
  __shared__ float normM[16];
  __shared__ float rs[4];
  __shared__ float xw[512];
  __shared__ float hmat[512];
  __shared__ float hw[1024];
  __shared__ float gv[256];
  __shared__ float r1[128];

  for (int i = t; i < 256; i += 128) nfb[i] = nf[b*256 + i];
  __syncthreads();
  if (t < 8) {
    const int i = t & 3;
    const float* w = ws_w + (t >> 2)*64;
    float acc = 0.f;
    for (int c = 0; c < 64; ++c) acc = fmaf(nfb[i*64+c], w[c], acc);
    fafb[t] = acc;
  }
  if (t >= 64 && t < 128) {
    const int d = t - 64;
    meannf[d] = 0.25f*(nfb[d] + nfb[64+d] + nfb[128+d] + nfb[192+d]);
  }
  __syncthreads();
  if (t < 32) {
    float acc = mc_b1[t];
    const float* w = mc_w1 + t*64;
    for (int c = 0; c < 64; ++c) acc = fmaf(meannf[c], w[c], acc);
    z1[t] = fmaxf(acc, 0.f);
  }
  __syncthreads();
  if (t == 0) {
    float li = mc_b2[0];
    for (int k = 0; k < 32; ++k) li = fmaf(z1[k], mc_w2[k], li);
    const float lam = (1.0f/(1.0f + __expf(-li))) * lambda_init[0];
    const float AB[4][4] = {{1,1,0,0},{1,1,1,1},{0,1,1,1},{0,1,1,1}};
    const float add = ws_b[0] + b_s[0];
    float sM[4][4], deg[4];
    for (int i = 0; i < 4; ++i) {
      float d_ = 0.f;
      for (int j = 0; j < 4; ++j) {
        sM[i][j] = 1.0f/(1.0f + __expf(-(fafb[i] + fafb[4+j] + add)));
        d_ += sM[i][j];
      }
      deg[i] = d_;
    }
    float A[4][4], dinv[4];
    for (int i = 0; i < 4; ++i)
      for (int j = 0; j < 4; ++j) {
        const float a_ = sM[i][j] / (deg[j] + 1e-8f);
        const float sh = fmaxf(a_ * AB[i][j], 0.f);
        A[i][j] = lam*((i==j) ? 1.f : 0.f) + (1.0f - lam)*sh;
      }
    for (int j = 0; j < 4; ++j) {
      float d_ = 0.f;
      for (int i = 0; i < 4; ++i) d_ += A[i][j];
      dinv[j] = (d_ > 0.f) ? rsqrtf(d_) : 0.f;
    }
    for (int i = 0; i < 4; ++i) {
      float r_ = 0.f;
      for (int j = 0; j < 4; ++j) {
        const float n_ = dinv[i]*A[i][j]*dinv[j];
        normM[i*4+j] = n_;
        r_ += n_;
      }
      rs[i] = r_;
    }
  }
  __syncthreads();
  for (int idx = t; idx < 512; idx += 128) {
    const int i = idx >> 7, f = idx & 127;
    float acc = 0.f;
    for (int c = 0; c < 64; ++c) acc = fmaf(nfb[i*64+c], g1w[c*128 + f], acc);
    xw[idx] = acc;
  }
  __syncthreads();
  for (int idx = t; idx < 512; idx += 128) {
    const int j = idx >> 7, f = idx & 127;
    float acc = g1b[f];
    #pragma unroll
    for (int i = 0; i < 4; ++i) acc = fmaf(normM[i*4+j], xw[i*128+f], acc);
    hmat[j*128+f] = fmaxf(acc, 0.f);
  }
  __syncthreads();
  for (int idx = t; idx < 1024; idx += 128) {
    const int i = idx >> 8, f = idx & 255;
    float acc = 0.f;
    for (int c = 0; c < 128; ++c) acc = fmaf(hmat[i*128+c], g2w[c*256+f], acc);
    hw[idx] = acc;
  }
  __syncthreads();
  for (int f = t; f < 256; f += 128) {
    float acc = 0.f;
    #pragma unroll
    for (int i = 0; i < 4; ++i) acc = fmaf(rs[i], hw[i*256+f], acc);
    gv[f] = 0.25f*acc + g2b[f];
  }
  __syncthreads();
  if (t < 128) {
    float acc = cb1[t];
    for (int c = 0; c < 256; ++c) acc = fmaf(gv[c], cw1[c*128+t], acc);
    r1[t] = fmaxf(acc, 0.f);
  }
  __syncthreads();
  if (t < 5) {
    float acc = cb2[t];
    for (int k = 0; k < 128; ++k) acc = fmaf(r1[k], cw2[k*5 + t], acc);
    out[b*5 + t] = acc;
  }
}

// ------------------------- launch -------------------------
extern "C" void kernel_launch(void* const* d_in, const int* in_sizes, int n_in,
                              void* d_out, int out_size, void* d_ws, size_t ws_size,
                              hipStream_t stream) {
  (void)in_sizes; (void)n_in; (void)out_size; (void)ws_size;
  const float* sens   = (const float*)d_in[0];
  const float* c1w    = (const float*)d_in[1];
  const float* c1b    = (const float*)d_in[2];
  const float* bn1g   = (const float*)d_in[3];
  const float* bn1b   = (const float*)d_in[4];
  const float* c2w    = (const float*)d_in[5];
  const float* c2b    = (const float*)d_in[6];
  const float* bn2g   = (const float*)d_in[7];
  const float* bn2b   = (const float*)d_in[8];
  const float* wqkv   = (const float*)d_in[9];
  const float* bqkv   = (const float*)d_in[10];
  const float* wo     = (const float*)d_in[11];
  const float* bo     = (const float*)d_in[12];
  const float* ln1g   = (const float*)d_in[13];
  const float* ln1b   = (const float*)d_in[14];
  const float* fw1    = (const float*)d_in[15];
  const float* fb1    = (const float*)d_in[16];
  const float* fw2    = (const float*)d_in[17];
  const float* fb2    = (const float*)d_in[18];
  const float* ln2g   = (const float*)d_in[19];
  const float* ln2b   = (const float*)d_in[20];
  const float* ws_w   = (const float*)d_in[21];
  const float* ws_b   = (const float*)d_in[22];
  const float* b_s    = (const float*)d_in[23];
  const float* lam0   = (const float*)d_in[24];
  const float* mc_w1  = (const float*)d_in[25];
  const float* mc_b1  = (const float*)d_in[26];
  const float* mc_w2  = (const float*)d_in[27];
  const float* mc_b2  = (const float*)d_in[28];
  const float* g1w    = (const float*)d_in[29];
  const float* g1b    = (const float*)d_in[30];
  const float* g2w    = (const float*)d_in[31];
  const float* g2b    = (const float*)d_in[32];
  const float* cw1    = (const float*)d_in[33];
  const float* cb1    = (const float*)d_in[34];
  const float* cw2    = (const float*)d_in[35];
  const float* cb2    = (const float*)d_in[36];

  float* x0 = (float*)d_ws;                                      // 16 MiB
  float* nf = (float*)((char*)d_ws + (size_t)NSENS*NB*SEQ*DM*4); // 64 KiB

  conv_kernel<<<NSENS*NB, 256, 0, stream>>>(sens, c1w, c1b, bn1g, bn1b,
                                            c2w, c2b, bn2g, bn2b, x0);
  tx_kernel<<<NSENS*NB, 1024, 0, stream>>>(x0, nf, wqkv, bqkv, wo, bo,
                                           ln1g, ln1b, fw1, fb1, fw2, fb2, ln2g, ln2b);
  head_kernel<<<NB, 128, 0, stream>>>(nf, ws_w, ws_b, b_s, lam0,
                                      mc_w1, mc_b1, mc_w2, mc_b2,
                                      g1w, g1b, g2w, g2b, cw1, cb1, cw2, cb2,
                                      (float*)d_out);
}

// Round 9
// 356.064 us; speedup vs baseline: 2.8130x; 2.8130x over previous
//
#include <hip/hip_runtime.h>
#include <hip/hip_fp16.h>

#define NSENS 4
#define NB    64
#define LIN   2048
#define C1N   32
#define LP1   512
#define C2N   64
#define SEQ   256
#define DM    64
#define H1S   516

typedef _Float16 f16x4 __attribute__((ext_vector_type(4)));
typedef _Float16 f16x8 __attribute__((ext_vector_type(8)));
typedef float    f32x4 __attribute__((ext_vector_type(4)));

#define MFMA16(A,B,C) __builtin_amdgcn_mfma_f32_16x16x16f16((A),(B),(C),0,0,0)
#define MFMA32(A,B,C) __builtin_amdgcn_mfma_f32_16x16x32_f16((A),(B),(C),0,0,0)

// swizzled LDS addressing: 16B-chunk XOR by (row&7)<<4
__device__ __forceinline__ char* swp(char* base, int row, int stride, int byteoff) {
  return base + row*stride + ((byteoff & ~15) ^ ((row & 7) << 4)) + (byteoff & 15);
}
__device__ __forceinline__ void sw_h(char* base, int row, int stride, int col, float v) {
  *(_Float16*)swp(base, row, stride, col*2) = (_Float16)v;
}
__device__ __forceinline__ float sr_h(char* base, int row, int stride, int col) {
  return (float)*(const _Float16*)swp(base, row, stride, col*2);
}
__device__ __forceinline__ void pack8(char* p, float4 a, float4 b) {
  __half2 h0 = __floats2half2_rn(a.x,a.y), h1 = __floats2half2_rn(a.z,a.w);
  __half2 h2 = __floats2half2_rn(b.x,b.y), h3 = __floats2half2_rn(b.z,b.w);
  uint4 u; u.x=*(unsigned*)&h0; u.y=*(unsigned*)&h1; u.z=*(unsigned*)&h2; u.w=*(unsigned*)&h3;
  *(uint4*)p = u;
}

// ---------------- weight pack: fp32 -> fp16 row-major ----------------
// per wi: wqkv[192*64] | wo[64*64] | w1[256*64] | w2[64*256]  (49152 halfs)
__global__ __launch_bounds__(256) void wprep_kernel(
    const float* __restrict__ wqkv, const float* __restrict__ wo,
    const float* __restrict__ fw1,  const float* __restrict__ fw2,
    unsigned short* __restrict__ w16)
{
  const int wi = blockIdx.x;
  unsigned short* dst = w16 + (size_t)wi*49152;
  const float* s0 = wqkv + (size_t)wi*12288;
  const float* s1 = wo   + (size_t)wi*4096;
  const float* s2 = fw1  + (size_t)wi*16384;
  const float* s3 = fw2  + (size_t)wi*16384;
  for (int i = threadIdx.x; i < 12288; i += 256) { __half h = __float2half_rn(s0[i]); dst[i]       = *(unsigned short*)&h; }
  for (int i = threadIdx.x; i < 4096;  i += 256) { __half h = __float2half_rn(s1[i]); dst[12288+i] = *(unsigned short*)&h; }
  for (int i = threadIdx.x; i < 16384; i += 256) { __half h = __float2half_rn(s2[i]); dst[16384+i] = *(unsigned short*)&h; }
  for (int i = threadIdx.x; i < 16384; i += 256) { __half h = __float2half_rn(s3[i]); dst[32768+i] = *(unsigned short*)&h; }
}

// ------------------------- conv branch kernel (unchanged) -------------------------
__global__ __launch_bounds__(256) void conv_kernel(
    const float* __restrict__ sens,
    const float* __restrict__ c1w, const float* __restrict__ c1b,
    const float* __restrict__ bn1g, const float* __restrict__ bn1b,
    const float* __restrict__ c2w, const float* __restrict__ c2b,
    const float* __restrict__ bn2g, const float* __restrict__ bn2b,
    float* __restrict__ x0)
{
  const int bid = blockIdx.x;
  const int s = bid >> 6, b = bid & 63;
  const int tid = threadIdx.x;
  __shared__ __half h1p[C1N][H1S];
  __shared__ float w2s[C1N*3*C2N];

  for (int i = tid; i < C1N*3*C2N; i += 256) {
    int co = i & 63; int rem = i >> 6; int k = rem % 3; int ci = rem / 3;
    w2s[(ci*3 + k)*64 + co] = c2w[((s*C2N + co)*C1N + ci)*3 + k];
  }

  const float* xg = sens + (size_t)(s*NB + b)*LIN;
  const float bnr = rsqrtf(1.0f + 1e-5f);

  {
    const int c = tid & 31;
    const int l0 = tid >> 5;
    const float w0 = c1w[(s*C1N + c)*5 + 0];
    const float w1 = c1w[(s*C1N + c)*5 + 1];
    const float w2 = c1w[(s*C1N + c)*5 + 2];
    const float w3 = c1w[(s*C1N + c)*5 + 3];
    const float w4 = c1w[(s*C1N + c)*5 + 4];
    const float cb = c1b[s*C1N + c];
    const float sc = bn1g[s*C1N + c]*bnr;
    const float bt = bn1b[s*C1N + c];
    for (int l = l0; l < LP1; l += 8) {
      const int base = 4*l;
      float xm2 = (base-2 >= 0) ? xg[base-2] : 0.f;
      float xm1 = (base-1 >= 0) ? xg[base-1] : 0.f;
      float x0v = xg[base+0];
      float x1v = xg[base+1];
      float x2v = xg[base+2];
      float x3v = xg[base+3];
      float x4v = (base+4 < LIN) ? xg[base+4] : 0.f;
      float y0 = w0*xm2 + w1*xm1 + w2*x0v + w3*x1v + w4*x2v;
      float y1 = w0*x0v + w1*x1v + w2*x2v + w3*x3v + w4*x4v;
      y0 = (y0 + cb)*sc + bt;
      y1 = (y1 + cb)*sc + bt;
      h1p[c][l+1] = __float2half(fmaxf(fmaxf(y0, y1), 0.f));
      if (l == 0)      h1p[c][0]      = __float2half(0.f);
      if (l == LP1-1)  h1p[c][LP1+1]  = __float2half(0.f);
    }
  }
  __syncthreads();

  const int rg = tid & 31, cg = tid >> 5;
  const int c0 = cg*8;
  float cb2[8], sc2[8], bt2[8];
  #pragma unroll
  for (int cc = 0; cc < 8; ++cc) {
    cb2[cc] = c2b[s*C2N + c0 + cc];
    sc2[cc] = bn2g[s*C2N + c0 + cc]*bnr;
    bt2[cc] = bn2b[s*C2N + c0 + cc];
  }
  for (int it = 0; it < 4; ++it) {
    const int rA = 64*it + rg;
    const int rB = rA + 32;
    float acc[2][2][8] = {};
    for (int ci = 0; ci < C1N; ++ci) {
      const __half2 a01 = *(const __half2*)&h1p[ci][2*rA];
      const __half2 a23 = *(const __half2*)&h1p[ci][2*rA+2];
      const __half2 b01 = *(const __half2*)&h1p[ci][2*rB];
      const __half2 b23 = *(const __half2*)&h1p[ci][2*rB+2];
      const float hA[4] = { __low2float(a01), __high2float(a01), __low2float(a23), __high2float(a23) };
      const float hB[4] = { __low2float(b01), __high2float(b01), __low2float(b23), __high2float(b23) };
      #pragma unroll
      for (int k = 0; k < 3; ++k) {
        const float4 wv0 = *(const float4*)&w2s[(ci*3+k)*64 + c0];
        const float4 wv1 = *(const float4*)&w2s[(ci*3+k)*64 + c0 + 4];
        const float wr[8] = {wv0.x, wv0.y, wv0.z, wv0.w, wv1.x, wv1.y, wv1.z, wv1.w};
        #pragma unroll
        for (int p = 0; p < 2; ++p) {
          const float xa = hA[k+p];
          const float xb = hB[k+p];
          #pragma unroll
          for (int cc = 0; cc < 8; ++cc) {
            acc[0][p][cc] = fmaf(wr[cc], xa, acc[0][p][cc]);
            acc[1][p][cc] = fmaf(wr[cc], xb, acc[1][p][cc]);
          }
        }
      }
    }
    #pragma unroll
    for (int rr = 0; rr < 2; ++rr) {
      const int r = rr ? rB : rA;
      float* outp = x0 + ((size_t)bid*SEQ + r)*DM + c0;
      #pragma unroll
      for (int cc = 0; cc < 8; ++cc) {
        float v0 = (acc[rr][0][cc] + cb2[cc])*sc2[cc] + bt2[cc];
        float v1 = (acc[rr][1][cc] + cb2[cc])*sc2[cc] + bt2[cc];
        float v = fmaxf(fmaxf(v0, v1), 0.f);
        const int d = c0 + cc;
        const float ang = (float)r * __expf(-0.14391156463f*(float)(d & ~1));
        const float pe = (d & 1) ? cosf(ang) : sinf(ang);
        outp[cc] = v + pe;
      }
    }
  }
}

// ---------------- transformer kernel v8: MFMA, 512 threads = 8 waves ----------------
// LDS: xs[256][64]f16 | Qb (att overlays) | Kb | Vt[64][256]f16 | ffs 8*768B | red 1KB
__global__ __launch_bounds__(512, 2) void tx_kernel(
  const float* __restrict__ x0, float* __restrict__ nf,
  const unsigned short* __restrict__ w16,
  const float* __restrict__ bqkv, const float* __restrict__ bo,
  const float* __restrict__ ln1g, const float* __restrict__ ln1b,
  const float* __restrict__ fb1,  const float* __restrict__ fb2,
  const float* __restrict__ ln2g, const float* __restrict__ ln2b)
{
  __shared__ char smem[139264];
  char* xs = smem;
  char* Qb = smem + 32768;
  char* Kb = smem + 65536;
  char* Vt = smem + 98304;
  char* ffs = smem + 131072;
  float* red = (float*)(smem + 131072 + 6144);

  const int bid = blockIdx.x;
  const int s = bid >> 6, b = bid & 63;
  const int t = threadIdx.x;
  const int l = t & 63, w = t >> 6;
  const int g = l >> 4, c = l & 15;
  const float qs = 0.35355339059327373f * 1.4426950408889634f; // 1/sqrt(8)*log2(e)

  // ---- x0 -> xs (fp16, swizzled) ----
  {
    const int r = t >> 1, hf = t & 1;
    const float* xp = x0 + ((size_t)bid*SEQ + r)*DM + hf*32;
    #pragma unroll
    for (int ch = 0; ch < 4; ++ch) {
      float4 a = *(const float4*)(xp + ch*8);
      float4 bb = *(const float4*)(xp + ch*8 + 4);
      pack8(swp(xs, r, 128, hf*64 + ch*16), a, bb);
    }
  }
  __syncthreads();

  for (int layer = 0; layer < 2; ++layer) {
    const int wi = s*2 + layer;
    const unsigned short* wq = w16 + (size_t)wi*49152;
    const unsigned short* wo = wq + 12288;
    const unsigned short* w1 = wq + 16384;
    const unsigned short* w2 = wq + 32768;
    const float* Bq  = bqkv + wi*192;
    const float* Bo  = bo   + wi*64;
    const float* G1  = ln1g + wi*64; const float* B1 = ln1b + wi*64;
    const float* Bf1 = fb1  + wi*256; const float* Bf2 = fb2 + wi*64;
    const float* G2  = ln2g + wi*64; const float* B2 = ln2b + wi*64;

    // ======== QKV projections (wave w owns rows w*32..w*32+31) ========
    #pragma unroll
    for (int mi = 0; mi < 2; ++mi) {
      const int m0 = w*32 + mi*16;
      f16x8 a0 = *(const f16x8*)swp(xs, m0+c, 128, 0  + g*16);
      f16x8 a1 = *(const f16x8*)swp(xs, m0+c, 128, 64 + g*16);
      // K (wqkv rows 64..127) -> Kb row-major
      #pragma unroll
      for (int nt = 0; nt < 4; ++nt) {
        const int row = 64 + nt*16 + c;
        f16x8 b0 = *(const f16x8*)(wq + row*64 + 8*g);
        f16x8 b1 = *(const f16x8*)(wq + row*64 + 32 + 8*g);
        f32x4 d = {0.f,0.f,0.f,0.f};
        d = MFMA32(a0, b0, d); d = MFMA32(a1, b1, d);
        const float bias = Bq[64 + nt*16 + c];
        #pragma unroll
        for (int i = 0; i < 4; ++i) sw_h(Kb, m0+4*g+i, 128, nt*16+c, d[i] + bias);
      }
      // Q (rows 0..63), scaled -> Qb row-major
      #pragma unroll
      for (int nt = 0; nt < 4; ++nt) {
        const int row = nt*16 + c;
        f16x8 b0 = *(const f16x8*)(wq + row*64 + 8*g);
        f16x8 b1 = *(const f16x8*)(wq + row*64 + 32 + 8*g);
        f32x4 d = {0.f,0.f,0.f,0.f};
        d = MFMA32(a0, b0, d); d = MFMA32(a1, b1, d);
        const float bias = Bq[nt*16 + c];
        #pragma unroll
        for (int i = 0; i < 4; ++i) sw_h(Qb, m0+4*g+i, 128, nt*16+c, (d[i] + bias)*qs);
      }
      // V (rows 128..191) -> Vt transposed [dim][j]
      #pragma unroll
      for (int nt = 0; nt < 4; ++nt) {
        const int row = 128 + nt*16 + c;
        f16x8 b0 = *(const f16x8*)(wq + row*64 + 8*g);
        f16x8 b1 = *(const f16x8*)(wq + row*64 + 32 + 8*g);
        f32x4 d = {0.f,0.f,0.f,0.f};
        d = MFMA32(a0, b0, d); d = MFMA32(a1, b1, d);
        const float bias = Bq[128 + nt*16 + c];
        #pragma unroll
        for (int i = 0; i < 4; ++i) sw_h(Vt, nt*16+c, 512, m0+4*g+i, d[i] + bias);
      }
    }
    __syncthreads();   // (a) Q/K/Vt visible to all

    // ======== attention: 16 tasks = 8 heads x 2 q-tiles ========
    unsigned pk0[16], pk1[16];
    #pragma unroll
    for (int task = 0; task < 16; ++task) {
      const int h = task >> 1;
      const int q0 = w*32 + (task & 1)*16;
      f16x4 qb = {0,0,0,0};
      if (g < 2) qb = *(const f16x4*)swp(Qb, q0+c, 128, 16*h + 8*g);
      f32x4 o = {0.f,0.f,0.f,0.f};
      #pragma unroll 2
      for (int jt = 0; jt < 16; ++jt) {
        f16x4 ka = {0,0,0,0};
        if (g < 2) ka = *(const f16x4*)swp(Kb, jt*16+c, 128, 16*h + 8*g);
        f32x4 st = {0.f,0.f,0.f,0.f};
        st = MFMA16(ka, qb, st);            // S^T tile: lane holds S^T[jt*16+4g+i][q0+c]
        f16x4 pb;
        pb[0] = (_Float16)exp2f(st[0]);
        pb[1] = (_Float16)exp2f(st[1]);
        pb[2] = (_Float16)exp2f(st[2]);
        pb[3] = (_Float16)exp2f(st[3]);
        f16x4 va;
        if (c < 8) va = *(const f16x4*)swp(Vt, 8*h+c, 512, jt*32 + (g>>1)*16 + (g&1)*8);
        else { va[0]=(_Float16)1.f; va[1]=(_Float16)1.f; va[2]=(_Float16)1.f; va[3]=(_Float16)1.f; }
        o = MFMA16(va, pb, o);              // O^T: rows d' (c<8), row8 = denom
      }
      const float den = __shfl(o[0], 32 + c, 64);
      const float rinv = 1.0f / den;
      __half2 lo = __floats2half2_rn(o[0]*rinv, o[1]*rinv);
      __half2 hi = __floats2half2_rn(o[2]*rinv, o[3]*rinv);
      pk0[task] = *(unsigned*)&lo;
      pk1[task] = *(unsigned*)&hi;
    }
    __syncthreads();   // (b) all K/Vt/Q reads complete

    // write att (overlays Qb; own rows only)
    #pragma unroll
    for (int task = 0; task < 16; ++task) {
      if (g < 2) {
        const int h = task >> 1;
        const int q0 = w*32 + (task & 1)*16;
        uint2 u; u.x = pk0[task]; u.y = pk1[task];
        *(uint2*)swp(Qb, q0+c, 128, 16*h + 8*g) = u;
      }
    }

    // ======== O-projection + residual + LN1 (own rows; no barrier needed) ========
    #pragma unroll
    for (int mi = 0; mi < 2; ++mi) {
      const int m0 = w*32 + mi*16;
      f16x8 a0 = *(const f16x8*)swp(Qb, m0+c, 128, 0  + g*16);
      f16x8 a1 = *(const f16x8*)swp(Qb, m0+c, 128, 64 + g*16);
      float vals[4][4];
      #pragma unroll
      for (int nt = 0; nt < 4; ++nt) {
        const int row = nt*16 + c;
        f16x8 b0 = *(const f16x8*)(wo + row*64 + 8*g);
        f16x8 b1 = *(const f16x8*)(wo + row*64 + 32 + 8*g);
        f32x4 d = {0.f,0.f,0.f,0.f};
        d = MFMA32(a0, b0, d); d = MFMA32(a1, b1, d);
        const float bias = Bo[nt*16 + c];
        #pragma unroll
        for (int i = 0; i < 4; ++i)
          vals[nt][i] = d[i] + bias + sr_h(xs, m0+4*g+i, 128, nt*16+c);
      }
      float mean[4], rstd[4];
      #pragma unroll
      for (int i = 0; i < 4; ++i) {
        float p1 = vals[0][i]+vals[1][i]+vals[2][i]+vals[3][i];
        float p2 = fmaf(vals[0][i],vals[0][i], fmaf(vals[1][i],vals[1][i],
                   fmaf(vals[2][i],vals[2][i], vals[3][i]*vals[3][i])));
        p1 += __shfl_xor(p1,1,16); p1 += __shfl_xor(p1,2,16); p1 += __shfl_xor(p1,4,16); p1 += __shfl_xor(p1,8,16);
        p2 += __shfl_xor(p2,1,16); p2 += __shfl_xor(p2,2,16); p2 += __shfl_xor(p2,4,16); p2 += __shfl_xor(p2,8,16);
        mean[i] = p1*(1.0f/64.0f);
        rstd[i] = rsqrtf(p2*(1.0f/64.0f) - mean[i]*mean[i] + 1e-5f);
      }
      #pragma unroll
      for (int nt = 0; nt < 4; ++nt) {
        const float gg = G1[nt*16+c], bb = B1[nt*16+c];
        #pragma unroll
        for (int i = 0; i < 4; ++i)
          sw_h(xs, m0+4*g+i, 128, nt*16+c, (vals[nt][i]-mean[i])*rstd[i]*gg + bb);
      }
    }

    // ======== FF fused (own rows) ========
    #pragma unroll
    for (int mi = 0; mi < 2; ++mi) {
      const int m0 = w*32 + mi*16;
      char* tile = ffs + w*768;
      f32x4 o2[4];
      #pragma unroll
      for (int nt2 = 0; nt2 < 4; ++nt2) { o2[nt2][0]=0.f; o2[nt2][1]=0.f; o2[nt2][2]=0.f; o2[nt2][3]=0.f; }
      f16x8 xa0 = *(const f16x8*)swp(xs, m0+c, 128, 0  + g*16);
      f16x8 xa1 = *(const f16x8*)swp(xs, m0+c, 128, 64 + g*16);
      for (int ht = 0; ht < 16; ++ht) {
        const int hrow = ht*16 + c;
        f16x8 b0 = *(const f16x8*)(w1 + hrow*64 + 8*g);
        f16x8 b1 = *(const f16x8*)(w1 + hrow*64 + 32 + 8*g);
        f32x4 d = {0.f,0.f,0.f,0.f};
        d = MFMA32(xa0, b0, d); d = MFMA32(xa1, b1, d);
        const float bias = Bf1[ht*16 + c];
        #pragma unroll
        for (int i = 0; i < 4; ++i) {
          float hv = d[i] + bias;
          hv = 0.5f*hv*(1.0f + erff(hv*0.70710678118654752f));
          *(_Float16*)(tile + (4*g+i)*48 + c*2) = (_Float16)hv;   // tile[qloc][hloc], pad 24
        }
        f16x4 a2 = *(const f16x4*)(tile + c*48 + 8*g);            // tile[c][4g..4g+3]
        #pragma unroll
        for (int nt2 = 0; nt2 < 4; ++nt2) {
          f16x4 b2 = *(const f16x4*)(w2 + (nt2*16+c)*256 + ht*16 + 4*g);
          o2[nt2] = MFMA16(a2, b2, o2[nt2]);
        }
      }
      float vals[4][4];
      #pragma unroll
      for (int nt2 = 0; nt2 < 4; ++nt2) {
        const float bias = Bf2[nt2*16 + c];
        #pragma unroll
        for (int i = 0; i < 4; ++i)
          vals[nt2][i] = o2[nt2][i] + bias + sr_h(xs, m0+4*g+i, 128, nt2*16+c);
      }
      float mean[4], rstd[4];
      #pragma unroll
      for (int i = 0; i < 4; ++i) {
        float p1 = vals[0][i]+vals[1][i]+vals[2][i]+vals[3][i];
        float p2 = fmaf(vals[0][i],vals[0][i], fmaf(vals[1][i],vals[1][i],
                   fmaf(vals[2][i],vals[2][i], vals[3][i]*vals[3][i])));
        p1 += __shfl_xor(p1,1,16); p1 += __shfl_xor(p1,2,16); p1 += __shfl_xor(p1,4,16); p1 += __shfl_xor(p1,8,16);
        p2 += __shfl_xor(p2,1,16); p2 += __shfl_xor(p2,2,16); p2 += __shfl_xor(p2,4,16); p2 += __shfl_xor(p2,8,16);
        mean[i] = p1*(1.0f/64.0f);
        rstd[i] = rsqrtf(p2*(1.0f/64.0f) - mean[i]*mean[i] + 1e-5f);
      }
      #pragma unroll
      for (int nt2 = 0; nt2 < 4; ++nt2) {
        const float gg = G2[nt2*16+c], bb = B2[nt2*16+c];
        #pragma unroll
        for (int i = 0; i < 4; ++i)
          sw_h(xs, m0+4*g+i, 128, nt2*16+c, (vals[nt2][i]-mean[i])*rstd[i]*gg + bb);
      }
    }
    // next layer's projections read only own rows; barrier (a) of next layer covers cross-wave
  }

  // ---- mean over sequence -> nf ----
  __syncthreads();
  if (t < 256) {
    const int d = t & 63, qu = t >> 6;
    float sm = 0.f;
    for (int rr = qu*64; rr < qu*64 + 64; ++rr) sm += sr_h(xs, rr, 128, d);
    red[qu*64 + d] = sm;
  }
  __syncthreads();
  if (t < 64) {
    float sm = red[t] + red[64+t] + red[128+t] + red[192+t];
    nf[((size_t)b*4 + s)*64 + t] = sm * (1.0f/256.0f);
  }
}

// ------------------------- graph head kernel (unchanged) -------------------------
__global__ __launch_bounds__(128) void head_kernel(
  const float* __restrict__ nf,
  const float* __restrict__ ws_w, const float* __restrict__ ws_b,
  const float* __restrict__ b_s,  const float* __restrict__ lambda_init,
  const float* __restrict__ mc_w1, const float* __restrict__ mc_b1,
  const float* __restrict__ mc_w2, const float* __restrict__ mc_b2,
  const float* __restrict__ g1w, const float* __restrict__ g1b,
  const float* __restrict__ g2w, const float* __restrict__ g2b,
  const float* __restrict__ cw1, const float* __restrict__ cb1,
  const float* __restrict__ cw2, const float* __restrict__ cb2,
  float* __restrict__ out)
{
  const int b = blockIdx.x, t = threadIdx.x;
  __shared__ float nfb[256];
  __shared__ float meannf[64];
  __shared__ float fafb[8];
  __shared__ float z1[32];
  __shared__ float normM[16];
  __shared__ float rs[4];
  __shared__ float xw[512];
  __shared__ float hmat[512];
  __shared__ float hw[1024];
  __shared__ float gv[256];
  __shared__ float r1[128];

  for (int i = t; i < 256; i += 128) nfb[i] = nf[b*256 + i];
  __syncthreads();
  if (t < 8) {
    const int i = t & 3;
    const float* w = ws_w + (t >> 2)*64;
    float acc = 0.f;
    for (int c = 0; c < 64; ++c) acc = fmaf(nfb[i*64+c], w[c], acc);
    fafb[t] = acc;
  }
  if (t >= 64 && t < 128) {
    const int d = t - 64;
    meannf[d] = 0.25f*(nfb[d] + nfb[64+d] + nfb[128+d] + nfb[192+d]);
  }
  __syncthreads();
  if (t < 32) {
    float acc = mc_b1[t];
    const float* w = mc_w1 + t*64;
    for (int c = 0; c < 64; ++c) acc = fmaf(meannf[c], w[c], acc);
    z1[t] = fmaxf(acc, 0.f);
  }
  __syncthreads();
  if (t == 0) {
    float li = mc_b2[0];
    for (int k = 0; k < 32; ++k) li = fmaf(z1[k], mc_w2[k], li);
    const float lam = (1.0f/(1.0f + __expf(-li))) * lambda_init[0];
    const float AB[4][4] = {{1,1,0,0},{1,1,1,1},{0,1,1,1},{0,1,1,1}};
    const float add = ws_b[0] + b_s[0];
    float sM[4][4], deg[4];
    for (int i = 0; i < 4; ++i) {
      float d_ = 0.f;
      for (int j = 0; j < 4; ++j) {
        sM[i][j] = 1.0f/(1.0f + __expf(-(fafb[i] + fafb[4+j] + add)));
        d_ += sM[i][j];
      }
      deg[i] = d_;
    }
    float A[4][4], dinv[4];
    for (int i = 0; i < 4; ++i)
      for (int j = 0; j < 4; ++j) {
        const float a_ = sM[i][j] / (deg[j] + 1e-8f);
        const float sh = fmaxf(a_ * AB[i][j], 0.f);
        A[i][j] = lam*((i==j) ? 1.f : 0.f) + (1.0f - lam)*sh;
      }
    for (int j = 0; j < 4; ++j) {
      float d_ = 0.f;
      for (int i = 0; i < 4; ++i) d_ += A[i][j];
      dinv[j] = (d_ > 0.f) ? rsqrtf(d_) : 0.f;
    }
    for (int i = 0; i < 4; ++i) {
      float r_ = 0.f;
      for (int j = 0; j < 4; ++j) {
        const float n_ = dinv[i]*A[i][j]*dinv[j];
        normM[i*4+j] = n_;
        r_ += n_;
      }
      rs[i] = r_;
    }
  }
  __syncthreads();
  for (int idx = t; idx < 512; idx += 128) {
    const int i = idx >> 7, f = idx & 127;
    float acc = 0.f;
    for (int c = 0; c < 64; ++c) acc = fmaf(nfb[i*64+c], g1w[c*128 + f], acc);
    xw[idx] = acc;
  }
  __syncthreads();
  for (int idx = t; idx < 512; idx += 128) {
    const int j = idx >> 7, f = idx & 127;
    float acc = g1b[f];
    #pragma unroll
    for (int i = 0; i < 4; ++i) acc = fmaf(normM[i*4+j], xw[i*128+f], acc);
    hmat[j*128+f] = fmaxf(acc, 0.f);
  }
  __syncthreads();
  for (int idx = t; idx < 1024; idx += 128) {
    const int i = idx >> 8, f = idx & 255;
    float acc = 0.f;
    for (int c = 0; c < 128; ++c) acc = fmaf(hmat[i*128+c], g2w[c*256+f], acc);
    hw[idx] = acc;
  }
  __syncthreads();
  for (int f = t; f < 256; f += 128) {
    float acc = 0.f;
    #pragma unroll
    for (int i = 0; i < 4; ++i) acc = fmaf(rs[i], hw[i*256+f], acc);
    gv[f] = 0.25f*acc + g2b[f];
  }
  __syncthreads();
  if (t < 128) {
    float acc = cb1[t];
    for (int c = 0; c < 256; ++c) acc = fmaf(gv[c], cw1[c*128+t], acc);
    r1[t] = fmaxf(acc, 0.f);
  }
  __syncthreads();
  if (t < 5) {
    float acc = cb2[t];
    for (int k = 0; k < 128; ++k) acc = fmaf(r1[k], cw2[k*5 + t], acc);
    out[b*5 + t] = acc;
  }
}

// ------------------------- launch -------------------------
extern "C" void kernel_launch(void* const* d_in, const int* in_sizes, int n_in,
                              void* d_out, int out_size, void* d_ws, size_t ws_size,
                              hipStream_t stream) {
  (void)in_sizes; (void)n_in; (void)out_size; (void)ws_size;
  const float* sens   = (const float*)d_in[0];
  const float* c1w    = (const float*)d_in[1];
  const float* c1b    = (const float*)d_in[2];
  const float* bn1g   = (const float*)d_in[3];
  const float* bn1b   = (const float*)d_in[4];
  const float* c2w    = (const float*)d_in[5];
  const float* c2b    = (const float*)d_in[6];
  const float* bn2g   = (const float*)d_in[7];
  const float* bn2b   = (const float*)d_in[8];
  const float* wqkv   = (const float*)d_in[9];
  const float* bqkv   = (const float*)d_in[10];
  const float* wo     = (const float*)d_in[11];
  const float* bo     = (const float*)d_in[12];
  const float* ln1g   = (const float*)d_in[13];
  const float* ln1b   = (const float*)d_in[14];
  const float* fw1    = (const float*)d_in[15];
  const float* fb1    = (const float*)d_in[16];
  const float* fw2    = (const float*)d_in[17];
  const float* fb2    = (const float*)d_in[18];
  const float* ln2g   = (const float*)d_in[19];
  const float* ln2b   = (const float*)d_in[20];
  const float* ws_w   = (const float*)d_in[21];
  const float* ws_b   = (const float*)d_in[22];
  const float* b_s    = (const float*)d_in[23];
  const float* lam0   = (const float*)d_in[24];
  const float* mc_w1  = (const float*)d_in[25];
  const float* mc_b1  = (const float*)d_in[26];
  const float* mc_w2  = (const float*)d_in[27];
  const float* mc_b2  = (const float*)d_in[28];
  const float* g1w    = (const float*)d_in[29];
  const float* g1b    = (const float*)d_in[30];
  const float* g2w    = (const float*)d_in[31];
  const float* g2b    = (const float*)d_in[32];
  const float* cw1    = (const float*)d_in[33];
  const float* cb1    = (const float*)d_in[34];
  const float* cw2    = (const float*)d_in[35];
  const float* cb2    = (const float*)d_in[36];

  float*          x0  = (float*)d_ws;                                        // 16 MiB
  float*          nf  = (float*)((char*)d_ws + (size_t)NSENS*NB*SEQ*DM*4);   // 64 KiB
  unsigned short* w16 = (unsigned short*)((char*)d_ws + (size_t)NSENS*NB*SEQ*DM*4 + 65536); // 768 KiB

  wprep_kernel<<<8, 256, 0, stream>>>(wqkv, wo, fw1, fw2, w16);
  conv_kernel<<<NSENS*NB, 256, 0, stream>>>(sens, c1w, c1b, bn1g, bn1b,
                                            c2w, c2b, bn2g, bn2b, x0);
  tx_kernel<<<NSENS*NB, 512, 0, stream>>>(x0, nf, w16, bqkv, bo,
                                          ln1g, ln1b, fb1, fb2, ln2g, ln2b);
  head_kernel<<<NB, 128, 0, stream>>>(nf, ws_w, ws_b, b_s, lam0,
                                      mc_w1, mc_b1, mc_w2, mc_b2,
                                      g1w, g1b, g2w, g2b, cw1, cb1, cw2, cb2,
                                      (float*)d_out);
}

// Round 11
// 354.414 us; speedup vs baseline: 2.8261x; 1.0047x over previous
//
#include <hip/hip_runtime.h>
#include <hip/hip_fp16.h>

#define NSENS 4
#define NB    64
#define LIN   2048
#define C1N   32
#define LP1   512
#define C2N   64
#define SEQ   256
#define DM    64
#define H1S   516

typedef _Float16 f16x4 __attribute__((ext_vector_type(4)));
typedef _Float16 f16x8 __attribute__((ext_vector_type(8)));
typedef float    f32x4 __attribute__((ext_vector_type(4)));

#define MFMA16(A,B,C) __builtin_amdgcn_mfma_f32_16x16x16f16((A),(B),(C),0,0,0)
#define MFMA32(A,B,C) __builtin_amdgcn_mfma_f32_16x16x32_f16((A),(B),(C),0,0,0)

// swizzled LDS addressing: 16B-chunk XOR by (row&7)<<4
__device__ __forceinline__ char* swp(char* base, int row, int stride, int byteoff) {
  return base + row*stride + ((byteoff & ~15) ^ ((row & 7) << 4)) + (byteoff & 15);
}
__device__ __forceinline__ void sw_h(char* base, int row, int stride, int col, float v) {
  *(_Float16*)swp(base, row, stride, col*2) = (_Float16)v;
}
__device__ __forceinline__ float sr_h(char* base, int row, int stride, int col) {
  return (float)*(const _Float16*)swp(base, row, stride, col*2);
}
__device__ __forceinline__ void pack8(char* p, float4 a, float4 b) {
  __half2 h0 = __floats2half2_rn(a.x,a.y), h1 = __floats2half2_rn(a.z,a.w);
  __half2 h2 = __floats2half2_rn(b.x,b.y), h3 = __floats2half2_rn(b.z,b.w);
  uint4 u; u.x=*(unsigned*)&h0; u.y=*(unsigned*)&h1; u.z=*(unsigned*)&h2; u.w=*(unsigned*)&h3;
  *(uint4*)p = u;
}

// ---------------- weight pack: fp32 -> fp16 row-major ----------------
// per wi: wqkv[192*64] | wo[64*64] | w1[256*64] | w2[64*256]  (49152 halfs)
__global__ __launch_bounds__(256) void wprep_kernel(
    const float* __restrict__ wqkv, const float* __restrict__ wo,
    const float* __restrict__ fw1,  const float* __restrict__ fw2,
    unsigned short* __restrict__ w16)
{
  const int wi = blockIdx.x;
  unsigned short* dst = w16 + (size_t)wi*49152;
  const float* s0 = wqkv + (size_t)wi*12288;
  const float* s1 = wo   + (size_t)wi*4096;
  const float* s2 = fw1  + (size_t)wi*16384;
  const float* s3 = fw2  + (size_t)wi*16384;
  for (int i = threadIdx.x; i < 12288; i += 256) { __half h = __float2half_rn(s0[i]); dst[i]       = *(unsigned short*)&h; }
  for (int i = threadIdx.x; i < 4096;  i += 256) { __half h = __float2half_rn(s1[i]); dst[12288+i] = *(unsigned short*)&h; }
  for (int i = threadIdx.x; i < 16384; i += 256) { __half h = __float2half_rn(s2[i]); dst[16384+i] = *(unsigned short*)&h; }
  for (int i = threadIdx.x; i < 16384; i += 256) { __half h = __float2half_rn(s3[i]); dst[32768+i] = *(unsigned short*)&h; }
}

// ------------------------- conv branch kernel (unchanged) -------------------------
__global__ __launch_bounds__(256) void conv_kernel(
    const float* __restrict__ sens,
    const float* __restrict__ c1w, const float* __restrict__ c1b,
    const float* __restrict__ bn1g, const float* __restrict__ bn1b,
    const float* __restrict__ c2w, const float* __restrict__ c2b,
    const float* __restrict__ bn2g, const float* __restrict__ bn2b,
    float* __restrict__ x0)
{
  const int bid = blockIdx.x;
  const int s = bid >> 6, b = bid & 63;
  const int tid = threadIdx.x;
  __shared__ __half h1p[C1N][H1S];
  __shared__ float w2s[C1N*3*C2N];

  for (int i = tid; i < C1N*3*C2N; i += 256) {
    int co = i & 63; int rem = i >> 6; int k = rem % 3; int ci = rem / 3;
    w2s[(ci*3 + k)*64 + co] = c2w[((s*C2N + co)*C1N + ci)*3 + k];
  }

  const float* xg = sens + (size_t)(s*NB + b)*LIN;
  const float bnr = rsqrtf(1.0f + 1e-5f);

  {
    const int c = tid & 31;
    const int l0 = tid >> 5;
    const float w0 = c1w[(s*C1N + c)*5 + 0];
    const float w1 = c1w[(s*C1N + c)*5 + 1];
    const float w2 = c1w[(s*C1N + c)*5 + 2];
    const float w3 = c1w[(s*C1N + c)*5 + 3];
    const float w4 = c1w[(s*C1N + c)*5 + 4];
    const float cb = c1b[s*C1N + c];
    const float sc = bn1g[s*C1N + c]*bnr;
    const float bt = bn1b[s*C1N + c];
    for (int l = l0; l < LP1; l += 8) {
      const int base = 4*l;
      float xm2 = (base-2 >= 0) ? xg[base-2] : 0.f;
      float xm1 = (base-1 >= 0) ? xg[base-1] : 0.f;
      float x0v = xg[base+0];
      float x1v = xg[base+1];
      float x2v = xg[base+2];
      float x3v = xg[base+3];
      float x4v = (base+4 < LIN) ? xg[base+4] : 0.f;
      float y0 = w0*xm2 + w1*xm1 + w2*x0v + w3*x1v + w4*x2v;
      float y1 = w0*x0v + w1*x1v + w2*x2v + w3*x3v + w4*x4v;
      y0 = (y0 + cb)*sc + bt;
      y1 = (y1 + cb)*sc + bt;
      h1p[c][l+1] = __float2half(fmaxf(fmaxf(y0, y1), 0.f));
      if (l == 0)      h1p[c][0]      = __float2half(0.f);
      if (l == LP1-1)  h1p[c][LP1+1]  = __float2half(0.f);
    }
  }
  __syncthreads();

  const int rg = tid & 31, cg = tid >> 5;
  const int c0 = cg*8;
  float cb2[8], sc2[8], bt2[8];
  #pragma unroll
  for (int cc = 0; cc < 8; ++cc) {
    cb2[cc] = c2b[s*C2N + c0 + cc];
    sc2[cc] = bn2g[s*C2N + c0 + cc]*bnr;
    bt2[cc] = bn2b[s*C2N + c0 + cc];
  }
  for (int it = 0; it < 4; ++it) {
    const int rA = 64*it + rg;
    const int rB = rA + 32;
    float acc[2][2][8] = {};
    for (int ci = 0; ci < C1N; ++ci) {
      const __half2 a01 = *(const __half2*)&h1p[ci][2*rA];
      const __half2 a23 = *(const __half2*)&h1p[ci][2*rA+2];
      const __half2 b01 = *(const __half2*)&h1p[ci][2*rB];
      const __half2 b23 = *(const __half2*)&h1p[ci][2*rB+2];
      const float hA[4] = { __low2float(a01), __high2float(a01), __low2float(a23), __high2float(a23) };
      const float hB[4] = { __low2float(b01), __high2float(b01), __low2float(b23), __high2float(b23) };
      #pragma unroll
      for (int k = 0; k < 3; ++k) {
        const float4 wv0 = *(const float4*)&w2s[(ci*3+k)*64 + c0];
        const float4 wv1 = *(const float4*)&w2s[(ci*3+k)*64 + c0 + 4];
        const float wr[8] = {wv0.x, wv0.y, wv0.z, wv0.w, wv1.x, wv1.y, wv1.z, wv1.w};
        #pragma unroll
        for (int p = 0; p < 2; ++p) {
          const float xa = hA[k+p];
          const float xb = hB[k+p];
          #pragma unroll
          for (int cc = 0; cc < 8; ++cc) {
            acc[0][p][cc] = fmaf(wr[cc], xa, acc[0][p][cc]);
            acc[1][p][cc] = fmaf(wr[cc], xb, acc[1][p][cc]);
          }
        }
      }
    }
    #pragma unroll
    for (int rr = 0; rr < 2; ++rr) {
      const int r = rr ? rB : rA;
      float* outp = x0 + ((size_t)bid*SEQ + r)*DM + c0;
      #pragma unroll
      for (int cc = 0; cc < 8; ++cc) {
        float v0 = (acc[rr][0][cc] + cb2[cc])*sc2[cc] + bt2[cc];
        float v1 = (acc[rr][1][cc] + cb2[cc])*sc2[cc] + bt2[cc];
        float v = fmaxf(fmaxf(v0, v1), 0.f);
        const int d = c0 + cc;
        const float ang = (float)r * __expf(-0.14391156463f*(float)(d & ~1));
        const float pe = (d & 1) ? cosf(ang) : sinf(ang);
        outp[cc] = v + pe;
      }
    }
  }
}

// ---------------- transformer kernel v9: MFMA, 1024 threads = 16 waves ----------------
// LDS: xs[256][64]f16 | Qb (att overlays) | Kb | Vt[64][256]f16 | ffs 16*768B | red 1KB
__global__ __launch_bounds__(1024, 1) void tx_kernel(
  const float* __restrict__ x0, float* __restrict__ nf,
  const unsigned short* __restrict__ w16,
  const float* __restrict__ bqkv, const float* __restrict__ bo,
  const float* __restrict__ ln1g, const float* __restrict__ ln1b,
  const float* __restrict__ fb1,  const float* __restrict__ fb2,
  const float* __restrict__ ln2g, const float* __restrict__ ln2b)
{
  __shared__ char smem[144384];
  char* xs = smem;
  char* Qb = smem + 32768;
  char* Kb = smem + 65536;
  char* Vt = smem + 98304;
  char* ffs = smem + 131072;                     // 16 waves * 768 B
  float* red = (float*)(smem + 131072 + 12288);

  const int bid = blockIdx.x;
  const int s = bid >> 6, b = bid & 63;
  const int t = threadIdx.x;
  const int l = t & 63, w = t >> 6;              // wave id 0..15
  const int g = l >> 4, c = l & 15;
  const int m0 = w * 16;                         // wave owns rows m0..m0+15
  const float qs = 0.35355339059327373f * 1.4426950408889634f; // 1/sqrt(8)*log2(e)

  // ---- x0 -> xs (fp16, swizzled): each thread loads 16 dims of one row ----
  {
    const int r = t >> 2, qd = t & 3;
    const float* xp = x0 + ((size_t)bid*SEQ + r)*DM + qd*16;
    float4 a0 = *(const float4*)(xp + 0);
    float4 a1 = *(const float4*)(xp + 4);
    float4 a2 = *(const float4*)(xp + 8);
    float4 a3 = *(const float4*)(xp + 12);
    pack8(swp(xs, r, 128, qd*32), a0, a1);
    pack8(swp(xs, r, 128, qd*32 + 16), a2, a3);
  }
  __syncthreads();

  for (int layer = 0; layer < 2; ++layer) {
    const int wi = s*2 + layer;
    const unsigned short* wq = w16 + (size_t)wi*49152;
    const unsigned short* wo = wq + 12288;
    const unsigned short* w1 = wq + 16384;
    const unsigned short* w2 = wq + 32768;
    const float* Bq  = bqkv + wi*192;
    const float* Bo  = bo   + wi*64;
    const float* G1  = ln1g + wi*64; const float* B1 = ln1b + wi*64;
    const float* Bf1 = fb1  + wi*256; const float* Bf2 = fb2 + wi*64;
    const float* G2  = ln2g + wi*64; const float* B2 = ln2b + wi*64;

    // ======== QKV projections (wave owns 16 rows) ========
    {
      f16x8 a0 = *(const f16x8*)swp(xs, m0+c, 128, 0  + g*16);
      f16x8 a1 = *(const f16x8*)swp(xs, m0+c, 128, 64 + g*16);
      // K -> Kb row-major
      #pragma unroll
      for (int nt = 0; nt < 4; ++nt) {
        const int row = 64 + nt*16 + c;
        f16x8 b0 = *(const f16x8*)(wq + row*64 + 8*g);
        f16x8 b1 = *(const f16x8*)(wq + row*64 + 32 + 8*g);
        f32x4 d = {0.f,0.f,0.f,0.f};
        d = MFMA32(a0, b0, d); d = MFMA32(a1, b1, d);
        const float bias = Bq[64 + nt*16 + c];
        #pragma unroll
        for (int i = 0; i < 4; ++i) sw_h(Kb, m0+4*g+i, 128, nt*16+c, d[i] + bias);
      }
      // Q (scaled) -> Qb row-major
      #pragma unroll
      for (int nt = 0; nt < 4; ++nt) {
        const int row = nt*16 + c;
        f16x8 b0 = *(const f16x8*)(wq + row*64 + 8*g);
        f16x8 b1 = *(const f16x8*)(wq + row*64 + 32 + 8*g);
        f32x4 d = {0.f,0.f,0.f,0.f};
        d = MFMA32(a0, b0, d); d = MFMA32(a1, b1, d);
        const float bias = Bq[nt*16 + c];
        #pragma unroll
        for (int i = 0; i < 4; ++i) sw_h(Qb, m0+4*g+i, 128, nt*16+c, (d[i] + bias)*qs);
      }
      // V -> Vt transposed [dim][j]
      #pragma unroll
      for (int nt = 0; nt < 4; ++nt) {
        const int row = 128 + nt*16 + c;
        f16x8 b0 = *(const f16x8*)(wq + row*64 + 8*g);
        f16x8 b1 = *(const f16x8*)(wq + row*64 + 32 + 8*g);
        f32x4 d = {0.f,0.f,0.f,0.f};
        d = MFMA32(a0, b0, d); d = MFMA32(a1, b1, d);
        const float bias = Bq[128 + nt*16 + c];
        #pragma unroll
        for (int i = 0; i < 4; ++i) sw_h(Vt, nt*16+c, 512, m0+4*g+i, d[i] + bias);
      }
    }
    __syncthreads();   // (a) Q/K/Vt visible to all

    // ======== attention: 8 tasks = 8 heads over own 16 q-rows ========
    unsigned pk0[8], pk1[8];
    #pragma unroll
    for (int task = 0; task < 8; ++task) {
      const int h = task;
      f16x4 qb = {0,0,0,0};
      if (g < 2) qb = *(const f16x4*)swp(Qb, m0+c, 128, 16*h + 8*g);
      f32x4 o = {0.f,0.f,0.f,0.f};
      #pragma unroll 2
      for (int jt = 0; jt < 16; ++jt) {
        f16x4 ka = {0,0,0,0};
        if (g < 2) ka = *(const f16x4*)swp(Kb, jt*16+c, 128, 16*h + 8*g);
        f32x4 st = {0.f,0.f,0.f,0.f};
        st = MFMA16(ka, qb, st);            // S^T tile: lane holds S^T[jt*16+4g+i][m0+c]
        __half2 plo = __floats2half2_rn(exp2f(st[0]), exp2f(st[1]));
        __half2 phi = __floats2half2_rn(exp2f(st[2]), exp2f(st[3]));
        uint2 pu; pu.x = *(unsigned*)&plo; pu.y = *(unsigned*)&phi;
        f16x4 pb = *(f16x4*)&pu;
        f16x4 va;
        if (c < 8) va = *(const f16x4*)swp(Vt, 8*h+c, 512, jt*32 + (g>>1)*16 + (g&1)*8);
        else { va[0]=(_Float16)1.f; va[1]=(_Float16)1.f; va[2]=(_Float16)1.f; va[3]=(_Float16)1.f; }
        o = MFMA16(va, pb, o);              // O^T: rows d' (c<8), row8 = denom
      }
      const float den = __shfl(o[0], 32 + c, 64);
      const float rinv = 1.0f / den;
      __half2 lo = __floats2half2_rn(o[0]*rinv, o[1]*rinv);
      __half2 hi = __floats2half2_rn(o[2]*rinv, o[3]*rinv);
      pk0[task] = *(unsigned*)&lo;
      pk1[task] = *(unsigned*)&hi;
    }
    __syncthreads();   // (b) all K/Vt/Q reads complete

    // write att (overlays Qb; own rows only)
    #pragma unroll
    for (int task = 0; task < 8; ++task) {
      if (g < 2) {
        uint2 u; u.x = pk0[task]; u.y = pk1[task];
        *(uint2*)swp(Qb, m0+c, 128, 16*task + 8*g) = u;
      }
    }

    // ======== O-projection + residual + LN1 (own rows; no barrier needed) ========
    {
      f16x8 a0 = *(const f16x8*)swp(Qb, m0+c, 128, 0  + g*16);
      f16x8 a1 = *(const f16x8*)swp(Qb, m0+c, 128, 64 + g*16);
      float vals[4][4];
      #pragma unroll
      for (int nt = 0; nt < 4; ++nt) {
        const int row = nt*16 + c;
        f16x8 b0 = *(const f16x8*)(wo + row*64 + 8*g);
        f16x8 b1 = *(const f16x8*)(wo + row*64 + 32 + 8*g);
        f32x4 d = {0.f,0.f,0.f,0.f};
        d = MFMA32(a0, b0, d); d = MFMA32(a1, b1, d);
        const float bias = Bo[nt*16 + c];
        #pragma unroll
        for (int i = 0; i < 4; ++i)
          vals[nt][i] = d[i] + bias + sr_h(xs, m0+4*g+i, 128, nt*16+c);
      }
      float mean[4], rstd[4];
      #pragma unroll
      for (int i = 0; i < 4; ++i) {
        float p1 = vals[0][i]+vals[1][i]+vals[2][i]+vals[3][i];
        float p2 = fmaf(vals[0][i],vals[0][i], fmaf(vals[1][i],vals[1][i],
                   fmaf(vals[2][i],vals[2][i], vals[3][i]*vals[3][i])));
        p1 += __shfl_xor(p1,1,16); p1 += __shfl_xor(p1,2,16); p1 += __shfl_xor(p1,4,16); p1 += __shfl_xor(p1,8,16);
        p2 += __shfl_xor(p2,1,16); p2 += __shfl_xor(p2,2,16); p2 += __shfl_xor(p2,4,16); p2 += __shfl_xor(p2,8,16);
        mean[i] = p1*(1.0f/64.0f);
        rstd[i] = rsqrtf(p2*(1.0f/64.0f) - mean[i]*mean[i] + 1e-5f);
      }
      #pragma unroll
      for (int nt = 0; nt < 4; ++nt) {
        const float gg = G1[nt*16+c], bb = B1[nt*16+c];
        #pragma unroll
        for (int i = 0; i < 4; ++i)
          sw_h(xs, m0+4*g+i, 128, nt*16+c, (vals[nt][i]-mean[i])*rstd[i]*gg + bb);
      }
    }

    // ======== FF fused (own rows) ========
    {
      char* tile = ffs + w*768;
      f32x4 o2[4];
      #pragma unroll
      for (int nt2 = 0; nt2 < 4; ++nt2) { o2[nt2][0]=0.f; o2[nt2][1]=0.f; o2[nt2][2]=0.f; o2[nt2][3]=0.f; }
      f16x8 xa0 = *(const f16x8*)swp(xs, m0+c, 128, 0  + g*16);
      f16x8 xa1 = *(const f16x8*)swp(xs, m0+c, 128, 64 + g*16);
      for (int ht = 0; ht < 16; ++ht) {
        const int hrow = ht*16 + c;
        f16x8 b0 = *(const f16x8*)(w1 + hrow*64 + 8*g);
        f16x8 b1 = *(const f16x8*)(w1 + hrow*64 + 32 + 8*g);
        f32x4 d = {0.f,0.f,0.f,0.f};
        d = MFMA32(xa0, b0, d); d = MFMA32(xa1, b1, d);
        const float bias = Bf1[ht*16 + c];
        #pragma unroll
        for (int i = 0; i < 4; ++i) {
          float hv = d[i] + bias;
          hv = 0.5f*hv*(1.0f + erff(hv*0.70710678118654752f));
          *(_Float16*)(tile + (4*g+i)*48 + c*2) = (_Float16)hv;   // tile[qloc][hloc], pad 24
        }
        f16x4 a2 = *(const f16x4*)(tile + c*48 + 8*g);            // tile[c][4g..4g+3]
        #pragma unroll
        for (int nt2 = 0; nt2 < 4; ++nt2) {
          f16x4 b2 = *(const f16x4*)(w2 + (nt2*16+c)*256 + ht*16 + 4*g);
          o2[nt2] = MFMA16(a2, b2, o2[nt2]);
        }
      }
      float vals[4][4];
      #pragma unroll
      for (int nt2 = 0; nt2 < 4; ++nt2) {
        const float bias = Bf2[nt2*16 + c];
        #pragma unroll
        for (int i = 0; i < 4; ++i)
          vals[nt2][i] = o2[nt2][i] + bias + sr_h(xs, m0+4*g+i, 128, nt2*16+c);
      }
      float mean[4], rstd[4];
      #pragma unroll
      for (int i = 0; i < 4; ++i) {
        float p1 = vals[0][i]+vals[1][i]+vals[2][i]+vals[3][i];
        float p2 = fmaf(vals[0][i],vals[0][i], fmaf(vals[1][i],vals[1][i],
                   fmaf(vals[2][i],vals[2][i], vals[3][i]*vals[3][i])));
        p1 += __shfl_xor(p1,1,16); p1 += __shfl_xor(p1,2,16); p1 += __shfl_xor(p1,4,16); p1 += __shfl_xor(p1,8,16);
        p2 += __shfl_xor(p2,1,16); p2 += __shfl_xor(p2,2,16); p2 += __shfl_xor(p2,4,16); p2 += __shfl_xor(p2,8,16);
        mean[i] = p1*(1.0f/64.0f);
        rstd[i] = rsqrtf(p2*(1.0f/64.0f) - mean[i]*mean[i] + 1e-5f);
      }
      #pragma unroll
      for (int nt2 = 0; nt2 < 4; ++nt2) {
        const float gg = G2[nt2*16+c], bb = B2[nt2*16+c];
        #pragma unroll
        for (int i = 0; i < 4; ++i)
          sw_h(xs, m0+4*g+i, 128, nt2*16+c, (vals[nt2][i]-mean[i])*rstd[i]*gg + bb);
      }
    }
    // next layer's projections read only own rows; barrier (a) covers cross-wave reads
  }

  // ---- mean over sequence -> nf ----
  __syncthreads();
  if (t < 256) {
    const int d = t & 63, qu = t >> 6;
    float sm = 0.f;
    for (int rr = qu*64; rr < qu*64 + 64; ++rr) sm += sr_h(xs, rr, 128, d);
    red[qu*64 + d] = sm;
  }
  __syncthreads();
  if (t < 64) {
    float sm = red[t] + red[64+t] + red[128+t] + red[192+t];
    nf[((size_t)b*4 + s)*64 + t] = sm * (1.0f/256.0f);
  }
}

// ------------------------- graph head kernel (unchanged) -------------------------
__global__ __launch_bounds__(128) void head_kernel(
  const float* __restrict__ nf,
  const float* __restrict__ ws_w, const float* __restrict__ ws_b,
  const float* __restrict__ b_s,  const float* __restrict__ lambda_init,
  const float* __restrict__ mc_w1, const float* __restrict__ mc_b1,
  const float* __restrict__ mc_w2, const float* __restrict__ mc_b2,
  const float* __restrict__ g1w, const float* __restrict__ g1b,
  const float* __restrict__ g2w, const float* __restrict__ g2b,
  const float* __restrict__ cw1, const float* __restrict__ cb1,
  const float* __restrict__ cw2, const float* __restrict__ cb2,
  float* __restrict__ out)
{
  const int b = blockIdx.x, t = threadIdx.x;
  __shared__ float nfb[256];
  __shared__ float meannf[64];
  __shared__ float fafb[8];
  __shared__ float z1[32];
  __shared__ float normM[16];
  __shared__ float rs[4];
  __shared__ float xw[512];
  __shared__ float hmat[512];
  __shared__ float hw[1024];
  __shared__ float gv[256];
  __shared__ float r1[128];

  for (int i = t; i < 256; i += 128) nfb[i] = nf[b*256 + i];
  __syncthreads();
  if (t < 8) {
    const int i = t & 3;
    const float* w = ws_w + (t >> 2)*64;
    float acc = 0.f;
    for (int c = 0; c < 64; ++c) acc = fmaf(nfb[i*64+c], w[c], acc);
    fafb[t] = acc;
  }
  if (t >= 64 && t < 128) {
    const int d = t - 64;
    meannf[d] = 0.25f*(nfb[d] + nfb[64+d] + nfb[128+d] + nfb[192+d]);
  }
  __syncthreads();
  if (t < 32) {
    float acc = mc_b1[t];
    const float* w = mc_w1 + t*64;
    for (int c = 0; c < 64; ++c) acc = fmaf(meannf[c], w[c], acc);
    z1[t] = fmaxf(acc, 0.f);
  }
  __syncthreads();
  if (t == 0) {
    float li = mc_b2[0];
    for (int k = 0; k < 32; ++k) li = fmaf(z1[k], mc_w2[k], li);
    const float lam = (1.0f/(1.0f + __expf(-li))) * lambda_init[0];
    const float AB[4][4] = {{1,1,0,0},{1,1,1,1},{0,1,1,1},{0,1,1,1}};
    const float add = ws_b[0] + b_s[0];
    float sM[4][4], deg[4];
    for (int i = 0; i < 4; ++i) {
      float d_ = 0.f;
      for (int j = 0; j < 4; ++j) {
        sM[i][j] = 1.0f/(1.0f + __expf(-(fafb[i] + fafb[4+j] + add)));
        d_ += sM[i][j];
      }
      deg[i] = d_;
    }
    float A[4][4], dinv[4];
    for (int i = 0; i < 4; ++i)
      for (int j = 0; j < 4; ++j) {
        const float a_ = sM[i][j] / (deg[j] + 1e-8f);
        const float sh = fmaxf(a_ * AB[i][j], 0.f);
        A[i][j] = lam*((i==j) ? 1.f : 0.f) + (1.0f - lam)*sh;
      }
    for (int j = 0; j < 4; ++j) {
      float d_ = 0.f;
      for (int i = 0; i < 4; ++i) d_ += A[i][j];
      dinv[j] = (d_ > 0.f) ? rsqrtf(d_) : 0.f;
    }
    for (int i = 0; i < 4; ++i) {
      float r_ = 0.f;
      for (int j = 0; j < 4; ++j) {
        const float n_ = dinv[i]*A[i][j]*dinv[j];
        normM[i*4+j] = n_;
        r_ += n_;
      }
      rs[i] = r_;
    }
  }
  __syncthreads();
  for (int idx = t; idx < 512; idx += 128) {
    const int i = idx >> 7, f = idx & 127;
    float acc = 0.f;
    for (int c = 0; c < 64; ++c) acc = fmaf(nfb[i*64+c], g1w[c*128 + f], acc);
    xw[idx] = acc;
  }
  __syncthreads();
  for (int idx = t; idx < 512; idx += 128) {
    const int j = idx >> 7, f = idx & 127;
    float acc = g1b[f];
    #pragma unroll
    for (int i = 0; i < 4; ++i) acc = fmaf(normM[i*4+j], xw[i*128+f], acc);
    hmat[j*128+f] = fmaxf(acc, 0.f);
  }
  __syncthreads();
  for (int idx = t; idx < 1024; idx += 128) {
    const int i = idx >> 8, f = idx & 255;
    float acc = 0.f;
    for (int c = 0; c < 128; ++c) acc = fmaf(hmat[i*128+c], g2w[c*256+f], acc);
    hw[idx] = acc;
  }
  __syncthreads();
  for (int f = t; f < 256; f += 128) {
    float acc = 0.f;
    #pragma unroll
    for (int i = 0; i < 4; ++i) acc = fmaf(rs[i], hw[i*256+f], acc);
    gv[f] = 0.25f*acc + g2b[f];
  }
  __syncthreads();
  if (t < 128) {
    float acc = cb1[t];
    for (int c = 0; c < 256; ++c) acc = fmaf(gv[c], cw1[c*128+t], acc);
    r1[t] = fmaxf(acc, 0.f);
  }
  __syncthreads();
  if (t < 5) {
    float acc = cb2[t];
    for (int k = 0; k < 128; ++k) acc = fmaf(r1[k], cw2[k*5 + t], acc);
    out[b*5 + t] = acc;
  }
}

// ------------------------- launch -------------------------
extern "C" void kernel_launch(void* const* d_in, const int* in_sizes, int n_in,
                              void* d_out, int out_size, void* d_ws, size_t ws_size,
                              hipStream_t stream) {
  (void)in_sizes; (void)n_in; (void)out_size; (void)ws_size;
  const float* sens   = (const float*)d_in[0];
  const float* c1w    = (const float*)d_in[1];
  const float* c1b    = (const float*)d_in[2];
  const float* bn1g   = (const float*)d_in[3];
  const float* bn1b   = (const float*)d_in[4];
  const float* c2w    = (const float*)d_in[5];
  const float* c2b    = (const float*)d_in[6];
  const float* bn2g   = (const float*)d_in[7];
  const float* bn2b   = (const float*)d_in[8];
  const float* wqkv   = (const float*)d_in[9];
  const float* bqkv   = (const float*)d_in[10];
  const float* wo     = (const float*)d_in[11];
  const float* bo     = (const float*)d_in[12];
  const float* ln1g   = (const float*)d_in[13];
  const float* ln1b   = (const float*)d_in[14];
  const float* fw1    = (const float*)d_in[15];
  const float* fb1    = (const float*)d_in[16];
  const float* fw2    = (const float*)d_in[17];
  const float* fb2    = (const float*)d_in[18];
  const float* ln2g   = (const float*)d_in[19];
  const float* ln2b   = (const float*)d_in[20];
  const float* ws_w   = (const float*)d_in[21];
  const float* ws_b   = (const float*)d_in[22];
  const float* b_s    = (const float*)d_in[23];
  const float* lam0   = (const float*)d_in[24];
  const float* mc_w1  = (const float*)d_in[25];
  const float* mc_b1  = (const float*)d_in[26];
  const float* mc_w2  = (const float*)d_in[27];
  const float* mc_b2  = (const float*)d_in[28];
  const float* g1w    = (const float*)d_in[29];
  const float* g1b    = (const float*)d_in[30];
  const float* g2w    = (const float*)d_in[31];
  const float* g2b    = (const float*)d_in[32];
  const float* cw1    = (const float*)d_in[33];
  const float* cb1    = (const float*)d_in[34];
  const float* cw2    = (const float*)d_in[35];
  const float* cb2    = (const float*)d_in[36];

  float*          x0  = (float*)d_ws;                                        // 16 MiB
  float*          nf  = (float*)((char*)d_ws + (size_t)NSENS*NB*SEQ*DM*4);   // 64 KiB
  unsigned short* w16 = (unsigned short*)((char*)d_ws + (size_t)NSENS*NB*SEQ*DM*4 + 65536); // 768 KiB

  wprep_kernel<<<8, 256, 0, stream>>>(wqkv, wo, fw1, fw2, w16);
  conv_kernel<<<NSENS*NB, 256, 0, stream>>>(sens, c1w, c1b, bn1g, bn1b,
                                            c2w, c2b, bn2g, bn2b, x0);
  tx_kernel<<<NSENS*NB, 1024, 0, stream>>>(x0, nf, w16, bqkv, bo,
                                           ln1g, ln1b, fb1, fb2, ln2g, ln2b);
  head_kernel<<<NB, 128, 0, stream>>>(nf, ws_w, ws_b, b_s, lam0,
                                      mc_w1, mc_b1, mc_w2, mc_b2,
                                      g1w, g1b, g2w, g2b, cw1, cb1, cw2, cb2,
                                      (float*)d_out);
}

// Round 12
// 324.386 us; speedup vs baseline: 3.0877x; 1.0926x over previous
//
#include <hip/hip_runtime.h>
#include <hip/hip_fp16.h>

#define NSENS 4
#define NB    64
#define LIN   2048
#define C1N   32
#define LP1   512
#define C2N   64
#define SEQ   256
#define DM    64
#define H1S   516

typedef _Float16 f16x4 __attribute__((ext_vector_type(4)));
typedef _Float16 f16x8 __attribute__((ext_vector_type(8)));
typedef float    f32x4 __attribute__((ext_vector_type(4)));

#define MFMA16(A,B,C) __builtin_amdgcn_mfma_f32_16x16x16f16((A),(B),(C),0,0,0)
#define MFMA32(A,B,C) __builtin_amdgcn_mfma_f32_16x16x32_f16((A),(B),(C),0,0,0)

// swizzled LDS addressing: 16B-chunk XOR by (row&7)<<4
__device__ __forceinline__ char* swp(char* base, int row, int stride, int byteoff) {
  return base + row*stride + ((byteoff & ~15) ^ ((row & 7) << 4)) + (byteoff & 15);
}
__device__ __forceinline__ float sr_h(char* base, int row, int stride, int col) {
  return (float)*(const _Float16*)swp(base, row, stride, col*2);
}
__device__ __forceinline__ void pack8(char* p, float4 a, float4 b) {
  __half2 h0 = __floats2half2_rn(a.x,a.y), h1 = __floats2half2_rn(a.z,a.w);
  __half2 h2 = __floats2half2_rn(b.x,b.y), h3 = __floats2half2_rn(b.z,b.w);
  uint4 u; u.x=*(unsigned*)&h0; u.y=*(unsigned*)&h1; u.z=*(unsigned*)&h2; u.w=*(unsigned*)&h3;
  *(uint4*)p = u;
}
__device__ __forceinline__ uint2 pack4u(float a, float b, float cc, float d) {
  __half2 h0 = __floats2half2_rn(a, b), h1 = __floats2half2_rn(cc, d);
  uint2 u; u.x = *(unsigned*)&h0; u.y = *(unsigned*)&h1; return u;
}

// ---------------- weight pack: fp32 -> fp16 row-major ----------------
__global__ __launch_bounds__(256) void wprep_kernel(
    const float* __restrict__ wqkv, const float* __restrict__ wo,
    const float* __restrict__ fw1,  const float* __restrict__ fw2,
    unsigned short* __restrict__ w16)
{
  const int wi = blockIdx.x;
  unsigned short* dst = w16 + (size_t)wi*49152;
  const float* s0 = wqkv + (size_t)wi*12288;
  const float* s1 = wo   + (size_t)wi*4096;
  const float* s2 = fw1  + (size_t)wi*16384;
  const float* s3 = fw2  + (size_t)wi*16384;
  for (int i = threadIdx.x; i < 12288; i += 256) { __half h = __float2half_rn(s0[i]); dst[i]       = *(unsigned short*)&h; }
  for (int i = threadIdx.x; i < 4096;  i += 256) { __half h = __float2half_rn(s1[i]); dst[12288+i] = *(unsigned short*)&h; }
  for (int i = threadIdx.x; i < 16384; i += 256) { __half h = __float2half_rn(s2[i]); dst[16384+i] = *(unsigned short*)&h; }
  for (int i = threadIdx.x; i < 16384; i += 256) { __half h = __float2half_rn(s3[i]); dst[32768+i] = *(unsigned short*)&h; }
}

// ------------------------- conv branch kernel (unchanged) -------------------------
__global__ __launch_bounds__(256) void conv_kernel(
    const float* __restrict__ sens,
    const float* __restrict__ c1w, const float* __restrict__ c1b,
    const float* __restrict__ bn1g, const float* __restrict__ bn1b,
    const float* __restrict__ c2w, const float* __restrict__ c2b,
    const float* __restrict__ bn2g, const float* __restrict__ bn2b,
    float* __restrict__ x0)
{
  const int bid = blockIdx.x;
  const int s = bid >> 6, b = bid & 63;
  const int tid = threadIdx.x;
  __shared__ __half h1p[C1N][H1S];
  __shared__ float w2s[C1N*3*C2N];

  for (int i = tid; i < C1N*3*C2N; i += 256) {
    int co = i & 63; int rem = i >> 6; int k = rem % 3; int ci = rem / 3;
    w2s[(ci*3 + k)*64 + co] = c2w[((s*C2N + co)*C1N + ci)*3 + k];
  }

  const float* xg = sens + (size_t)(s*NB + b)*LIN;
  const float bnr = rsqrtf(1.0f + 1e-5f);

  {
    const int c = tid & 31;
    const int l0 = tid >> 5;
    const float w0 = c1w[(s*C1N + c)*5 + 0];
    const float w1 = c1w[(s*C1N + c)*5 + 1];
    const float w2 = c1w[(s*C1N + c)*5 + 2];
    const float w3 = c1w[(s*C1N + c)*5 + 3];
    const float w4 = c1w[(s*C1N + c)*5 + 4];
    const float cb = c1b[s*C1N + c];
    const float sc = bn1g[s*C1N + c]*bnr;
    const float bt = bn1b[s*C1N + c];
    for (int l = l0; l < LP1; l += 8) {
      const int base = 4*l;
      float xm2 = (base-2 >= 0) ? xg[base-2] : 0.f;
      float xm1 = (base-1 >= 0) ? xg[base-1] : 0.f;
      float x0v = xg[base+0];
      float x1v = xg[base+1];
      float x2v = xg[base+2];
      float x3v = xg[base+3];
      float x4v = (base+4 < LIN) ? xg[base+4] : 0.f;
      float y0 = w0*xm2 + w1*xm1 + w2*x0v + w3*x1v + w4*x2v;
      float y1 = w0*x0v + w1*x1v + w2*x2v + w3*x3v + w4*x4v;
      y0 = (y0 + cb)*sc + bt;
      y1 = (y1 + cb)*sc + bt;
      h1p[c][l+1] = __float2half(fmaxf(fmaxf(y0, y1), 0.f));
      if (l == 0)      h1p[c][0]      = __float2half(0.f);
      if (l == LP1-1)  h1p[c][LP1+1]  = __float2half(0.f);
    }
  }
  __syncthreads();

  const int rg = tid & 31, cg = tid >> 5;
  const int c0 = cg*8;
  float cb2[8], sc2[8], bt2[8];
  #pragma unroll
  for (int cc = 0; cc < 8; ++cc) {
    cb2[cc] = c2b[s*C2N + c0 + cc];
    sc2[cc] = bn2g[s*C2N + c0 + cc]*bnr;
    bt2[cc] = bn2b[s*C2N + c0 + cc];
  }
  for (int it = 0; it < 4; ++it) {
    const int rA = 64*it + rg;
    const int rB = rA + 32;
    float acc[2][2][8] = {};
    for (int ci = 0; ci < C1N; ++ci) {
      const __half2 a01 = *(const __half2*)&h1p[ci][2*rA];
      const __half2 a23 = *(const __half2*)&h1p[ci][2*rA+2];
      const __half2 b01 = *(const __half2*)&h1p[ci][2*rB];
      const __half2 b23 = *(const __half2*)&h1p[ci][2*rB+2];
      const float hA[4] = { __low2float(a01), __high2float(a01), __low2float(a23), __high2float(a23) };
      const float hB[4] = { __low2float(b01), __high2float(b01), __low2float(b23), __high2float(b23) };
      #pragma unroll
      for (int k = 0; k < 3; ++k) {
        const float4 wv0 = *(const float4*)&w2s[(ci*3+k)*64 + c0];
        const float4 wv1 = *(const float4*)&w2s[(ci*3+k)*64 + c0 + 4];
        const float wr[8] = {wv0.x, wv0.y, wv0.z, wv0.w, wv1.x, wv1.y, wv1.z, wv1.w};
        #pragma unroll
        for (int p = 0; p < 2; ++p) {
          const float xa = hA[k+p];
          const float xb = hB[k+p];
          #pragma unroll
          for (int cc = 0; cc < 8; ++cc) {
            acc[0][p][cc] = fmaf(wr[cc], xa, acc[0][p][cc]);
            acc[1][p][cc] = fmaf(wr[cc], xb, acc[1][p][cc]);
          }
        }
      }
    }
    #pragma unroll
    for (int rr = 0; rr < 2; ++rr) {
      const int r = rr ? rB : rA;
      float* outp = x0 + ((size_t)bid*SEQ + r)*DM + c0;
      #pragma unroll
      for (int cc = 0; cc < 8; ++cc) {
        float v0 = (acc[rr][0][cc] + cb2[cc])*sc2[cc] + bt2[cc];
        float v1 = (acc[rr][1][cc] + cb2[cc])*sc2[cc] + bt2[cc];
        float v = fmaxf(fmaxf(v0, v1), 0.f);
        const int d = c0 + cc;
        const float ang = (float)r * __expf(-0.14391156463f*(float)(d & ~1));
        const float pe = (d & 1) ? cosf(ang) : sinf(ang);
        outp[cc] = v + pe;
      }
    }
  }
}

// ---------------- transformer kernel v10: operand-swapped MFMA, 16 waves ----------------
// LDS: xs[256][64]f16 | Qb | Kb | Vt[64][256]f16 | red 1KB   (FF tile eliminated)
__global__ __launch_bounds__(1024, 1) void tx_kernel(
  const float* __restrict__ x0, float* __restrict__ nf,
  const unsigned short* __restrict__ w16,
  const float* __restrict__ bqkv, const float* __restrict__ bo,
  const float* __restrict__ ln1g, const float* __restrict__ ln1b,
  const float* __restrict__ fb1,  const float* __restrict__ fb2,
  const float* __restrict__ ln2g, const float* __restrict__ ln2b)
{
  __shared__ char smem[132096];
  char* xs = smem;
  char* Qb = smem + 32768;
  char* Kb = smem + 65536;
  char* Vt = smem + 98304;
  float* red = (float*)(smem + 131072);

  const int bid = blockIdx.x;
  const int s = bid >> 6, b = bid & 63;
  const int t = threadIdx.x;
  const int l = t & 63, w = t >> 6;              // wave id 0..15
  const int g = l >> 4, c = l & 15;
  const int m0 = w * 16;                         // wave owns rows m0..m0+15
  const float qs = 0.35355339059327373f * 1.4426950408889634f; // 1/sqrt(8)*log2(e)

  // ---- x0 -> xs (fp16, swizzled) ----
  {
    const int r = t >> 2, qd = t & 3;
    const float* xp = x0 + ((size_t)bid*SEQ + r)*DM + qd*16;
    float4 a0 = *(const float4*)(xp + 0);
    float4 a1 = *(const float4*)(xp + 4);
    float4 a2 = *(const float4*)(xp + 8);
    float4 a3 = *(const float4*)(xp + 12);
    pack8(swp(xs, r, 128, qd*32), a0, a1);
    pack8(swp(xs, r, 128, qd*32 + 16), a2, a3);
  }
  __syncthreads();

  for (int layer = 0; layer < 2; ++layer) {
    const int wi = s*2 + layer;
    const unsigned short* wq = w16 + (size_t)wi*49152;
    const unsigned short* wo = wq + 12288;
    const unsigned short* w1 = wq + 16384;
    const unsigned short* w2 = wq + 32768;
    const float* Bq  = bqkv + wi*192;
    const float* Bo  = bo   + wi*64;
    const float* G1  = ln1g + wi*64; const float* B1 = ln1b + wi*64;
    const float* Bf1 = fb1  + wi*256; const float* Bf2 = fb2 + wi*64;
    const float* G2  = ln2g + wi*64; const float* B2 = ln2b + wi*64;

    // ======== QKV projections ========
    {
      f16x8 xf0 = *(const f16x8*)swp(xs, m0+c, 128, 0  + g*16);
      f16x8 xf1 = *(const f16x8*)swp(xs, m0+c, 128, 64 + g*16);
      // K: A=weights, B=x -> lane holds (dims nt*16+4g..+3, seq m0+c) -> 8B write
      #pragma unroll
      for (int nt = 0; nt < 4; ++nt) {
        const int row = 64 + nt*16 + c;
        f16x8 w0f = *(const f16x8*)(wq + row*64 + 8*g);
        f16x8 w1f = *(const f16x8*)(wq + row*64 + 32 + 8*g);
        f32x4 d = {0.f,0.f,0.f,0.f};
        d = MFMA32(w0f, xf0, d); d = MFMA32(w1f, xf1, d);
        float4 b4 = *(const float4*)(Bq + 64 + nt*16 + 4*g);
        *(uint2*)swp(Kb, m0+c, 128, nt*32 + 8*g) =
            pack4u(d[0]+b4.x, d[1]+b4.y, d[2]+b4.z, d[3]+b4.w);
      }
      // Q (scaled)
      #pragma unroll
      for (int nt = 0; nt < 4; ++nt) {
        const int row = nt*16 + c;
        f16x8 w0f = *(const f16x8*)(wq + row*64 + 8*g);
        f16x8 w1f = *(const f16x8*)(wq + row*64 + 32 + 8*g);
        f32x4 d = {0.f,0.f,0.f,0.f};
        d = MFMA32(w0f, xf0, d); d = MFMA32(w1f, xf1, d);
        float4 b4 = *(const float4*)(Bq + nt*16 + 4*g);
        *(uint2*)swp(Qb, m0+c, 128, nt*32 + 8*g) =
            pack4u((d[0]+b4.x)*qs, (d[1]+b4.y)*qs, (d[2]+b4.z)*qs, (d[3]+b4.w)*qs);
      }
      // V: A=x, B=weights -> lane holds (seq m0+4g..+3, dim nt*16+c) -> Vt row write 8B
      #pragma unroll
      for (int nt = 0; nt < 4; ++nt) {
        const int row = 128 + nt*16 + c;
        f16x8 w0f = *(const f16x8*)(wq + row*64 + 8*g);
        f16x8 w1f = *(const f16x8*)(wq + row*64 + 32 + 8*g);
        f32x4 d = {0.f,0.f,0.f,0.f};
        d = MFMA32(xf0, w0f, d); d = MFMA32(xf1, w1f, d);
        const float bias = Bq[128 + nt*16 + c];
        *(uint2*)swp(Vt, nt*16+c, 512, 32*w + 8*g) =
            pack4u(d[0]+bias, d[1]+bias, d[2]+bias, d[3]+bias);
      }
    }
    __syncthreads();   // (a) Q/K/Vt visible to all

    // ======== attention: 8 heads over own 16 q-rows; per-task att write ========
    #pragma unroll 2
    for (int task = 0; task < 8; ++task) {
      const int h = task;
      f16x4 qb = {0,0,0,0};
      if (g < 2) qb = *(const f16x4*)swp(Qb, m0+c, 128, 16*h + 8*g);
      f32x4 o = {0.f,0.f,0.f,0.f};
      #pragma unroll 2
      for (int jt = 0; jt < 16; ++jt) {
        f16x4 ka = {0,0,0,0};
        if (g < 2) ka = *(const f16x4*)swp(Kb, jt*16+c, 128, 16*h + 8*g);
        f32x4 st = {0.f,0.f,0.f,0.f};
        st = MFMA16(ka, qb, st);            // S^T tile
        uint2 pu = pack4u(exp2f(st[0]), exp2f(st[1]), exp2f(st[2]), exp2f(st[3]));
        f16x4 pb = *(f16x4*)&pu;
        f16x4 va;
        if (c < 8) va = *(const f16x4*)swp(Vt, 8*h+c, 512, jt*32 + (g>>1)*16 + (g&1)*8);
        else { va[0]=(_Float16)1.f; va[1]=(_Float16)1.f; va[2]=(_Float16)1.f; va[3]=(_Float16)1.f; }
        o = MFMA16(va, pb, o);              // O^T: rows d' (c<8), row8 = denom
      }
      const float den = __shfl(o[0], 32 + c, 64);
      const float rinv = 1.0f / den;
      if (g < 2) {                          // own rows; safe before barrier
        *(uint2*)swp(Qb, m0+c, 128, 16*h + 8*g) =
            pack4u(o[0]*rinv, o[1]*rinv, o[2]*rinv, o[3]*rinv);
      }
    }
    __syncthreads();   // (b) all cross-wave K/Vt reads complete

    // ======== O-projection + residual + LN1 (swapped; all 8B LDS ops) ========
    {
      f16x8 ab0 = *(const f16x8*)swp(Qb, m0+c, 128, 0  + g*16);
      f16x8 ab1 = *(const f16x8*)swp(Qb, m0+c, 128, 64 + g*16);
      float vals[4][4];
      #pragma unroll
      for (int nt = 0; nt < 4; ++nt) {
        f16x8 w0f = *(const f16x8*)(wo + (nt*16+c)*64 + 8*g);
        f16x8 w1f = *(const f16x8*)(wo + (nt*16+c)*64 + 32 + 8*g);
        f32x4 d = {0.f,0.f,0.f,0.f};
        d = MFMA32(w0f, ab0, d); d = MFMA32(w1f, ab1, d);
        float4 b4 = *(const float4*)(Bo + nt*16 + 4*g);
        uint2 rr = *(uint2*)swp(xs, m0+c, 128, nt*32 + 8*g);
        float2 r0 = __half22float2(*(__half2*)&rr.x);
        float2 r1 = __half22float2(*(__half2*)&rr.y);
        vals[nt][0] = d[0] + b4.x + r0.x;
        vals[nt][1] = d[1] + b4.y + r0.y;
        vals[nt][2] = d[2] + b4.z + r1.x;
        vals[nt][3] = d[3] + b4.w + r1.y;
      }
      float p1 = 0.f, p2 = 0.f;
      #pragma unroll
      for (int nt = 0; nt < 4; ++nt)
        #pragma unroll
        for (int i = 0; i < 4; ++i) { p1 += vals[nt][i]; p2 = fmaf(vals[nt][i], vals[nt][i], p2); }
      p1 += __shfl_xor(p1, 16, 64); p1 += __shfl_xor(p1, 32, 64);
      p2 += __shfl_xor(p2, 16, 64); p2 += __shfl_xor(p2, 32, 64);
      const float mean = p1*(1.0f/64.0f);
      const float rstd = rsqrtf(p2*(1.0f/64.0f) - mean*mean + 1e-5f);
      #pragma unroll
      for (int nt = 0; nt < 4; ++nt) {
        float4 g4 = *(const float4*)(G1 + nt*16 + 4*g);
        float4 b4 = *(const float4*)(B1 + nt*16 + 4*g);
        *(uint2*)swp(xs, m0+c, 128, nt*32 + 8*g) =
            pack4u((vals[nt][0]-mean)*rstd*g4.x + b4.x,
                   (vals[nt][1]-mean)*rstd*g4.y + b4.y,
                   (vals[nt][2]-mean)*rstd*g4.z + b4.z,
                   (vals[nt][3]-mean)*rstd*g4.w + b4.w);
      }
    }

    // ======== FF fused (swapped; P stays in-lane, no LDS tile) ========
    {
      f16x8 xb0 = *(const f16x8*)swp(xs, m0+c, 128, 0  + g*16);
      f16x8 xb1 = *(const f16x8*)swp(xs, m0+c, 128, 64 + g*16);
      f32x4 o2[4];
      #pragma unroll
      for (int nt2 = 0; nt2 < 4; ++nt2) { o2[nt2][0]=0.f; o2[nt2][1]=0.f; o2[nt2][2]=0.f; o2[nt2][3]=0.f; }
      for (int ht = 0; ht < 16; ++ht) {
        f16x8 w0f = *(const f16x8*)(w1 + (ht*16+c)*64 + 8*g);
        f16x8 w1f = *(const f16x8*)(w1 + (ht*16+c)*64 + 32 + 8*g);
        f32x4 d = {0.f,0.f,0.f,0.f};
        d = MFMA32(w0f, xb0, d); d = MFMA32(w1f, xb1, d);
        float4 bf4 = *(const float4*)(Bf1 + ht*16 + 4*g);
        float h0 = d[0] + bf4.x, h1 = d[1] + bf4.y, h2 = d[2] + bf4.z, h3 = d[3] + bf4.w;
        h0 = 0.5f*h0*(1.0f + erff(h0*0.70710678118654752f));
        h1 = 0.5f*h1*(1.0f + erff(h1*0.70710678118654752f));
        h2 = 0.5f*h2*(1.0f + erff(h2*0.70710678118654752f));
        h3 = 0.5f*h3*(1.0f + erff(h3*0.70710678118654752f));
        uint2 pu = pack4u(h0, h1, h2, h3);
        f16x4 pf = *(f16x4*)&pu;            // P[seq m0+c][hidden ht*16+4g..+3] — in-lane
        #pragma unroll
        for (int nt2 = 0; nt2 < 4; ++nt2) {
          f16x4 a2 = *(const f16x4*)(w2 + (nt2*16+c)*256 + ht*16 + 4*g);
          o2[nt2] = MFMA16(a2, pf, o2[nt2]);
        }
      }
      float vals[4][4];
      #pragma unroll
      for (int nt2 = 0; nt2 < 4; ++nt2) {
        float4 b4 = *(const float4*)(Bf2 + nt2*16 + 4*g);
        uint2 rr = *(uint2*)swp(xs, m0+c, 128, nt2*32 + 8*g);
        float2 r0 = __half22float2(*(__half2*)&rr.x);
        float2 r1 = __half22float2(*(__half2*)&rr.y);
        vals[nt2][0] = o2[nt2][0] + b4.x + r0.x;
        vals[nt2][1] = o2[nt2][1] + b4.y + r0.y;
        vals[nt2][2] = o2[nt2][2] + b4.z + r1.x;
        vals[nt2][3] = o2[nt2][3] + b4.w + r1.y;
      }
      float p1 = 0.f, p2 = 0.f;
      #pragma unroll
      for (int nt2 = 0; nt2 < 4; ++nt2)
        #pragma unroll
        for (int i = 0; i < 4; ++i) { p1 += vals[nt2][i]; p2 = fmaf(vals[nt2][i], vals[nt2][i], p2); }
      p1 += __shfl_xor(p1, 16, 64); p1 += __shfl_xor(p1, 32, 64);
      p2 += __shfl_xor(p2, 16, 64); p2 += __shfl_xor(p2, 32, 64);
      const float mean = p1*(1.0f/64.0f);
      const float rstd = rsqrtf(p2*(1.0f/64.0f) - mean*mean + 1e-5f);
      #pragma unroll
      for (int nt2 = 0; nt2 < 4; ++nt2) {
        float4 g4 = *(const float4*)(G2 + nt2*16 + 4*g);
        float4 b4 = *(const float4*)(B2 + nt2*16 + 4*g);
        *(uint2*)swp(xs, m0+c, 128, nt2*32 + 8*g) =
            pack4u((vals[nt2][0]-mean)*rstd*g4.x + b4.x,
                   (vals[nt2][1]-mean)*rstd*g4.y + b4.y,
                   (vals[nt2][2]-mean)*rstd*g4.z + b4.z,
                   (vals[nt2][3]-mean)*rstd*g4.w + b4.w);
      }
    }
    // barrier (a) of next layer protects Kb/Qb/Vt; xs accesses are own-row
  }

  // ---- mean over sequence -> nf ----
  __syncthreads();
  if (t < 256) {
    const int d = t & 63, qu = t >> 6;
    float sm = 0.f;
    for (int rr = qu*64; rr < qu*64 + 64; ++rr) sm += sr_h(xs, rr, 128, d);
    red[qu*64 + d] = sm;
  }
  __syncthreads();
  if (t < 64) {
    float sm = red[t] + red[64+t] + red[128+t] + red[192+t];
    nf[((size_t)b*4 + s)*64 + t] = sm * (1.0f/256.0f);
  }
}

// ------------------------- graph head kernel (unchanged) -------------------------
__global__ __launch_bounds__(128) void head_kernel(
  const float* __restrict__ nf,
  const float* __restrict__ ws_w, const float* __restrict__ ws_b,
  const float* __restrict__ b_s,  const float* __restrict__ lambda_init,
  const float* __restrict__ mc_w1, const float* __restrict__ mc_b1,
  const float* __restrict__ mc_w2, const float* __restrict__ mc_b2,
  const float* __restrict__ g1w, const float* __restrict__ g1b,
  const float* __restrict__ g2w, const float* __restrict__ g2b,
  const float* __restrict__ cw1, const float* __restrict__ cb1,
  const float* __restrict__ cw2, const float* __restrict__ cb2,
  float* __restrict__ out)
{
  const int b = blockIdx.x, t = threadIdx.x;
  __shared__ float nfb[256];
  __shared__ float meannf[64];
  __shared__ float fafb[8];
  __shared__ float z1[32];
  __shared__ float normM[16];
  __shared__ float rs[4];
  __shared__ float xw[512];
  __shared__ float hmat[512];
  __shared__ float hw[1024];
  __shared__ float gv[256];
  __shared__ float r1[128];

  for (int i = t; i < 256; i += 128) nfb[i] = nf[b*256 + i];
  __syncthreads();
  if (t < 8) {
    const int i = t & 3;
    const float* w = ws_w + (t >> 2)*64;
    float acc = 0.f;
    for (int c = 0; c < 64; ++c) acc = fmaf(nfb[i*64+c], w[c], acc);
    fafb[t] = acc;
  }
  if (t >= 64 && t < 128) {
    const int d = t - 64;
    meannf[d] = 0.25f*(nfb[d] + nfb[64+d] + nfb[128+d] + nfb[192+d]);
  }
  __syncthreads();
  if (t < 32) {
    float acc = mc_b1[t];
    const float* w = mc_w1 + t*64;
    for (int c = 0; c < 64; ++c) acc = fmaf(meannf[c], w[c], acc);
    z1[t] = fmaxf(acc, 0.f);
  }
  __syncthreads();
  if (t == 0) {
    float li = mc_b2[0];
    for (int k = 0; k < 32; ++k) li = fmaf(z1[k], mc_w2[k], li);
    const float lam = (1.0f/(1.0f + __expf(-li))) * lambda_init[0];
    const float AB[4][4] = {{1,1,0,0},{1,1,1,1},{0,1,1,1},{0,1,1,1}};
    const float add = ws_b[0] + b_s[0];
    float sM[4][4], deg[4];
    for (int i = 0; i < 4; ++i) {
      float d_ = 0.f;
      for (int j = 0; j < 4; ++j) {
        sM[i][j] = 1.0f/(1.0f + __expf(-(fafb[i] + fafb[4+j] + add)));
        d_ += sM[i][j];
      }
      deg[i] = d_;
    }
    float A[4][4], dinv[4];
    for (int i = 0; i < 4; ++i)
      for (int j = 0; j < 4; ++j) {
        const float a_ = sM[i][j] / (deg[j] + 1e-8f);
        const float sh = fmaxf(a_ * AB[i][j], 0.f);
        A[i][j] = lam*((i==j) ? 1.f : 0.f) + (1.0f - lam)*sh;
      }
    for (int j = 0; j < 4; ++j) {
      float d_ = 0.f;
      for (int i = 0; i < 4; ++i) d_ += A[i][j];
      dinv[j] = (d_ > 0.f) ? rsqrtf(d_) : 0.f;
    }
    for (int i = 0; i < 4; ++i) {
      float r_ = 0.f;
      for (int j = 0; j < 4; ++j) {
        const float n_ = dinv[i]*A[i][j]*dinv[j];
        normM[i*4+j] = n_;
        r_ += n_;
      }
      rs[i] = r_;
    }
  }
  __syncthreads();
  for (int idx = t; idx < 512; idx += 128) {
    const int i = idx >> 7, f = idx & 127;
    float acc = 0.f;
    for (int c = 0; c < 64; ++c) acc = fmaf(nfb[i*64+c], g1w[c*128 + f], acc);
    xw[idx] = acc;
  }
  __syncthreads();
  for (int idx = t; idx < 512; idx += 128) {
    const int j = idx >> 7, f = idx & 127;
    float acc = g1b[f];
    #pragma unroll
    for (int i = 0; i < 4; ++i) acc = fmaf(normM[i*4+j], xw[i*128+f], acc);
    hmat[j*128+f] = fmaxf(acc, 0.f);
  }
  __syncthreads();
  for (int idx = t; idx < 1024; idx += 128) {
    const int i = idx >> 8, f = idx & 255;
    float acc = 0.f;
    for (int c = 0; c < 128; ++c) acc = fmaf(hmat[i*128+c], g2w[c*256+f], acc);
    hw[idx] = acc;
  }
  __syncthreads();
  for (int f = t; f < 256; f += 128) {
    float acc = 0.f;
    #pragma unroll
    for (int i = 0; i < 4; ++i) acc = fmaf(rs[i], hw[i*256+f], acc);
    gv[f] = 0.25f*acc + g2b[f];
  }
  __syncthreads();
  if (t < 128) {
    float acc = cb1[t];
    for (int c = 0; c < 256; ++c) acc = fmaf(gv[c], cw1[c*128+t], acc);
    r1[t] = fmaxf(acc, 0.f);
  }
  __syncthreads();
  if (t < 5) {
    float acc = cb2[t];
    for (int k = 0; k < 128; ++k) acc = fmaf(r1[k], cw2[k*5 + t], acc);
    out[b*5 + t] = acc;
  }
}

// ------------------------- launch -------------------------
extern "C" void kernel_launch(void* const* d_in, const int* in_sizes, int n_in,
                              void* d_out, int out_size, void* d_ws, size_t ws_size,
                              hipStream_t stream) {
  (void)in_sizes; (void)n_in; (void)out_size; (void)ws_size;
  const float* sens   = (const float*)d_in[0];
  const float* c1w    = (const float*)d_in[1];
  const float* c1b    = (const float*)d_in[2];
  const float* bn1g   = (const float*)d_in[3];
  const float* bn1b   = (const float*)d_in[4];
  const float* c2w    = (const float*)d_in[5];
  const float* c2b    = (const float*)d_in[6];
  const float* bn2g   = (const float*)d_in[7];
  const float* bn2b   = (const float*)d_in[8];
  const float* wqkv   = (const float*)d_in[9];
  const float* bqkv   = (const float*)d_in[10];
  const float* wo     = (const float*)d_in[11];
  const float* bo     = (const float*)d_in[12];
  const float* ln1g   = (const float*)d_in[13];
  const float* ln1b   = (const float*)d_in[14];
  const float* fw1    = (const float*)d_in[15];
  const float* fb1    = (const float*)d_in[16];
  const float* fw2    = (const float*)d_in[17];
  const float* fb2    = (const float*)d_in[18];
  const float* ln2g   = (const float*)d_in[19];
  const float* ln2b   = (const float*)d_in[20];
  const float* ws_w   = (const float*)d_in[21];
  const float* ws_b   = (const float*)d_in[22];
  const float* b_s    = (const float*)d_in[23];
  const float* lam0   = (const float*)d_in[24];
  const float* mc_w1  = (const float*)d_in[25];
  const float* mc_b1  = (const float*)d_in[26];
  const float* mc_w2  = (const float*)d_in[27];
  const float* mc_b2  = (const float*)d_in[28];
  const float* g1w    = (const float*)d_in[29];
  const float* g1b    = (const float*)d_in[30];
  const float* g2w    = (const float*)d_in[31];
  const float* g2b    = (const float*)d_in[32];
  const float* cw1    = (const float*)d_in[33];
  const float* cb1    = (const float*)d_in[34];
  const float* cw2    = (const float*)d_in[35];
  const float* cb2    = (const float*)d_in[36];

  float*          x0  = (float*)d_ws;                                        // 16 MiB
  float*          nf  = (float*)((char*)d_ws + (size_t)NSENS*NB*SEQ*DM*4);   // 64 KiB
  unsigned short* w16 = (unsigned short*)((char*)d_ws + (size_t)NSENS*NB*SEQ*DM*4 + 65536); // 768 KiB

  wprep_kernel<<<8, 256, 0, stream>>>(wqkv, wo, fw1, fw2, w16);
  conv_kernel<<<NSENS*NB, 256, 0, stream>>>(sens, c1w, c1b, bn1g, bn1b,
                                            c2w, c2b, bn2g, bn2b, x0);
  tx_kernel<<<NSENS*NB, 1024, 0, stream>>>(x0, nf, w16, bqkv, bo,
                                           ln1g, ln1b, fb1, fb2, ln2g, ln2b);
  head_kernel<<<NB, 128, 0, stream>>>(nf, ws_w, ws_b, b_s, lam0,
                                      mc_w1, mc_b1, mc_w2, mc_b2,
                                      g1w, g1b, g2w, g2b, cw1, cb1, cw2, cb2,
                                      (float*)d_out);
}

// Round 13
// 289.695 us; speedup vs baseline: 3.4574x; 1.1197x over previous
//
#include <hip/hip_runtime.h>
#include <hip/hip_fp16.h>

#define NSENS 4
#define NB    64
#define LIN   2048
#define C1N   32
#define LP1   512
#define C2N   64
#define SEQ   256
#define DM    64
#define H1S   516

typedef _Float16 f16x4 __attribute__((ext_vector_type(4)));
typedef _Float16 f16x8 __attribute__((ext_vector_type(8)));
typedef float    f32x4 __attribute__((ext_vector_type(4)));

#define MFMA16(A,B,C) __builtin_amdgcn_mfma_f32_16x16x16f16((A),(B),(C),0,0,0)
#define MFMA32(A,B,C) __builtin_amdgcn_mfma_f32_16x16x32_f16((A),(B),(C),0,0,0)

__device__ __forceinline__ float fast_exp2(float x) {
#if __has_builtin(__builtin_amdgcn_exp2f)
  return __builtin_amdgcn_exp2f(x);   // raw v_exp_f32; scores bounded, no fixup needed
#else
  return exp2f(x);
#endif
}

// swizzled LDS addressing: 16B-chunk XOR by (row&7)<<4
__device__ __forceinline__ char* swp(char* base, int row, int stride, int byteoff) {
  return base + row*stride + ((byteoff & ~15) ^ ((row & 7) << 4)) + (byteoff & 15);
}
__device__ __forceinline__ float sr_h(char* base, int row, int stride, int col) {
  return (float)*(const _Float16*)swp(base, row, stride, col*2);
}
__device__ __forceinline__ void pack8(char* p, float4 a, float4 b) {
  __half2 h0 = __floats2half2_rn(a.x,a.y), h1 = __floats2half2_rn(a.z,a.w);
  __half2 h2 = __floats2half2_rn(b.x,b.y), h3 = __floats2half2_rn(b.z,b.w);
  uint4 u; u.x=*(unsigned*)&h0; u.y=*(unsigned*)&h1; u.z=*(unsigned*)&h2; u.w=*(unsigned*)&h3;
  *(uint4*)p = u;
}
__device__ __forceinline__ uint2 pack4u(float a, float b, float cc, float d) {
  __half2 h0 = __floats2half2_rn(a, b), h1 = __floats2half2_rn(cc, d);
  uint2 u; u.x = *(unsigned*)&h0; u.y = *(unsigned*)&h1; return u;
}

// ---------------- weight pack: fp32 -> fp16 row-major ----------------
__global__ __launch_bounds__(256) void wprep_kernel(
    const float* __restrict__ wqkv, const float* __restrict__ wo,
    const float* __restrict__ fw1,  const float* __restrict__ fw2,
    unsigned short* __restrict__ w16)
{
  const int wi = blockIdx.x;
  unsigned short* dst = w16 + (size_t)wi*49152;
  const float* s0 = wqkv + (size_t)wi*12288;
  const float* s1 = wo   + (size_t)wi*4096;
  const float* s2 = fw1  + (size_t)wi*16384;
  const float* s3 = fw2  + (size_t)wi*16384;
  for (int i = threadIdx.x; i < 12288; i += 256) { __half h = __float2half_rn(s0[i]); dst[i]       = *(unsigned short*)&h; }
  for (int i = threadIdx.x; i < 4096;  i += 256) { __half h = __float2half_rn(s1[i]); dst[12288+i] = *(unsigned short*)&h; }
  for (int i = threadIdx.x; i < 16384; i += 256) { __half h = __float2half_rn(s2[i]); dst[16384+i] = *(unsigned short*)&h; }
  for (int i = threadIdx.x; i < 16384; i += 256) { __half h = __float2half_rn(s3[i]); dst[32768+i] = *(unsigned short*)&h; }
}

// ------------------------- conv branch kernel (unchanged) -------------------------
__global__ __launch_bounds__(256) void conv_kernel(
    const float* __restrict__ sens,
    const float* __restrict__ c1w, const float* __restrict__ c1b,
    const float* __restrict__ bn1g, const float* __restrict__ bn1b,
    const float* __restrict__ c2w, const float* __restrict__ c2b,
    const float* __restrict__ bn2g, const float* __restrict__ bn2b,
    float* __restrict__ x0)
{
  const int bid = blockIdx.x;
  const int s = bid >> 6, b = bid & 63;
  const int tid = threadIdx.x;
  __shared__ __half h1p[C1N][H1S];
  __shared__ float w2s[C1N*3*C2N];

  for (int i = tid; i < C1N*3*C2N; i += 256) {
    int co = i & 63; int rem = i >> 6; int k = rem % 3; int ci = rem / 3;
    w2s[(ci*3 + k)*64 + co] = c2w[((s*C2N + co)*C1N + ci)*3 + k];
  }

  const float* xg = sens + (size_t)(s*NB + b)*LIN;
  const float bnr = rsqrtf(1.0f + 1e-5f);

  {
    const int c = tid & 31;
    const int l0 = tid >> 5;
    const float w0 = c1w[(s*C1N + c)*5 + 0];
    const float w1 = c1w[(s*C1N + c)*5 + 1];
    const float w2 = c1w[(s*C1N + c)*5 + 2];
    const float w3 = c1w[(s*C1N + c)*5 + 3];
    const float w4 = c1w[(s*C1N + c)*5 + 4];
    const float cb = c1b[s*C1N + c];
    const float sc = bn1g[s*C1N + c]*bnr;
    const float bt = bn1b[s*C1N + c];
    for (int l = l0; l < LP1; l += 8) {
      const int base = 4*l;
      float xm2 = (base-2 >= 0) ? xg[base-2] : 0.f;
      float xm1 = (base-1 >= 0) ? xg[base-1] : 0.f;
      float x0v = xg[base+0];
      float x1v = xg[base+1];
      float x2v = xg[base+2];
      float x3v = xg[base+3];
      float x4v = (base+4 < LIN) ? xg[base+4] : 0.f;
      float y0 = w0*xm2 + w1*xm1 + w2*x0v + w3*x1v + w4*x2v;
      float y1 = w0*x0v + w1*x1v + w2*x2v + w3*x3v + w4*x4v;
      y0 = (y0 + cb)*sc + bt;
      y1 = (y1 + cb)*sc + bt;
      h1p[c][l+1] = __float2half(fmaxf(fmaxf(y0, y1), 0.f));
      if (l == 0)      h1p[c][0]      = __float2half(0.f);
      if (l == LP1-1)  h1p[c][LP1+1]  = __float2half(0.f);
    }
  }
  __syncthreads();

  const int rg = tid & 31, cg = tid >> 5;
  const int c0 = cg*8;
  float cb2[8], sc2[8], bt2[8];
  #pragma unroll
  for (int cc = 0; cc < 8; ++cc) {
    cb2[cc] = c2b[s*C2N + c0 + cc];
    sc2[cc] = bn2g[s*C2N + c0 + cc]*bnr;
    bt2[cc] = bn2b[s*C2N + c0 + cc];
  }
  for (int it = 0; it < 4; ++it) {
    const int rA = 64*it + rg;
    const int rB = rA + 32;
    float acc[2][2][8] = {};
    for (int ci = 0; ci < C1N; ++ci) {
      const __half2 a01 = *(const __half2*)&h1p[ci][2*rA];
      const __half2 a23 = *(const __half2*)&h1p[ci][2*rA+2];
      const __half2 b01 = *(const __half2*)&h1p[ci][2*rB];
      const __half2 b23 = *(const __half2*)&h1p[ci][2*rB+2];
      const float hA[4] = { __low2float(a01), __high2float(a01), __low2float(a23), __high2float(a23) };
      const float hB[4] = { __low2float(b01), __high2float(b01), __low2float(b23), __high2float(b23) };
      #pragma unroll
      for (int k = 0; k < 3; ++k) {
        const float4 wv0 = *(const float4*)&w2s[(ci*3+k)*64 + c0];
        const float4 wv1 = *(const float4*)&w2s[(ci*3+k)*64 + c0 + 4];
        const float wr[8] = {wv0.x, wv0.y, wv0.z, wv0.w, wv1.x, wv1.y, wv1.z, wv1.w};
        #pragma unroll
        for (int p = 0; p < 2; ++p) {
          const float xa = hA[k+p];
          const float xb = hB[k+p];
          #pragma unroll
          for (int cc = 0; cc < 8; ++cc) {
            acc[0][p][cc] = fmaf(wr[cc], xa, acc[0][p][cc]);
            acc[1][p][cc] = fmaf(wr[cc], xb, acc[1][p][cc]);
          }
        }
      }
    }
    #pragma unroll
    for (int rr = 0; rr < 2; ++rr) {
      const int r = rr ? rB : rA;
      float* outp = x0 + ((size_t)bid*SEQ + r)*DM + c0;
      #pragma unroll
      for (int cc = 0; cc < 8; ++cc) {
        float v0 = (acc[rr][0][cc] + cb2[cc])*sc2[cc] + bt2[cc];
        float v1 = (acc[rr][1][cc] + cb2[cc])*sc2[cc] + bt2[cc];
        float v = fmaxf(fmaxf(v0, v1), 0.f);
        const int d = c0 + cc;
        const float ang = (float)r * __expf(-0.14391156463f*(float)(d & ~1));
        const float pe = (d & 1) ? cosf(ang) : sinf(ang);
        outp[cc] = v + pe;
      }
    }
  }
}

// ---------------- transformer kernel v11: v10 + unrolls + raw exp2 ----------------
// LDS: xs[256][64]f16 | Qb | Kb | Vt[64][256]f16 | red 1KB
__global__ __launch_bounds__(1024, 1) void tx_kernel(
  const float* __restrict__ x0, float* __restrict__ nf,
  const unsigned short* __restrict__ w16,
  const float* __restrict__ bqkv, const float* __restrict__ bo,
  const float* __restrict__ ln1g, const float* __restrict__ ln1b,
  const float* __restrict__ fb1,  const float* __restrict__ fb2,
  const float* __restrict__ ln2g, const float* __restrict__ ln2b)
{
  __shared__ char smem[132096];
  char* xs = smem;
  char* Qb = smem + 32768;
  char* Kb = smem + 65536;
  char* Vt = smem + 98304;
  float* red = (float*)(smem + 131072);

  const int bid = blockIdx.x;
  const int s = bid >> 6, b = bid & 63;
  const int t = threadIdx.x;
  const int l = t & 63, w = t >> 6;              // wave id 0..15
  const int g = l >> 4, c = l & 15;
  const int m0 = w * 16;                         // wave owns rows m0..m0+15
  const float qs = 0.35355339059327373f * 1.4426950408889634f; // 1/sqrt(8)*log2(e)

  // ---- x0 -> xs (fp16, swizzled) ----
  {
    const int r = t >> 2, qd = t & 3;
    const float* xp = x0 + ((size_t)bid*SEQ + r)*DM + qd*16;
    float4 a0 = *(const float4*)(xp + 0);
    float4 a1 = *(const float4*)(xp + 4);
    float4 a2 = *(const float4*)(xp + 8);
    float4 a3 = *(const float4*)(xp + 12);
    pack8(swp(xs, r, 128, qd*32), a0, a1);
    pack8(swp(xs, r, 128, qd*32 + 16), a2, a3);
  }
  __syncthreads();

  for (int layer = 0; layer < 2; ++layer) {
    const int wi = s*2 + layer;
    const unsigned short* wq = w16 + (size_t)wi*49152;
    const unsigned short* wo = wq + 12288;
    const unsigned short* w1 = wq + 16384;
    const unsigned short* w2 = wq + 32768;
    const float* Bq  = bqkv + wi*192;
    const float* Bo  = bo   + wi*64;
    const float* G1  = ln1g + wi*64; const float* B1 = ln1b + wi*64;
    const float* Bf1 = fb1  + wi*256; const float* Bf2 = fb2 + wi*64;
    const float* G2  = ln2g + wi*64; const float* B2 = ln2b + wi*64;

    // ======== QKV projections ========
    {
      f16x8 xf0 = *(const f16x8*)swp(xs, m0+c, 128, 0  + g*16);
      f16x8 xf1 = *(const f16x8*)swp(xs, m0+c, 128, 64 + g*16);
      // K: A=weights, B=x -> lane holds (dims nt*16+4g..+3, seq m0+c) -> 8B write
      #pragma unroll
      for (int nt = 0; nt < 4; ++nt) {
        const int row = 64 + nt*16 + c;
        f16x8 w0f = *(const f16x8*)(wq + row*64 + 8*g);
        f16x8 w1f = *(const f16x8*)(wq + row*64 + 32 + 8*g);
        f32x4 d = {0.f,0.f,0.f,0.f};
        d = MFMA32(w0f, xf0, d); d = MFMA32(w1f, xf1, d);
        float4 b4 = *(const float4*)(Bq + 64 + nt*16 + 4*g);
        *(uint2*)swp(Kb, m0+c, 128, nt*32 + 8*g) =
            pack4u(d[0]+b4.x, d[1]+b4.y, d[2]+b4.z, d[3]+b4.w);
      }
      // Q (scaled)
      #pragma unroll
      for (int nt = 0; nt < 4; ++nt) {
        const int row = nt*16 + c;
        f16x8 w0f = *(const f16x8*)(wq + row*64 + 8*g);
        f16x8 w1f = *(const f16x8*)(wq + row*64 + 32 + 8*g);
        f32x4 d = {0.f,0.f,0.f,0.f};
        d = MFMA32(w0f, xf0, d); d = MFMA32(w1f, xf1, d);
        float4 b4 = *(const float4*)(Bq + nt*16 + 4*g);
        *(uint2*)swp(Qb, m0+c, 128, nt*32 + 8*g) =
            pack4u((d[0]+b4.x)*qs, (d[1]+b4.y)*qs, (d[2]+b4.z)*qs, (d[3]+b4.w)*qs);
      }
      // V: A=x, B=weights -> lane holds (seq m0+4g..+3, dim nt*16+c) -> Vt row write 8B
      #pragma unroll
      for (int nt = 0; nt < 4; ++nt) {
        const int row = 128 + nt*16 + c;
        f16x8 w0f = *(const f16x8*)(wq + row*64 + 8*g);
        f16x8 w1f = *(const f16x8*)(wq + row*64 + 32 + 8*g);
        f32x4 d = {0.f,0.f,0.f,0.f};
        d = MFMA32(xf0, w0f, d); d = MFMA32(xf1, w1f, d);
        const float bias = Bq[128 + nt*16 + c];
        *(uint2*)swp(Vt, nt*16+c, 512, 32*w + 8*g) =
            pack4u(d[0]+bias, d[1]+bias, d[2]+bias, d[3]+bias);
      }
    }
    __syncthreads();   // (a) Q/K/Vt visible to all

    // ======== attention: 8 heads over own 16 q-rows; per-task att write ========
    #pragma unroll 2
    for (int task = 0; task < 8; ++task) {
      const int h = task;
      f16x4 qb = {0,0,0,0};
      if (g < 2) qb = *(const f16x4*)swp(Qb, m0+c, 128, 16*h + 8*g);
      f32x4 o = {0.f,0.f,0.f,0.f};
      #pragma unroll
      for (int jt = 0; jt < 16; ++jt) {
        // unconditional ka load: k=8..15 lanes (g>=2) multiply against qb zeros
        f16x4 ka = *(const f16x4*)swp(Kb, jt*16+c, 128, (16*h + 8*g) & 127);
        f32x4 st = {0.f,0.f,0.f,0.f};
        st = MFMA16(ka, qb, st);            // S^T tile
        uint2 pu = pack4u(fast_exp2(st[0]), fast_exp2(st[1]),
                          fast_exp2(st[2]), fast_exp2(st[3]));
        f16x4 pb = *(f16x4*)&pu;
        f16x4 va;
        if (c < 8) va = *(const f16x4*)swp(Vt, 8*h+c, 512, jt*32 + (g>>1)*16 + (g&1)*8);
        else { va[0]=(_Float16)1.f; va[1]=(_Float16)1.f; va[2]=(_Float16)1.f; va[3]=(_Float16)1.f; }
        o = MFMA16(va, pb, o);              // O^T: rows d' (c<8), row8 = denom
      }
      const float den = __shfl(o[0], 32 + c, 64);
      const float rinv = 1.0f / den;
      if (g < 2) {                          // own rows; safe before barrier
        *(uint2*)swp(Qb, m0+c, 128, 16*h + 8*g) =
            pack4u(o[0]*rinv, o[1]*rinv, o[2]*rinv, o[3]*rinv);
      }
    }
    __syncthreads();   // (b) all cross-wave K/Vt reads complete

    // ======== O-projection + residual + LN1 (swapped; all 8B LDS ops) ========
    {
      f16x8 ab0 = *(const f16x8*)swp(Qb, m0+c, 128, 0  + g*16);
      f16x8 ab1 = *(const f16x8*)swp(Qb, m0+c, 128, 64 + g*16);
      float vals[4][4];
      #pragma unroll
      for (int nt = 0; nt < 4; ++nt) {
        f16x8 w0f = *(const f16x8*)(wo + (nt*16+c)*64 + 8*g);
        f16x8 w1f = *(const f16x8*)(wo + (nt*16+c)*64 + 32 + 8*g);
        f32x4 d = {0.f,0.f,0.f,0.f};
        d = MFMA32(w0f, ab0, d); d = MFMA32(w1f, ab1, d);
        float4 b4 = *(const float4*)(Bo + nt*16 + 4*g);
        uint2 rr = *(uint2*)swp(xs, m0+c, 128, nt*32 + 8*g);
        float2 r0 = __half22float2(*(__half2*)&rr.x);
        float2 r1 = __half22float2(*(__half2*)&rr.y);
        vals[nt][0] = d[0] + b4.x + r0.x;
        vals[nt][1] = d[1] + b4.y + r0.y;
        vals[nt][2] = d[2] + b4.z + r1.x;
        vals[nt][3] = d[3] + b4.w + r1.y;
      }
      float p1 = 0.f, p2 = 0.f;
      #pragma unroll
      for (int nt = 0; nt < 4; ++nt)
        #pragma unroll
        for (int i = 0; i < 4; ++i) { p1 += vals[nt][i]; p2 = fmaf(vals[nt][i], vals[nt][i], p2); }
      p1 += __shfl_xor(p1, 16, 64); p1 += __shfl_xor(p1, 32, 64);
      p2 += __shfl_xor(p2, 16, 64); p2 += __shfl_xor(p2, 32, 64);
      const float mean = p1*(1.0f/64.0f);
      const float rstd = rsqrtf(p2*(1.0f/64.0f) - mean*mean + 1e-5f);
      #pragma unroll
      for (int nt = 0; nt < 4; ++nt) {
        float4 g4 = *(const float4*)(G1 + nt*16 + 4*g);
        float4 b4 = *(const float4*)(B1 + nt*16 + 4*g);
        *(uint2*)swp(xs, m0+c, 128, nt*32 + 8*g) =
            pack4u((vals[nt][0]-mean)*rstd*g4.x + b4.x,
                   (vals[nt][1]-mean)*rstd*g4.y + b4.y,
                   (vals[nt][2]-mean)*rstd*g4.z + b4.z,
                   (vals[nt][3]-mean)*rstd*g4.w + b4.w);
      }
    }

    // ======== FF fused (swapped; P stays in-lane, no LDS tile) ========
    {
      f16x8 xb0 = *(const f16x8*)swp(xs, m0+c, 128, 0  + g*16);
      f16x8 xb1 = *(const f16x8*)swp(xs, m0+c, 128, 64 + g*16);
      f32x4 o2[4];
      #pragma unroll
      for (int nt2 = 0; nt2 < 4; ++nt2) { o2[nt2][0]=0.f; o2[nt2][1]=0.f; o2[nt2][2]=0.f; o2[nt2][3]=0.f; }
      #pragma unroll
      for (int ht = 0; ht < 16; ++ht) {
        f16x8 w0f = *(const f16x8*)(w1 + (ht*16+c)*64 + 8*g);
        f16x8 w1f = *(const f16x8*)(w1 + (ht*16+c)*64 + 32 + 8*g);
        f32x4 d = {0.f,0.f,0.f,0.f};
        d = MFMA32(w0f, xb0, d); d = MFMA32(w1f, xb1, d);
        float4 bf4 = *(const float4*)(Bf1 + ht*16 + 4*g);
        float h0 = d[0] + bf4.x, h1 = d[1] + bf4.y, h2 = d[2] + bf4.z, h3 = d[3] + bf4.w;
        h0 = 0.5f*h0*(1.0f + erff(h0*0.70710678118654752f));
        h1 = 0.5f*h1*(1.0f + erff(h1*0.70710678118654752f));
        h2 = 0.5f*h2*(1.0f + erff(h2*0.70710678118654752f));
        h3 = 0.5f*h3*(1.0f + erff(h3*0.70710678118654752f));
        uint2 pu = pack4u(h0, h1, h2, h3);
        f16x4 pf = *(f16x4*)&pu;            // P[seq m0+c][hidden ht*16+4g..+3] — in-lane
        #pragma unroll
        for (int nt2 = 0; nt2 < 4; ++nt2) {
          f16x4 a2 = *(const f16x4*)(w2 + (nt2*16+c)*256 + ht*16 + 4*g);
          o2[nt2] = MFMA16(a2, pf, o2[nt2]);
        }
      }
      float vals[4][4];
      #pragma unroll
      for (int nt2 = 0; nt2 < 4; ++nt2) {
        float4 b4 = *(const float4*)(Bf2 + nt2*16 + 4*g);
        uint2 rr = *(uint2*)swp(xs, m0+c, 128, nt2*32 + 8*g);
        float2 r0 = __half22float2(*(__half2*)&rr.x);
        float2 r1 = __half22float2(*(__half2*)&rr.y);
        vals[nt2][0] = o2[nt2][0] + b4.x + r0.x;
        vals[nt2][1] = o2[nt2][1] + b4.y + r0.y;
        vals[nt2][2] = o2[nt2][2] + b4.z + r1.x;
        vals[nt2][3] = o2[nt2][3] + b4.w + r1.y;
      }
      float p1 = 0.f, p2 = 0.f;
      #pragma unroll
      for (int nt2 = 0; nt2 < 4; ++nt2)
        #pragma unroll
        for (int i = 0; i < 4; ++i) { p1 += vals[nt2][i]; p2 = fmaf(vals[nt2][i], vals[nt2][i], p2); }
      p1 += __shfl_xor(p1, 16, 64); p1 += __shfl_xor(p1, 32, 64);
      p2 += __shfl_xor(p2, 16, 64); p2 += __shfl_xor(p2, 32, 64);
      const float mean = p1*(1.0f/64.0f);
      const float rstd = rsqrtf(p2*(1.0f/64.0f) - mean*mean + 1e-5f);
      #pragma unroll
      for (int nt2 = 0; nt2 < 4; ++nt2) {
        float4 g4 = *(const float4*)(G2 + nt2*16 + 4*g);
        float4 b4 = *(const float4*)(B2 + nt2*16 + 4*g);
        *(uint2*)swp(xs, m0+c, 128, nt2*32 + 8*g) =
            pack4u((vals[nt2][0]-mean)*rstd*g4.x + b4.x,
                   (vals[nt2][1]-mean)*rstd*g4.y + b4.y,
                   (vals[nt2][2]-mean)*rstd*g4.z + b4.z,
                   (vals[nt2][3]-mean)*rstd*g4.w + b4.w);
      }
    }
    // barrier (a) of next layer protects Kb/Qb/Vt; xs accesses are own-row
  }

  // ---- mean over sequence -> nf ----
  __syncthreads();
  if (t < 256) {
    const int d = t & 63, qu = t >> 6;
    float sm = 0.f;
    for (int rr = qu*64; rr < qu*64 + 64; ++rr) sm += sr_h(xs, rr, 128, d);
    red[qu*64 + d] = sm;
  }
  __syncthreads();
  if (t < 64) {
    float sm = red[t] + red[64+t] + red[128+t] + red[192+t];
    nf[((size_t)b*4 + s)*64 + t] = sm * (1.0f/256.0f);
  }
}

// ------------------------- graph head kernel (unchanged) -------------------------
__global__ __launch_bounds__(128) void head_kernel(
  const float* __restrict__ nf,
  const float* __restrict__ ws_w, const float* __restrict__ ws_b,
  const float* __restrict__ b_s,  const float* __restrict__ lambda_init,
  const float* __restrict__ mc_w1, const float* __restrict__ mc_b1,
  const float* __restrict__ mc_w2, const float* __restrict__ mc_b2,
  const float* __restrict__ g1w, const float* __restrict__ g1b,
  const float* __restrict__ g2w, const float* __restrict__ g2b,
  const float* __restrict__ cw1, const float* __restrict__ cb1,
  const float* __restrict__ cw2, const float* __restrict__ cb2,
  float* __restrict__ out)
{
  const int b = blockIdx.x, t = threadIdx.x;
  __shared__ float nfb[256];
  __shared__ float meannf[64];
  __shared__ float fafb[8];
  __shared__ float z1[32];
  __shared__ float normM[16];
  __shared__ float rs[4];
  __shared__ float xw[512];
  __shared__ float hmat[512];
  __shared__ float hw[1024];
  __shared__ float gv[256];
  __shared__ float r1[128];

  for (int i = t; i < 256; i += 128) nfb[i] = nf[b*256 + i];
  __syncthreads();
  if (t < 8) {
    const int i = t & 3;
    const float* w = ws_w + (t >> 2)*64;
    float acc = 0.f;
    for (int c = 0; c < 64; ++c) acc = fmaf(nfb[i*64+c], w[c], acc);
    fafb[t] = acc;
  }
  if (t >= 64 && t < 128) {
    const int d = t - 64;
    meannf[d] = 0.25f*(nfb[d] + nfb[64+d] + nfb[128+d] + nfb[192+d]);
  }
  __syncthreads();
  if (t < 32) {
    float acc = mc_b1[t];
    const float* w = mc_w1 + t*64;
    for (int c = 0; c < 64; ++c) acc = fmaf(meannf[c], w[c], acc);
    z1[t] = fmaxf(acc, 0.f);
  }
  __syncthreads();
  if (t == 0) {
    float li = mc_b2[0];
    for (int k = 0; k < 32; ++k) li = fmaf(z1[k], mc_w2[k], li);
    const float lam = (1.0f/(1.0f + __expf(-li))) * lambda_init[0];
    const float AB[4][4] = {{1,1,0,0},{1,1,1,1},{0,1,1,1},{0,1,1,1}};
    const float add = ws_b[0] + b_s[0];
    float sM[4][4], deg[4];
    for (int i = 0; i < 4; ++i) {
      float d_ = 0.f;
      for (int j = 0; j < 4; ++j) {
        sM[i][j] = 1.0f/(1.0f + __expf(-(fafb[i] + fafb[4+j] + add)));
        d_ += sM[i][j];
      }
      deg[i] = d_;
    }
    float A[4][4], dinv[4];
    for (int i = 0; i < 4; ++i)
      for (int j = 0; j < 4; ++j) {
        const float a_ = sM[i][j] / (deg[j] + 1e-8f);
        const float sh = fmaxf(a_ * AB[i][j], 0.f);
        A[i][j] = lam*((i==j) ? 1.f : 0.f) + (1.0f - lam)*sh;
      }
    for (int j = 0; j < 4; ++j) {
      float d_ = 0.f;
      for (int i = 0; i < 4; ++i) d_ += A[i][j];
      dinv[j] = (d_ > 0.f) ? rsqrtf(d_) : 0.f;
    }
    for (int i = 0; i < 4; ++i) {
      float r_ = 0.f;
      for (int j = 0; j < 4; ++j) {
        const float n_ = dinv[i]*A[i][j]*dinv[j];
        normM[i*4+j] = n_;
        r_ += n_;
      }
      rs[i] = r_;
    }
  }
  __syncthreads();
  for (int idx = t; idx < 512; idx += 128) {
    const int i = idx >> 7, f = idx & 127;
    float acc = 0.f;
    for (int c = 0; c < 64; ++c) acc = fmaf(nfb[i*64+c], g1w[c*128 + f], acc);
    xw[idx] = acc;
  }
  __syncthreads();
  for (int idx = t; idx < 512; idx += 128) {
    const int j = idx >> 7, f = idx & 127;
    float acc = g1b[f];
    #pragma unroll
    for (int i = 0; i < 4; ++i) acc = fmaf(normM[i*4+j], xw[i*128+f], acc);
    hmat[j*128+f] = fmaxf(acc, 0.f);
  }
  __syncthreads();
  for (int idx = t; idx < 1024; idx += 128) {
    const int i = idx >> 8, f = idx & 255;
    float acc = 0.f;
    for (int c = 0; c < 128; ++c) acc = fmaf(hmat[i*128+c], g2w[c*256+f], acc);
    hw[idx] = acc;
  }
  __syncthreads();
  for (int f = t; f < 256; f += 128) {
    float acc = 0.f;
    #pragma unroll
    for (int i = 0; i < 4; ++i) acc = fmaf(rs[i], hw[i*256+f], acc);
    gv[f] = 0.25f*acc + g2b[f];
  }
  __syncthreads();
  if (t < 128) {
    float acc = cb1[t];
    for (int c = 0; c < 256; ++c) acc = fmaf(gv[c], cw1[c*128+t], acc);
    r1[t] = fmaxf(acc, 0.f);
  }
  __syncthreads();
  if (t < 5) {
    float acc = cb2[t];
    for (int k = 0; k < 128; ++k) acc = fmaf(r1[k], cw2[k*5 + t], acc);
    out[b*5 + t] = acc;
  }
}

// ------------------------- launch -------------------------
extern "C" void kernel_launch(void* const* d_in, const int* in_sizes, int n_in,
                              void* d_out, int out_size, void* d_ws, size_t ws_size,
                              hipStream_t stream) {
  (void)in_sizes; (void)n_in; (void)out_size; (void)ws_size;
  const float* sens   = (const float*)d_in[0];
  const float* c1w    = (const float*)d_in[1];
  const float* c1b    = (const float*)d_in[2];
  const float* bn1g   = (const float*)d_in[3];
  const float* bn1b   = (const float*)d_in[4];
  const float* c2w    = (const float*)d_in[5];
  const float* c2b    = (const float*)d_in[6];
  const float* bn2g   = (const float*)d_in[7];
  const float* bn2b   = (const float*)d_in[8];
  const float* wqkv   = (const float*)d_in[9];
  const float* bqkv   = (const float*)d_in[10];
  const float* wo     = (const float*)d_in[11];
  const float* bo     = (const float*)d_in[12];
  const float* ln1g   = (const float*)d_in[13];
  const float* ln1b   = (const float*)d_in[14];
  const float* fw1    = (const float*)d_in[15];
  const float* fb1    = (const float*)d_in[16];
  const float* fw2    = (const float*)d_in[17];
  const float* fb2    = (const float*)d_in[18];
  const float* ln2g   = (const float*)d_in[19];
  const float* ln2b   = (const float*)d_in[20];
  const float* ws_w   = (const float*)d_in[21];
  const float* ws_b   = (const float*)d_in[22];
  const float* b_s    = (const float*)d_in[23];
  const float* lam0   = (const float*)d_in[24];
  const float* mc_w1  = (const float*)d_in[25];
  const float* mc_b1  = (const float*)d_in[26];
  const float* mc_w2  = (const float*)d_in[27];
  const float* mc_b2  = (const float*)d_in[28];
  const float* g1w    = (const float*)d_in[29];
  const float* g1b    = (const float*)d_in[30];
  const float* g2w    = (const float*)d_in[31];
  const float* g2b    = (const float*)d_in[32];
  const float* cw1    = (const float*)d_in[33];
  const float* cb1    = (const float*)d_in[34];
  const float* cw2    = (const float*)d_in[35];
  const float* cb2    = (const float*)d_in[36];

  float*          x0  = (float*)d_ws;                                        // 16 MiB
  float*          nf  = (float*)((char*)d_ws + (size_t)NSENS*NB*SEQ*DM*4);   // 64 KiB
  unsigned short* w16 = (unsigned short*)((char*)d_ws + (size_t)NSENS*NB*SEQ*DM*4 + 65536); // 768 KiB

  wprep_kernel<<<8, 256, 0, stream>>>(wqkv, wo, fw1, fw2, w16);
  conv_kernel<<<NSENS*NB, 256, 0, stream>>>(sens, c1w, c1b, bn1g, bn1b,
                                            c2w, c2b, bn2g, bn2b, x0);
  tx_kernel<<<NSENS*NB, 1024, 0, stream>>>(x0, nf, w16, bqkv, bo,
                                           ln1g, ln1b, fb1, fb2, ln2g, ln2b);
  head_kernel<<<NB, 128, 0, stream>>>(nf, ws_w, ws_b, b_s, lam0,
                                      mc_w1, mc_b1, mc_w2, mc_b2,
                                      g1w, g1b, g2w, g2b, cw1, cb1, cw2, cb2,
                                      (float*)d_out);
}

// Round 14
// 265.339 us; speedup vs baseline: 3.7748x; 1.0918x over previous
//
#include <hip/hip_runtime.h>
#include <hip/hip_fp16.h>

#define NSENS 4
#define NB    64
#define LIN   2048
#define C1N   32
#define LP1   512
#define C2N   64
#define SEQ   256
#define DM    64

typedef _Float16 f16x4 __attribute__((ext_vector_type(4)));
typedef _Float16 f16x8 __attribute__((ext_vector_type(8)));
typedef float    f32x4 __attribute__((ext_vector_type(4)));

#define MFMA16(A,B,C) __builtin_amdgcn_mfma_f32_16x16x16f16((A),(B),(C),0,0,0)
#define MFMA32(A,B,C) __builtin_amdgcn_mfma_f32_16x16x32_f16((A),(B),(C),0,0,0)

__device__ __forceinline__ float fast_exp2(float x) {
#if __has_builtin(__builtin_amdgcn_exp2f)
  return __builtin_amdgcn_exp2f(x);
#else
  return exp2f(x);
#endif
}

// swizzled LDS addressing: 16B-chunk XOR by (row&7)<<4
__device__ __forceinline__ char* swp(char* base, int row, int stride, int byteoff) {
  return base + row*stride + ((byteoff & ~15) ^ ((row & 7) << 4)) + (byteoff & 15);
}
__device__ __forceinline__ float sr_h(char* base, int row, int stride, int col) {
  return (float)*(const _Float16*)swp(base, row, stride, col*2);
}
__device__ __forceinline__ void pack8(char* p, float4 a, float4 b) {
  __half2 h0 = __floats2half2_rn(a.x,a.y), h1 = __floats2half2_rn(a.z,a.w);
  __half2 h2 = __floats2half2_rn(b.x,b.y), h3 = __floats2half2_rn(b.z,b.w);
  uint4 u; u.x=*(unsigned*)&h0; u.y=*(unsigned*)&h1; u.z=*(unsigned*)&h2; u.w=*(unsigned*)&h3;
  *(uint4*)p = u;
}
__device__ __forceinline__ uint2 pack4u(float a, float b, float cc, float d) {
  __half2 h0 = __floats2half2_rn(a, b), h1 = __floats2half2_rn(cc, d);
  uint2 u; u.x = *(unsigned*)&h0; u.y = *(unsigned*)&h1; return u;
}

// ---------------- weight pack: fp32 -> fp16 row-major ----------------
__global__ __launch_bounds__(256) void wprep_kernel(
    const float* __restrict__ wqkv, const float* __restrict__ wo,
    const float* __restrict__ fw1,  const float* __restrict__ fw2,
    unsigned short* __restrict__ w16)
{
  const int wi = blockIdx.x;
  unsigned short* dst = w16 + (size_t)wi*49152;
  const float* s0 = wqkv + (size_t)wi*12288;
  const float* s1 = wo   + (size_t)wi*4096;
  const float* s2 = fw1  + (size_t)wi*16384;
  const float* s3 = fw2  + (size_t)wi*16384;
  for (int i = threadIdx.x; i < 12288; i += 256) { __half h = __float2half_rn(s0[i]); dst[i]       = *(unsigned short*)&h; }
  for (int i = threadIdx.x; i < 4096;  i += 256) { __half h = __float2half_rn(s1[i]); dst[12288+i] = *(unsigned short*)&h; }
  for (int i = threadIdx.x; i < 16384; i += 256) { __half h = __float2half_rn(s2[i]); dst[16384+i] = *(unsigned short*)&h; }
  for (int i = threadIdx.x; i < 16384; i += 256) { __half h = __float2half_rn(s3[i]); dst[32768+i] = *(unsigned short*)&h; }
}

// ---------------- fused conv + transformer kernel: 1024 threads = 16 waves ----------------
// LDS map: xs[256][64]f16 @0 | Qb @32K | Kb @64K | Vt[64][256] @96K | red @128K
// conv prologue overlays: h1p[32][516]f16 @32768 (33KB), w2s[6144]f32 @65792 (24KB)
__global__ __launch_bounds__(1024, 1) void tx_kernel(
  const float* __restrict__ sens,
  const float* __restrict__ c1w, const float* __restrict__ c1b,
  const float* __restrict__ bn1g, const float* __restrict__ bn1b,
  const float* __restrict__ c2w, const float* __restrict__ c2b,
  const float* __restrict__ bn2g, const float* __restrict__ bn2b,
  float* __restrict__ nf,
  const unsigned short* __restrict__ w16,
  const float* __restrict__ bqkv, const float* __restrict__ bo,
  const float* __restrict__ ln1g, const float* __restrict__ ln1b,
  const float* __restrict__ fb1,  const float* __restrict__ fb2,
  const float* __restrict__ ln2g, const float* __restrict__ ln2b)
{
  __shared__ char smem[132096];
  char* xs = smem;
  char* Qb = smem + 32768;
  char* Kb = smem + 65536;
  char* Vt = smem + 98304;
  float* red = (float*)(smem + 131072);

  const int bid = blockIdx.x;
  const int s = bid >> 6, b = bid & 63;
  const int t = threadIdx.x;
  const int l = t & 63, w = t >> 6;
  const int g = l >> 4, c = l & 15;
  const int m0 = w * 16;
  const float qs = 0.35355339059327373f * 1.4426950408889634f; // 1/sqrt(8)*log2(e)

  // ================= conv prologue (overlays Qb/Kb region) =================
  {
    __half (*h1p)[516] = (__half(*)[516])(smem + 32768);   // 33024 B
    float* w2s = (float*)(smem + 65792);                   // 24576 B

    for (int i = t; i < C1N*3*C2N; i += 1024) {
      int co = i & 63; int rem = i >> 6; int k = rem % 3; int ci = rem / 3;
      w2s[(ci*3 + k)*64 + co] = c2w[((s*C2N + co)*C1N + ci)*3 + k];
    }
    const float* xg = sens + (size_t)(s*NB + b)*LIN;
    const float bnr = rsqrtf(1.0f + 1e-5f);
    // conv1 (k=5,s=2,p=2)+bn+relu+pool -> h1p; ch = t&31, pos stride 32
    {
      const int cc1 = t & 31;
      const int l0 = t >> 5;           // 0..31
      const float w0 = c1w[(s*C1N + cc1)*5 + 0];
      const float w1 = c1w[(s*C1N + cc1)*5 + 1];
      const float w2 = c1w[(s*C1N + cc1)*5 + 2];
      const float w3 = c1w[(s*C1N + cc1)*5 + 3];
      const float w4 = c1w[(s*C1N + cc1)*5 + 4];
      const float cb = c1b[s*C1N + cc1];
      const float sc = bn1g[s*C1N + cc1]*bnr;
      const float bt = bn1b[s*C1N + cc1];
      for (int ll = l0; ll < LP1; ll += 32) {
        const int base = 4*ll;
        float xm2 = (base-2 >= 0) ? xg[base-2] : 0.f;
        float xm1 = (base-1 >= 0) ? xg[base-1] : 0.f;
        float x0v = xg[base+0];
        float x1v = xg[base+1];
        float x2v = xg[base+2];
        float x3v = xg[base+3];
        float x4v = (base+4 < LIN) ? xg[base+4] : 0.f;
        float y0 = w0*xm2 + w1*xm1 + w2*x0v + w3*x1v + w4*x2v;
        float y1 = w0*x0v + w1*x1v + w2*x2v + w3*x3v + w4*x4v;
        y0 = (y0 + cb)*sc + bt;
        y1 = (y1 + cb)*sc + bt;
        h1p[cc1][ll+1] = __float2half(fmaxf(fmaxf(y0, y1), 0.f));
        if (ll == 0)      h1p[cc1][0]      = __float2half(0.f);
        if (ll == LP1-1)  h1p[cc1][LP1+1]  = __float2half(0.f);
      }
    }
    __syncthreads();
    // conv2 (k=3,p=1)+bn+relu+pool+posenc -> xs; thread = (row r, 16 chans q*16..)
    {
      const int r = t & 255, q = t >> 8;       // q uniform per wave
      float acc0[16], acc1[16];
      #pragma unroll
      for (int i = 0; i < 16; ++i) { acc0[i] = 0.f; acc1[i] = 0.f; }
      for (int ci = 0; ci < C1N; ++ci) {
        const __half2 a01 = *(const __half2*)&h1p[ci][2*r];
        const __half2 a23 = *(const __half2*)&h1p[ci][2*r+2];
        const float2 f01 = __half22float2(a01);
        const float2 f23 = __half22float2(a23);
        const float hx[4] = { f01.x, f01.y, f23.x, f23.y };
        #pragma unroll
        for (int k = 0; k < 3; ++k) {
          const float* wrow = w2s + (ci*3+k)*64 + q*16;
          const float4 wv0 = *(const float4*)(wrow + 0);
          const float4 wv1 = *(const float4*)(wrow + 4);
          const float4 wv2 = *(const float4*)(wrow + 8);
          const float4 wv3 = *(const float4*)(wrow + 12);
          const float wr[16] = {wv0.x,wv0.y,wv0.z,wv0.w, wv1.x,wv1.y,wv1.z,wv1.w,
                                wv2.x,wv2.y,wv2.z,wv2.w, wv3.x,wv3.y,wv3.z,wv3.w};
          const float xa = hx[k], xb = hx[k+1];
          #pragma unroll
          for (int i = 0; i < 16; ++i) {
            acc0[i] = fmaf(wr[i], xa, acc0[i]);
            acc1[i] = fmaf(wr[i], xb, acc1[i]);
          }
        }
      }
      float vv[16];
      #pragma unroll
      for (int i = 0; i < 16; ++i) {
        const int d = q*16 + i;
        const float cb2 = c2b[s*C2N + d];
        const float sc2 = bn2g[s*C2N + d]*bnr;
        const float bt2 = bn2b[s*C2N + d];
        float v0 = (acc0[i] + cb2)*sc2 + bt2;
        float v1 = (acc1[i] + cb2)*sc2 + bt2;
        float v = fmaxf(fmaxf(v0, v1), 0.f);
        const float ang = (float)r * __expf(-0.14391156463f*(float)(d & ~1));
        const float pe = (d & 1) ? cosf(ang) : sinf(ang);
        vv[i] = v + pe;
      }
      pack8(swp(xs, r, 128, q*32),
            make_float4(vv[0],vv[1],vv[2],vv[3]), make_float4(vv[4],vv[5],vv[6],vv[7]));
      pack8(swp(xs, r, 128, q*32 + 16),
            make_float4(vv[8],vv[9],vv[10],vv[11]), make_float4(vv[12],vv[13],vv[14],vv[15]));
    }
  }
  __syncthreads();   // conv done; Qb/Kb region free for reuse

  // ================= transformer layers =================
  for (int layer = 0; layer < 2; ++layer) {
    const int wi = s*2 + layer;
    const unsigned short* wq = w16 + (size_t)wi*49152;
    const unsigned short* wo = wq + 12288;
    const unsigned short* w1 = wq + 16384;
    const unsigned short* w2 = wq + 32768;
    const float* Bq  = bqkv + wi*192;
    const float* Bo  = bo   + wi*64;
    const float* G1  = ln1g + wi*64; const float* B1 = ln1b + wi*64;
    const float* Bf1 = fb1  + wi*256; const float* Bf2 = fb2 + wi*64;
    const float* G2  = ln2g + wi*64; const float* B2 = ln2b + wi*64;

    // ======== QKV projections ========
    {
      f16x8 xf0 = *(const f16x8*)swp(xs, m0+c, 128, 0  + g*16);
      f16x8 xf1 = *(const f16x8*)swp(xs, m0+c, 128, 64 + g*16);
      #pragma unroll
      for (int nt = 0; nt < 4; ++nt) {
        const int row = 64 + nt*16 + c;
        f16x8 w0f = *(const f16x8*)(wq + row*64 + 8*g);
        f16x8 w1f = *(const f16x8*)(wq + row*64 + 32 + 8*g);
        f32x4 d = {0.f,0.f,0.f,0.f};
        d = MFMA32(w0f, xf0, d); d = MFMA32(w1f, xf1, d);
        float4 b4 = *(const float4*)(Bq + 64 + nt*16 + 4*g);
        *(uint2*)swp(Kb, m0+c, 128, nt*32 + 8*g) =
            pack4u(d[0]+b4.x, d[1]+b4.y, d[2]+b4.z, d[3]+b4.w);
      }
      #pragma unroll
      for (int nt = 0; nt < 4; ++nt) {
        const int row = nt*16 + c;
        f16x8 w0f = *(const f16x8*)(wq + row*64 + 8*g);
        f16x8 w1f = *(const f16x8*)(wq + row*64 + 32 + 8*g);
        f32x4 d = {0.f,0.f,0.f,0.f};
        d = MFMA32(w0f, xf0, d); d = MFMA32(w1f, xf1, d);
        float4 b4 = *(const float4*)(Bq + nt*16 + 4*g);
        *(uint2*)swp(Qb, m0+c, 128, nt*32 + 8*g) =
            pack4u((d[0]+b4.x)*qs, (d[1]+b4.y)*qs, (d[2]+b4.z)*qs, (d[3]+b4.w)*qs);
      }
      #pragma unroll
      for (int nt = 0; nt < 4; ++nt) {
        const int row = 128 + nt*16 + c;
        f16x8 w0f = *(const f16x8*)(wq + row*64 + 8*g);
        f16x8 w1f = *(const f16x8*)(wq + row*64 + 32 + 8*g);
        f32x4 d = {0.f,0.f,0.f,0.f};
        d = MFMA32(xf0, w0f, d); d = MFMA32(xf1, w1f, d);
        const float bias = Bq[128 + nt*16 + c];
        *(uint2*)swp(Vt, nt*16+c, 512, 32*w + 8*g) =
            pack4u(d[0]+bias, d[1]+bias, d[2]+bias, d[3]+bias);
      }
    }
    __syncthreads();   // (a) Q/K/Vt visible to all

    // ======== attention ========
    #pragma unroll 2
    for (int task = 0; task < 8; ++task) {
      const int h = task;
      f16x4 qb = {0,0,0,0};
      if (g < 2) qb = *(const f16x4*)swp(Qb, m0+c, 128, 16*h + 8*g);
      f32x4 o = {0.f,0.f,0.f,0.f};
      #pragma unroll
      for (int jt = 0; jt < 16; ++jt) {
        f16x4 ka = *(const f16x4*)swp(Kb, jt*16+c, 128, (16*h + 8*g) & 127);
        f32x4 st = {0.f,0.f,0.f,0.f};
        st = MFMA16(ka, qb, st);
        uint2 pu = pack4u(fast_exp2(st[0]), fast_exp2(st[1]),
                          fast_exp2(st[2]), fast_exp2(st[3]));
        f16x4 pb = *(f16x4*)&pu;
        f16x4 va;
        if (c < 8) va = *(const f16x4*)swp(Vt, 8*h+c, 512, jt*32 + (g>>1)*16 + (g&1)*8);
        else { va[0]=(_Float16)1.f; va[1]=(_Float16)1.f; va[2]=(_Float16)1.f; va[3]=(_Float16)1.f; }
        o = MFMA16(va, pb, o);
      }
      const float den = __shfl(o[0], 32 + c, 64);
      const float rinv = 1.0f / den;
      if (g < 2) {
        *(uint2*)swp(Qb, m0+c, 128, 16*h + 8*g) =
            pack4u(o[0]*rinv, o[1]*rinv, o[2]*rinv, o[3]*rinv);
      }
    }
    __syncthreads();   // (b) cross-wave reads complete

    // ======== O-projection + residual + LN1 ========
    {
      f16x8 ab0 = *(const f16x8*)swp(Qb, m0+c, 128, 0  + g*16);
      f16x8 ab1 = *(const f16x8*)swp(Qb, m0+c, 128, 64 + g*16);
      float vals[4][4];
      #pragma unroll
      for (int nt = 0; nt < 4; ++nt) {
        f16x8 w0f = *(const f16x8*)(wo + (nt*16+c)*64 + 8*g);
        f16x8 w1f = *(const f16x8*)(wo + (nt*16+c)*64 + 32 + 8*g);
        f32x4 d = {0.f,0.f,0.f,0.f};
        d = MFMA32(w0f, ab0, d); d = MFMA32(w1f, ab1, d);
        float4 b4 = *(const float4*)(Bo + nt*16 + 4*g);
        uint2 rr = *(uint2*)swp(xs, m0+c, 128, nt*32 + 8*g);
        float2 r0 = __half22float2(*(__half2*)&rr.x);
        float2 r1 = __half22float2(*(__half2*)&rr.y);
        vals[nt][0] = d[0] + b4.x + r0.x;
        vals[nt][1] = d[1] + b4.y + r0.y;
        vals[nt][2] = d[2] + b4.z + r1.x;
        vals[nt][3] = d[3] + b4.w + r1.y;
      }
      float p1 = 0.f, p2 = 0.f;
      #pragma unroll
      for (int nt = 0; nt < 4; ++nt)
        #pragma unroll
        for (int i = 0; i < 4; ++i) { p1 += vals[nt][i]; p2 = fmaf(vals[nt][i], vals[nt][i], p2); }
      p1 += __shfl_xor(p1, 16, 64); p1 += __shfl_xor(p1, 32, 64);
      p2 += __shfl_xor(p2, 16, 64); p2 += __shfl_xor(p2, 32, 64);
      const float mean = p1*(1.0f/64.0f);
      const float rstd = rsqrtf(p2*(1.0f/64.0f) - mean*mean + 1e-5f);
      #pragma unroll
      for (int nt = 0; nt < 4; ++nt) {
        float4 g4 = *(const float4*)(G1 + nt*16 + 4*g);
        float4 b4 = *(const float4*)(B1 + nt*16 + 4*g);
        *(uint2*)swp(xs, m0+c, 128, nt*32 + 8*g) =
            pack4u((vals[nt][0]-mean)*rstd*g4.x + b4.x,
                   (vals[nt][1]-mean)*rstd*g4.y + b4.y,
                   (vals[nt][2]-mean)*rstd*g4.z + b4.z,
                   (vals[nt][3]-mean)*rstd*g4.w + b4.w);
      }
    }

    // ======== FF fused ========
    {
      f16x8 xb0 = *(const f16x8*)swp(xs, m0+c, 128, 0  + g*16);
      f16x8 xb1 = *(const f16x8*)swp(xs, m0+c, 128, 64 + g*16);
      f32x4 o2[4];
      #pragma unroll
      for (int nt2 = 0; nt2 < 4; ++nt2) { o2[nt2][0]=0.f; o2[nt2][1]=0.f; o2[nt2][2]=0.f; o2[nt2][3]=0.f; }
      #pragma unroll
      for (int ht = 0; ht < 16; ++ht) {
        f16x8 w0f = *(const f16x8*)(w1 + (ht*16+c)*64 + 8*g);
        f16x8 w1f = *(const f16x8*)(w1 + (ht*16+c)*64 + 32 + 8*g);
        f32x4 d = {0.f,0.f,0.f,0.f};
        d = MFMA32(w0f, xb0, d); d = MFMA32(w1f, xb1, d);
        float4 bf4 = *(const float4*)(Bf1 + ht*16 + 4*g);
        float h0 = d[0] + bf4.x, h1 = d[1] + bf4.y, h2 = d[2] + bf4.z, h3 = d[3] + bf4.w;
        h0 = 0.5f*h0*(1.0f + erff(h0*0.70710678118654752f));
        h1 = 0.5f*h1*(1.0f + erff(h1*0.70710678118654752f));
        h2 = 0.5f*h2*(1.0f + erff(h2*0.70710678118654752f));
        h3 = 0.5f*h3*(1.0f + erff(h3*0.70710678118654752f));
        uint2 pu = pack4u(h0, h1, h2, h3);
        f16x4 pf = *(f16x4*)&pu;
        #pragma unroll
        for (int nt2 = 0; nt2 < 4; ++nt2) {
          f16x4 a2 = *(const f16x4*)(w2 + (nt2*16+c)*256 + ht*16 + 4*g);
          o2[nt2] = MFMA16(a2, pf, o2[nt2]);
        }
      }
      float vals[4][4];
      #pragma unroll
      for (int nt2 = 0; nt2 < 4; ++nt2) {
        float4 b4 = *(const float4*)(Bf2 + nt2*16 + 4*g);
        uint2 rr = *(uint2*)swp(xs, m0+c, 128, nt2*32 + 8*g);
        float2 r0 = __half22float2(*(__half2*)&rr.x);
        float2 r1 = __half22float2(*(__half2*)&rr.y);
        vals[nt2][0] = o2[nt2][0] + b4.x + r0.x;
        vals[nt2][1] = o2[nt2][1] + b4.y + r0.y;
        vals[nt2][2] = o2[nt2][2] + b4.z + r1.x;
        vals[nt2][3] = o2[nt2][3] + b4.w + r1.y;
      }
      float p1 = 0.f, p2 = 0.f;
      #pragma unroll
      for (int nt2 = 0; nt2 < 4; ++nt2)
        #pragma unroll
        for (int i = 0; i < 4; ++i) { p1 += vals[nt2][i]; p2 = fmaf(vals[nt2][i], vals[nt2][i], p2); }
      p1 += __shfl_xor(p1, 16, 64); p1 += __shfl_xor(p1, 32, 64);
      p2 += __shfl_xor(p2, 16, 64); p2 += __shfl_xor(p2, 32, 64);
      const float mean = p1*(1.0f/64.0f);
      const float rstd = rsqrtf(p2*(1.0f/64.0f) - mean*mean + 1e-5f);
      #pragma unroll
      for (int nt2 = 0; nt2 < 4; ++nt2) {
        float4 g4 = *(const float4*)(G2 + nt2*16 + 4*g);
        float4 b4 = *(const float4*)(B2 + nt2*16 + 4*g);
        *(uint2*)swp(xs, m0+c, 128, nt2*32 + 8*g) =
            pack4u((vals[nt2][0]-mean)*rstd*g4.x + b4.x,
                   (vals[nt2][1]-mean)*rstd*g4.y + b4.y,
                   (vals[nt2][2]-mean)*rstd*g4.z + b4.z,
                   (vals[nt2][3]-mean)*rstd*g4.w + b4.w);
      }
    }
  }

  // ---- mean over sequence -> nf ----
  __syncthreads();
  if (t < 256) {
    const int d = t & 63, qu = t >> 6;
    float sm = 0.f;
    for (int rr = qu*64; rr < qu*64 + 64; ++rr) sm += sr_h(xs, rr, 128, d);
    red[qu*64 + d] = sm;
  }
  __syncthreads();
  if (t < 64) {
    float sm = red[t] + red[64+t] + red[128+t] + red[192+t];
    nf[((size_t)b*4 + s)*64 + t] = sm * (1.0f/256.0f);
  }
}

// ------------------------- graph head kernel (unchanged) -------------------------
__global__ __launch_bounds__(128) void head_kernel(
  const float* __restrict__ nf,
  const float* __restrict__ ws_w, const float* __restrict__ ws_b,
  const float* __restrict__ b_s,  const float* __restrict__ lambda_init,
  const float* __restrict__ mc_w1, const float* __restrict__ mc_b1,
  const float* __restrict__ mc_w2, const float* __restrict__ mc_b2,
  const float* __restrict__ g1w, const float* __restrict__ g1b,
  const float* __restrict__ g2w, const float* __restrict__ g2b,
  const float* __restrict__ cw1, const float* __restrict__ cb1,
  const float* __restrict__ cw2, const float* __restrict__ cb2,
  float* __restrict__ out)
{
  const int b = blockIdx.x, t = threadIdx.x;
  __shared__ float nfb[256];
  __shared__ float meannf[64];
  __shared__ float fafb[8];
  __shared__ float z1[32];
  __shared__ float normM[16];
  __shared__ float rs[4];
  __shared__ float xw[512];
  __shared__ float hmat[512];
  __shared__ float hw[1024];
  __shared__ float gv[256];
  __shared__ float r1[128];

  for (int i = t; i < 256; i += 128) nfb[i] = nf[b*256 + i];
  __syncthreads();
  if (t < 8) {
    const int i = t & 3;
    const float* w = ws_w + (t >> 2)*64;
    float acc = 0.f;
    for (int c = 0; c < 64; ++c) acc = fmaf(nfb[i*64+c], w[c], acc);
    fafb[t] = acc;
  }
  if (t >= 64 && t < 128) {
    const int d = t - 64;
    meannf[d] = 0.25f*(nfb[d] + nfb[64+d] + nfb[128+d] + nfb[192+d]);
  }
  __syncthreads();
  if (t < 32) {
    float acc = mc_b1[t];
    const float* w = mc_w1 + t*64;
    for (int c = 0; c < 64; ++c) acc = fmaf(meannf[c], w[c], acc);
    z1[t] = fmaxf(acc, 0.f);
  }
  __syncthreads();
  if (t == 0) {
    float li = mc_b2[0];
    for (int k = 0; k < 32; ++k) li = fmaf(z1[k], mc_w2[k], li);
    const float lam = (1.0f/(1.0f + __expf(-li))) * lambda_init[0];
    const float AB[4][4] = {{1,1,0,0},{1,1,1,1},{0,1,1,1},{0,1,1,1}};
    const float add = ws_b[0] + b_s[0];
    float sM[4][4], deg[4];
    for (int i = 0; i < 4; ++i) {
      float d_ = 0.f;
      for (int j = 0; j < 4; ++j) {
        sM[i][j] = 1.0f/(1.0f + __expf(-(fafb[i] + fafb[4+j] + add)));
        d_ += sM[i][j];
      }
      deg[i] = d_;
    }
    float A[4][4], dinv[4];
    for (int i = 0; i < 4; ++i)
      for (int j = 0; j < 4; ++j) {
        const float a_ = sM[i][j] / (deg[j] + 1e-8f);
        const float sh = fmaxf(a_ * AB[i][j], 0.f);
        A[i][j] = lam*((i==j) ? 1.f : 0.f) + (1.0f - lam)*sh;
      }
    for (int j = 0; j < 4; ++j) {
      float d_ = 0.f;
      for (int i = 0; i < 4; ++i) d_ += A[i][j];
      dinv[j] = (d_ > 0.f) ? rsqrtf(d_) : 0.f;
    }
    for (int i = 0; i < 4; ++i) {
      float r_ = 0.f;
      for (int j = 0; j < 4; ++j) {
        const float n_ = dinv[i]*A[i][j]*dinv[j];
        normM[i*4+j] = n_;
        r_ += n_;
      }
      rs[i] = r_;
    }
  }
  __syncthreads();
  for (int idx = t; idx < 512; idx += 128) {
    const int i = idx >> 7, f = idx & 127;
    float acc = 0.f;
    for (int c = 0; c < 64; ++c) acc = fmaf(nfb[i*64+c], g1w[c*128 + f], acc);
    xw[idx] = acc;
  }
  __syncthreads();
  for (int idx = t; idx < 512; idx += 128) {
    const int j = idx >> 7, f = idx & 127;
    float acc = g1b[f];
    #pragma unroll
    for (int i = 0; i < 4; ++i) acc = fmaf(normM[i*4+j], xw[i*128+f], acc);
    hmat[j*128+f] = fmaxf(acc, 0.f);
  }
  __syncthreads();
  for (int idx = t; idx < 1024; idx += 128) {
    const int i = idx >> 8, f = idx & 255;
    float acc = 0.f;
    for (int c = 0; c < 128; ++c) acc = fmaf(hmat[i*128+c], g2w[c*256+f], acc);
    hw[idx] = acc;
  }
  __syncthreads();
  for (int f = t; f < 256; f += 128) {
    float acc = 0.f;
    #pragma unroll
    for (int i = 0; i < 4; ++i) acc = fmaf(rs[i], hw[i*256+f], acc);
    gv[f] = 0.25f*acc + g2b[f];
  }
  __syncthreads();
  if (t < 128) {
    float acc = cb1[t];
    for (int c = 0; c < 256; ++c) acc = fmaf(gv[c], cw1[c*128+t], acc);
    r1[t] = fmaxf(acc, 0.f);
  }
  __syncthreads();
  if (t < 5) {
    float acc = cb2[t];
    for (int k = 0; k < 128; ++k) acc = fmaf(r1[k], cw2[k*5 + t], acc);
    out[b*5 + t] = acc;
  }
}

// ------------------------- launch -------------------------
extern "C" void kernel_launch(void* const* d_in, const int* in_sizes, int n_in,
                              void* d_out, int out_size, void* d_ws, size_t ws_size,
                              hipStream_t stream) {
  (void)in_sizes; (void)n_in; (void)out_size; (void)ws_size;
  const float* sens   = (const float*)d_in[0];
  const float* c1w    = (const float*)d_in[1];
  const float* c1b    = (const float*)d_in[2];
  const float* bn1g   = (const float*)d_in[3];
  const float* bn1b   = (const float*)d_in[4];
  const float* c2w    = (const float*)d_in[5];
  const float* c2b    = (const float*)d_in[6];
  const float* bn2g   = (const float*)d_in[7];
  const float* bn2b   = (const float*)d_in[8];
  const float* wqkv   = (const float*)d_in[9];
  const float* bqkv   = (const float*)d_in[10];
  const float* wo     = (const float*)d_in[11];
  const float* bo     = (const float*)d_in[12];
  const float* ln1g   = (const float*)d_in[13];
  const float* ln1b   = (const float*)d_in[14];
  const float* fw1    = (const float*)d_in[15];
  const float* fb1    = (const float*)d_in[16];
  const float* fw2    = (const float*)d_in[17];
  const float* fb2    = (const float*)d_in[18];
  const float* ln2g   = (const float*)d_in[19];
  const float* ln2b   = (const float*)d_in[20];
  const float* ws_w   = (const float*)d_in[21];
  const float* ws_b   = (const float*)d_in[22];
  const float* b_s    = (const float*)d_in[23];
  const float* lam0   = (const float*)d_in[24];
  const float* mc_w1  = (const float*)d_in[25];
  const float* mc_b1  = (const float*)d_in[26];
  const float* mc_w2  = (const float*)d_in[27];
  const float* mc_b2  = (const float*)d_in[28];
  const float* g1w    = (const float*)d_in[29];
  const float* g1b    = (const float*)d_in[30];
  const float* g2w    = (const float*)d_in[31];
  const float* g2b    = (const float*)d_in[32];
  const float* cw1    = (const float*)d_in[33];
  const float* cb1    = (const float*)d_in[34];
  const float* cw2    = (const float*)d_in[35];
  const float* cb2    = (const float*)d_in[36];

  float*          nf  = (float*)d_ws;                                  // 64 KiB
  unsigned short* w16 = (unsigned short*)((char*)d_ws + 65536);        // 768 KiB

  wprep_kernel<<<8, 256, 0, stream>>>(wqkv, wo, fw1, fw2, w16);
  tx_kernel<<<NSENS*NB, 1024, 0, stream>>>(sens, c1w, c1b, bn1g, bn1b,
                                           c2w, c2b, bn2g, bn2b,
                                           nf, w16, bqkv, bo,
                                           ln1g, ln1b, fb1, fb2, ln2g, ln2b);
  head_kernel<<<NB, 128, 0, stream>>>(nf, ws_w, ws_b, b_s, lam0,
                                      mc_w1, mc_b1, mc_w2, mc_b2,
                                      g1w, g1b, g2w, g2b, cw1, cb1, cw2, cb2,
                                      (float*)d_out);
}

// Round 15
// 230.697 us; speedup vs baseline: 4.3416x; 1.1502x over previous
//
#include <hip/hip_runtime.h>
#include <hip/hip_fp16.h>

#define NSENS 4
#define NB    64
#define LIN   2048
#define C1N   32
#define LP1   512
#define C2N   64
#define SEQ   256
#define DM    64

typedef _Float16 f16x4 __attribute__((ext_vector_type(4)));
typedef _Float16 f16x8 __attribute__((ext_vector_type(8)));
typedef float    f32x4 __attribute__((ext_vector_type(4)));

#define MFMA16(A,B,C) __builtin_amdgcn_mfma_f32_16x16x16f16((A),(B),(C),0,0,0)
#define MFMA32(A,B,C) __builtin_amdgcn_mfma_f32_16x16x32_f16((A),(B),(C),0,0,0)

__device__ __forceinline__ float fast_exp2(float x) {
#if __has_builtin(__builtin_amdgcn_exp2f)
  return __builtin_amdgcn_exp2f(x);
#else
  return exp2f(x);
#endif
}

// swizzled LDS addressing: 16B-chunk XOR by (row&7)<<4
__device__ __forceinline__ char* swp(char* base, int row, int stride, int byteoff) {
  return base + row*stride + ((byteoff & ~15) ^ ((row & 7) << 4)) + (byteoff & 15);
}
__device__ __forceinline__ float sr_h(char* base, int row, int stride, int col) {
  return (float)*(const _Float16*)swp(base, row, stride, col*2);
}
__device__ __forceinline__ uint2 pack4u(float a, float b, float cc, float d) {
  __half2 h0 = __floats2half2_rn(a, b), h1 = __floats2half2_rn(cc, d);
  uint2 u; u.x = *(unsigned*)&h0; u.y = *(unsigned*)&h1; return u;
}

// ---------------- weight pack: fp32 -> fp16 row-major ----------------
__global__ __launch_bounds__(256) void wprep_kernel(
    const float* __restrict__ wqkv, const float* __restrict__ wo,
    const float* __restrict__ fw1,  const float* __restrict__ fw2,
    unsigned short* __restrict__ w16)
{
  const int wi = blockIdx.x;
  unsigned short* dst = w16 + (size_t)wi*49152;
  const float* s0 = wqkv + (size_t)wi*12288;
  const float* s1 = wo   + (size_t)wi*4096;
  const float* s2 = fw1  + (size_t)wi*16384;
  const float* s3 = fw2  + (size_t)wi*16384;
  for (int i = threadIdx.x; i < 12288; i += 256) { __half h = __float2half_rn(s0[i]); dst[i]       = *(unsigned short*)&h; }
  for (int i = threadIdx.x; i < 4096;  i += 256) { __half h = __float2half_rn(s1[i]); dst[12288+i] = *(unsigned short*)&h; }
  for (int i = threadIdx.x; i < 16384; i += 256) { __half h = __float2half_rn(s2[i]); dst[16384+i] = *(unsigned short*)&h; }
  for (int i = threadIdx.x; i < 16384; i += 256) { __half h = __float2half_rn(s3[i]); dst[32768+i] = *(unsigned short*)&h; }
}

// ---------------- fused conv + transformer kernel: 1024 threads = 16 waves ----------------
// LDS map: xs[256][64]f16 @0 | Qb @32K | Kb @64K | Vt[64][256] @96K | red @128K
// conv prologue overlays (within Qb..Kb): h1t[514][32]f16 @32768 (32896B),
//                                         w2hT[3][64][32]f16 @65664 (12288B)
__global__ __launch_bounds__(1024, 1) void tx_kernel(
  const float* __restrict__ sens,
  const float* __restrict__ c1w, const float* __restrict__ c1b,
  const float* __restrict__ bn1g, const float* __restrict__ bn1b,
  const float* __restrict__ c2w, const float* __restrict__ c2b,
  const float* __restrict__ bn2g, const float* __restrict__ bn2b,
  float* __restrict__ nf,
  const unsigned short* __restrict__ w16,
  const float* __restrict__ bqkv, const float* __restrict__ bo,
  const float* __restrict__ ln1g, const float* __restrict__ ln1b,
  const float* __restrict__ fb1,  const float* __restrict__ fb2,
  const float* __restrict__ ln2g, const float* __restrict__ ln2b)
{
  __shared__ char smem[132096];
  char* xs = smem;
  char* Qb = smem + 32768;
  char* Kb = smem + 65536;
  char* Vt = smem + 98304;
  float* red = (float*)(smem + 131072);

  const int bid = blockIdx.x;
  const int s = bid >> 6, b = bid & 63;
  const int t = threadIdx.x;
  const int l = t & 63, w = t >> 6;
  const int g = l >> 4, c = l & 15;
  const int m0 = w * 16;
  const float qs = 0.35355339059327373f * 1.4426950408889634f; // 1/sqrt(8)*log2(e)

  // ================= conv prologue (MFMA conv2) =================
  {
    __half* h1t  = (__half*)(smem + 32768);    // [514][32]  (h1t[i] = h1[i-1]; rows 0,513 zero)
    __half* w2hT = (__half*)(smem + 65664);    // [3][64][32]

    // pack conv2 weights fp16 transposed: w2hT[k][co][ci]
    for (int i = t; i < 3*64*32; i += 1024) {
      const int ci = i & 31; const int rem = i >> 5; const int co = rem & 63; const int k = rem >> 6;
      w2hT[i] = __float2half_rn(c2w[((s*C2N + co)*C1N + ci)*3 + k]);
    }
    if (t < 32) { h1t[t] = __float2half(0.f); h1t[513*32 + t] = __float2half(0.f); }

    const float* xg = sens + (size_t)(s*NB + b)*LIN;
    const float bnr = rsqrtf(1.0f + 1e-5f);
    // conv1 (k=5,s=2,p=2)+bn+relu+pool -> h1t transposed
    {
      const int ch = t & 31;
      const int l0 = t >> 5;           // 0..31
      const float w0 = c1w[(s*C1N + ch)*5 + 0];
      const float w1 = c1w[(s*C1N + ch)*5 + 1];
      const float w2 = c1w[(s*C1N + ch)*5 + 2];
      const float w3 = c1w[(s*C1N + ch)*5 + 3];
      const float w4 = c1w[(s*C1N + ch)*5 + 4];
      const float cb = c1b[s*C1N + ch];
      const float sc = bn1g[s*C1N + ch]*bnr;
      const float bt = bn1b[s*C1N + ch];
      for (int ll = l0; ll < LP1; ll += 32) {
        const int base = 4*ll;
        float xm2 = (base-2 >= 0) ? xg[base-2] : 0.f;
        float xm1 = (base-1 >= 0) ? xg[base-1] : 0.f;
        float x0v = xg[base+0];
        float x1v = xg[base+1];
        float x2v = xg[base+2];
        float x3v = xg[base+3];
        float x4v = (base+4 < LIN) ? xg[base+4] : 0.f;
        float y0 = w0*xm2 + w1*xm1 + w2*x0v + w3*x1v + w4*x2v;
        float y1 = w0*x0v + w1*x1v + w2*x2v + w3*x3v + w4*x4v;
        y0 = (y0 + cb)*sc + bt;
        y1 = (y1 + cb)*sc + bt;
        h1t[(ll+1)*32 + ch] = __float2half(fmaxf(fmaxf(y0, y1), 0.f));
      }
    }
    __syncthreads();
    // conv2 via MFMA: wave w covers positions m0*2 .. m0*2+31 (2 pos-tiles)
    {
      const int p0a = m0*2, p0b = m0*2 + 16;
      f16x8 aA[3], aB[3];
      #pragma unroll
      for (int k = 0; k < 3; ++k) {
        aA[k] = *(const f16x8*)&h1t[(p0a + c + k)*32 + 8*g];
        aB[k] = *(const f16x8*)&h1t[(p0b + c + k)*32 + 8*g];
      }
      #pragma unroll
      for (int ct = 0; ct < 4; ++ct) {
        f32x4 dA = {0.f,0.f,0.f,0.f}, dB = {0.f,0.f,0.f,0.f};
        #pragma unroll
        for (int k = 0; k < 3; ++k) {
          f16x8 bw = *(const f16x8*)&w2hT[(k*64 + ct*16 + c)*32 + 8*g];
          dA = MFMA32(aA[k], bw, dA);
          dB = MFMA32(aB[k], bw, dB);
        }
        const int d = ct*16 + c;
        const float cb2 = c2b[s*C2N + d];
        const float sc2 = bn2g[s*C2N + d]*bnr;
        const float bt2 = bn2b[s*C2N + d];
        const float efac = __expf(-0.14391156463f*(float)(d & ~1));
        float v[4];
        v[0] = fmaxf(fmaxf((dA[0]+cb2)*sc2+bt2, (dA[1]+cb2)*sc2+bt2), 0.f); // row m0+2g
        v[1] = fmaxf(fmaxf((dA[2]+cb2)*sc2+bt2, (dA[3]+cb2)*sc2+bt2), 0.f); // row m0+2g+1
        v[2] = fmaxf(fmaxf((dB[0]+cb2)*sc2+bt2, (dB[1]+cb2)*sc2+bt2), 0.f); // row m0+8+2g
        v[3] = fmaxf(fmaxf((dB[2]+cb2)*sc2+bt2, (dB[3]+cb2)*sc2+bt2), 0.f); // row m0+8+2g+1
        const int rr[4] = { m0+2*g, m0+2*g+1, m0+8+2*g, m0+8+2*g+1 };
        #pragma unroll
        for (int i = 0; i < 4; ++i) {
          const float ang = (float)rr[i] * efac;
          const float pe = (d & 1) ? cosf(ang) : sinf(ang);
          *(_Float16*)swp(xs, rr[i], 128, d*2) = (_Float16)(v[i] + pe);
        }
      }
    }
  }
  __syncthreads();   // conv done; Qb/Kb region free

  // ================= transformer layers =================
  for (int layer = 0; layer < 2; ++layer) {
    const int wi = s*2 + layer;
    const unsigned short* wq = w16 + (size_t)wi*49152;
    const unsigned short* wo = wq + 12288;
    const unsigned short* w1 = wq + 16384;
    const unsigned short* w2 = wq + 32768;
    const float* Bq  = bqkv + wi*192;
    const float* Bo  = bo   + wi*64;
    const float* G1  = ln1g + wi*64; const float* B1 = ln1b + wi*64;
    const float* Bf1 = fb1  + wi*256; const float* Bf2 = fb2 + wi*64;
    const float* G2  = ln2g + wi*64; const float* B2 = ln2b + wi*64;

    // ======== QKV projections ========
    {
      f16x8 xf0 = *(const f16x8*)swp(xs, m0+c, 128, 0  + g*16);
      f16x8 xf1 = *(const f16x8*)swp(xs, m0+c, 128, 64 + g*16);
      #pragma unroll
      for (int nt = 0; nt < 4; ++nt) {
        const int row = 64 + nt*16 + c;
        f16x8 w0f = *(const f16x8*)(wq + row*64 + 8*g);
        f16x8 w1f = *(const f16x8*)(wq + row*64 + 32 + 8*g);
        f32x4 d = {0.f,0.f,0.f,0.f};
        d = MFMA32(w0f, xf0, d); d = MFMA32(w1f, xf1, d);
        float4 b4 = *(const float4*)(Bq + 64 + nt*16 + 4*g);
        *(uint2*)swp(Kb, m0+c, 128, nt*32 + 8*g) =
            pack4u(d[0]+b4.x, d[1]+b4.y, d[2]+b4.z, d[3]+b4.w);
      }
      #pragma unroll
      for (int nt = 0; nt < 4; ++nt) {
        const int row = nt*16 + c;
        f16x8 w0f = *(const f16x8*)(wq + row*64 + 8*g);
        f16x8 w1f = *(const f16x8*)(wq + row*64 + 32 + 8*g);
        f32x4 d = {0.f,0.f,0.f,0.f};
        d = MFMA32(w0f, xf0, d); d = MFMA32(w1f, xf1, d);
        float4 b4 = *(const float4*)(Bq + nt*16 + 4*g);
        *(uint2*)swp(Qb, m0+c, 128, nt*32 + 8*g) =
            pack4u((d[0]+b4.x)*qs, (d[1]+b4.y)*qs, (d[2]+b4.z)*qs, (d[3]+b4.w)*qs);
      }
      #pragma unroll
      for (int nt = 0; nt < 4; ++nt) {
        const int row = 128 + nt*16 + c;
        f16x8 w0f = *(const f16x8*)(wq + row*64 + 8*g);
        f16x8 w1f = *(const f16x8*)(wq + row*64 + 32 + 8*g);
        f32x4 d = {0.f,0.f,0.f,0.f};
        d = MFMA32(xf0, w0f, d); d = MFMA32(xf1, w1f, d);
        const float bias = Bq[128 + nt*16 + c];
        *(uint2*)swp(Vt, nt*16+c, 512, 32*w + 8*g) =
            pack4u(d[0]+bias, d[1]+bias, d[2]+bias, d[3]+bias);
      }
    }
    __syncthreads();   // (a) Q/K/Vt visible to all

    // ======== attention (split even/odd accumulators) ========
    #pragma unroll 2
    for (int task = 0; task < 8; ++task) {
      const int h = task;
      f16x4 qb = {0,0,0,0};
      if (g < 2) qb = *(const f16x4*)swp(Qb, m0+c, 128, 16*h + 8*g);
      f32x4 oA = {0.f,0.f,0.f,0.f}, oB = {0.f,0.f,0.f,0.f};
      #pragma unroll
      for (int jt = 0; jt < 16; ++jt) {
        f16x4 ka = *(const f16x4*)swp(Kb, jt*16+c, 128, (16*h + 8*g) & 127);
        f32x4 st = {0.f,0.f,0.f,0.f};
        st = MFMA16(ka, qb, st);
        uint2 pu = pack4u(fast_exp2(st[0]), fast_exp2(st[1]),
                          fast_exp2(st[2]), fast_exp2(st[3]));
        f16x4 pb = *(f16x4*)&pu;
        f16x4 va;
        if (c < 8) va = *(const f16x4*)swp(Vt, 8*h+c, 512, jt*32 + (g>>1)*16 + (g&1)*8);
        else { va[0]=(_Float16)1.f; va[1]=(_Float16)1.f; va[2]=(_Float16)1.f; va[3]=(_Float16)1.f; }
        if (jt & 1) oB = MFMA16(va, pb, oB);
        else        oA = MFMA16(va, pb, oA);
      }
      f32x4 o;
      o[0] = oA[0]+oB[0]; o[1] = oA[1]+oB[1]; o[2] = oA[2]+oB[2]; o[3] = oA[3]+oB[3];
      const float den = __shfl(o[0], 32 + c, 64);
      const float rinv = 1.0f / den;
      if (g < 2) {
        *(uint2*)swp(Qb, m0+c, 128, 16*h + 8*g) =
            pack4u(o[0]*rinv, o[1]*rinv, o[2]*rinv, o[3]*rinv);
      }
    }
    __syncthreads();   // (b) cross-wave reads complete

    // ======== O-projection + residual + LN1 ========
    {
      f16x8 ab0 = *(const f16x8*)swp(Qb, m0+c, 128, 0  + g*16);
      f16x8 ab1 = *(const f16x8*)swp(Qb, m0+c, 128, 64 + g*16);
      float vals[4][4];
      #pragma unroll
      for (int nt = 0; nt < 4; ++nt) {
        f16x8 w0f = *(const f16x8*)(wo + (nt*16+c)*64 + 8*g);
        f16x8 w1f = *(const f16x8*)(wo + (nt*16+c)*64 + 32 + 8*g);
        f32x4 d = {0.f,0.f,0.f,0.f};
        d = MFMA32(w0f, ab0, d); d = MFMA32(w1f, ab1, d);
        float4 b4 = *(const float4*)(Bo + nt*16 + 4*g);
        uint2 rr = *(uint2*)swp(xs, m0+c, 128, nt*32 + 8*g);
        float2 r0 = __half22float2(*(__half2*)&rr.x);
        float2 r1 = __half22float2(*(__half2*)&rr.y);
        vals[nt][0] = d[0] + b4.x + r0.x;
        vals[nt][1] = d[1] + b4.y + r0.y;
        vals[nt][2] = d[2] + b4.z + r1.x;
        vals[nt][3] = d[3] + b4.w + r1.y;
      }
      float p1 = 0.f, p2 = 0.f;
      #pragma unroll
      for (int nt = 0; nt < 4; ++nt)
        #pragma unroll
        for (int i = 0; i < 4; ++i) { p1 += vals[nt][i]; p2 = fmaf(vals[nt][i], vals[nt][i], p2); }
      p1 += __shfl_xor(p1, 16, 64); p1 += __shfl_xor(p1, 32, 64);
      p2 += __shfl_xor(p2, 16, 64); p2 += __shfl_xor(p2, 32, 64);
      const float mean = p1*(1.0f/64.0f);
      const float rstd = rsqrtf(p2*(1.0f/64.0f) - mean*mean + 1e-5f);
      #pragma unroll
      for (int nt = 0; nt < 4; ++nt) {
        float4 g4 = *(const float4*)(G1 + nt*16 + 4*g);
        float4 b4 = *(const float4*)(B1 + nt*16 + 4*g);
        *(uint2*)swp(xs, m0+c, 128, nt*32 + 8*g) =
            pack4u((vals[nt][0]-mean)*rstd*g4.x + b4.x,
                   (vals[nt][1]-mean)*rstd*g4.y + b4.y,
                   (vals[nt][2]-mean)*rstd*g4.z + b4.z,
                   (vals[nt][3]-mean)*rstd*g4.w + b4.w);
      }
    }

    // ======== FF fused ========
    {
      f16x8 xb0 = *(const f16x8*)swp(xs, m0+c, 128, 0  + g*16);
      f16x8 xb1 = *(const f16x8*)swp(xs, m0+c, 128, 64 + g*16);
      f32x4 o2[4];
      #pragma unroll
      for (int nt2 = 0; nt2 < 4; ++nt2) { o2[nt2][0]=0.f; o2[nt2][1]=0.f; o2[nt2][2]=0.f; o2[nt2][3]=0.f; }
      #pragma unroll
      for (int ht = 0; ht < 16; ++ht) {
        f16x8 w0f = *(const f16x8*)(w1 + (ht*16+c)*64 + 8*g);
        f16x8 w1f = *(const f16x8*)(w1 + (ht*16+c)*64 + 32 + 8*g);
        f32x4 d = {0.f,0.f,0.f,0.f};
        d = MFMA32(w0f, xb0, d); d = MFMA32(w1f, xb1, d);
        float4 bf4 = *(const float4*)(Bf1 + ht*16 + 4*g);
        float h0 = d[0] + bf4.x, h1 = d[1] + bf4.y, h2 = d[2] + bf4.z, h3 = d[3] + bf4.w;
        h0 = 0.5f*h0*(1.0f + erff(h0*0.70710678118654752f));
        h1 = 0.5f*h1*(1.0f + erff(h1*0.70710678118654752f));
        h2 = 0.5f*h2*(1.0f + erff(h2*0.70710678118654752f));
        h3 = 0.5f*h3*(1.0f + erff(h3*0.70710678118654752f));
        uint2 pu = pack4u(h0, h1, h2, h3);
        f16x4 pf = *(f16x4*)&pu;
        #pragma unroll
        for (int nt2 = 0; nt2 < 4; ++nt2) {
          f16x4 a2 = *(const f16x4*)(w2 + (nt2*16+c)*256 + ht*16 + 4*g);
          o2[nt2] = MFMA16(a2, pf, o2[nt2]);
        }
      }
      float vals[4][4];
      #pragma unroll
      for (int nt2 = 0; nt2 < 4; ++nt2) {
        float4 b4 = *(const float4*)(Bf2 + nt2*16 + 4*g);
        uint2 rr = *(uint2*)swp(xs, m0+c, 128, nt2*32 + 8*g);
        float2 r0 = __half22float2(*(__half2*)&rr.x);
        float2 r1 = __half22float2(*(__half2*)&rr.y);
        vals[nt2][0] = o2[nt2][0] + b4.x + r0.x;
        vals[nt2][1] = o2[nt2][1] + b4.y + r0.y;
        vals[nt2][2] = o2[nt2][2] + b4.z + r1.x;
        vals[nt2][3] = o2[nt2][3] + b4.w + r1.y;
      }
      float p1 = 0.f, p2 = 0.f;
      #pragma unroll
      for (int nt2 = 0; nt2 < 4; ++nt2)
        #pragma unroll
        for (int i = 0; i < 4; ++i) { p1 += vals[nt2][i]; p2 = fmaf(vals[nt2][i], vals[nt2][i], p2); }
      p1 += __shfl_xor(p1, 16, 64); p1 += __shfl_xor(p1, 32, 64);
      p2 += __shfl_xor(p2, 16, 64); p2 += __shfl_xor(p2, 32, 64);
      const float mean = p1*(1.0f/64.0f);
      const float rstd = rsqrtf(p2*(1.0f/64.0f) - mean*mean + 1e-5f);
      #pragma unroll
      for (int nt2 = 0; nt2 < 4; ++nt2) {
        float4 g4 = *(const float4*)(G2 + nt2*16 + 4*g);
        float4 b4 = *(const float4*)(B2 + nt2*16 + 4*g);
        *(uint2*)swp(xs, m0+c, 128, nt2*32 + 8*g) =
            pack4u((vals[nt2][0]-mean)*rstd*g4.x + b4.x,
                   (vals[nt2][1]-mean)*rstd*g4.y + b4.y,
                   (vals[nt2][2]-mean)*rstd*g4.z + b4.z,
                   (vals[nt2][3]-mean)*rstd*g4.w + b4.w);
      }
    }
  }

  // ---- mean over sequence -> nf ----
  __syncthreads();
  if (t < 256) {
    const int d = t & 63, qu = t >> 6;
    float sm = 0.f;
    for (int rr = qu*64; rr < qu*64 + 64; ++rr) sm += sr_h(xs, rr, 128, d);
    red[qu*64 + d] = sm;
  }
  __syncthreads();
  if (t < 64) {
    float sm = red[t] + red[64+t] + red[128+t] + red[192+t];
    nf[((size_t)b*4 + s)*64 + t] = sm * (1.0f/256.0f);
  }
}

// ------------------------- graph head kernel (unchanged) -------------------------
__global__ __launch_bounds__(128) void head_kernel(
  const float* __restrict__ nf,
  const float* __restrict__ ws_w, const float* __restrict__ ws_b,
  const float* __restrict__ b_s,  const float* __restrict__ lambda_init,
  const float* __restrict__ mc_w1, const float* __restrict__ mc_b1,
  const float* __restrict__ mc_w2, const float* __restrict__ mc_b2,
  const float* __restrict__ g1w, const float* __restrict__ g1b,
  const float* __restrict__ g2w, const float* __restrict__ g2b,
  const float* __restrict__ cw1, const float* __restrict__ cb1,
  const float* __restrict__ cw2, const float* __restrict__ cb2,
  float* __restrict__ out)
{
  const int b = blockIdx.x, t = threadIdx.x;
  __shared__ float nfb[256];
  __shared__ float meannf[64];
  __shared__ float fafb[8];
  __shared__ float z1[32];
  __shared__ float normM[16];
  __shared__ float rs[4];
  __shared__ float xw[512];
  __shared__ float hmat[512];
  __shared__ float hw[1024];
  __shared__ float gv[256];
  __shared__ float r1[128];

  for (int i = t; i < 256; i += 128) nfb[i] = nf[b*256 + i];
  __syncthreads();
  if (t < 8) {
    const int i = t & 3;
    const float* w = ws_w + (t >> 2)*64;
    float acc = 0.f;
    for (int c = 0; c < 64; ++c) acc = fmaf(nfb[i*64+c], w[c], acc);
    fafb[t] = acc;
  }
  if (t >= 64 && t < 128) {
    const int d = t - 64;
    meannf[d] = 0.25f*(nfb[d] + nfb[64+d] + nfb[128+d] + nfb[192+d]);
  }
  __syncthreads();
  if (t < 32) {
    float acc = mc_b1[t];
    const float* w = mc_w1 + t*64;
    for (int c = 0; c < 64; ++c) acc = fmaf(meannf[c], w[c], acc);
    z1[t] = fmaxf(acc, 0.f);
  }
  __syncthreads();
  if (t == 0) {
    float li = mc_b2[0];
    for (int k = 0; k < 32; ++k) li = fmaf(z1[k], mc_w2[k], li);
    const float lam = (1.0f/(1.0f + __expf(-li))) * lambda_init[0];
    const float AB[4][4] = {{1,1,0,0},{1,1,1,1},{0,1,1,1},{0,1,1,1}};
    const float add = ws_b[0] + b_s[0];
    float sM[4][4], deg[4];
    for (int i = 0; i < 4; ++i) {
      float d_ = 0.f;
      for (int j = 0; j < 4; ++j) {
        sM[i][j] = 1.0f/(1.0f + __expf(-(fafb[i] + fafb[4+j] + add)));
        d_ += sM[i][j];
      }
      deg[i] = d_;
    }
    float A[4][4], dinv[4];
    for (int i = 0; i < 4; ++i)
      for (int j = 0; j < 4; ++j) {
        const float a_ = sM[i][j] / (deg[j] + 1e-8f);
        const float sh = fmaxf(a_ * AB[i][j], 0.f);
        A[i][j] = lam*((i==j) ? 1.f : 0.f) + (1.0f - lam)*sh;
      }
    for (int j = 0; j < 4; ++j) {
      float d_ = 0.f;
      for (int i = 0; i < 4; ++i) d_ += A[i][j];
      dinv[j] = (d_ > 0.f) ? rsqrtf(d_) : 0.f;
    }
    for (int i = 0; i < 4; ++i) {
      float r_ = 0.f;
      for (int j = 0; j < 4; ++j) {
        const float n_ = dinv[i]*A[i][j]*dinv[j];
        normM[i*4+j] = n_;
        r_ += n_;
      }
      rs[i] = r_;
    }
  }
  __syncthreads();
  for (int idx = t; idx < 512; idx += 128) {
    const int i = idx >> 7, f = idx & 127;
    float acc = 0.f;
    for (int c = 0; c < 64; ++c) acc = fmaf(nfb[i*64+c], g1w[c*128 + f], acc);
    xw[idx] = acc;
  }
  __syncthreads();
  for (int idx = t; idx < 512; idx += 128) {
    const int j = idx >> 7, f = idx & 127;
    float acc = g1b[f];
    #pragma unroll
    for (int i = 0; i < 4; ++i) acc = fmaf(normM[i*4+j], xw[i*128+f], acc);
    hmat[j*128+f] = fmaxf(acc, 0.f);
  }
  __syncthreads();
  for (int idx = t; idx < 1024; idx += 128) {
    const int i = idx >> 8, f = idx & 255;
    float acc = 0.f;
    for (int c = 0; c < 128; ++c) acc = fmaf(hmat[i*128+c], g2w[c*256+f], acc);
    hw[idx] = acc;
  }
  __syncthreads();
  for (int f = t; f < 256; f += 128) {
    float acc = 0.f;
    #pragma unroll
    for (int i = 0; i < 4; ++i) acc = fmaf(rs[i], hw[i*256+f], acc);
    gv[f] = 0.25f*acc + g2b[f];
  }
  __syncthreads();
  if (t < 128) {
    float acc = cb1[t];
    for (int c = 0; c < 256; ++c) acc = fmaf(gv[c], cw1[c*128+t], acc);
    r1[t] = fmaxf(acc, 0.f);
  }
  __syncthreads();
  if (t < 5) {
    float acc = cb2[t];
    for (int k = 0; k < 128; ++k) acc = fmaf(r1[k], cw2[k*5 + t], acc);
    out[b*5 + t] = acc;
  }
}

// ------------------------- launch -------------------------
extern "C" void kernel_launch(void* const* d_in, const int* in_sizes, int n_in,
                              void* d_out, int out_size, void* d_ws, size_t ws_size,
                              hipStream_t stream) {
  (void)in_sizes; (void)n_in; (void)out_size; (void)ws_size;
  const float* sens   = (const float*)d_in[0];
  const float* c1w    = (const float*)d_in[1];
  const float* c1b    = (const float*)d_in[2];
  const float* bn1g   = (const float*)d_in[3];
  const float* bn1b   = (const float*)d_in[4];
  const float* c2w    = (const float*)d_in[5];
  const float* c2b    = (const float*)d_in[6];
  const float* bn2g   = (const float*)d_in[7];
  const float* bn2b   = (const float*)d_in[8];
  const float* wqkv   = (const float*)d_in[9];
  const float* bqkv   = (const float*)d_in[10];
  const float* wo     = (const float*)d_in[11];
  const float* bo     = (const float*)d_in[12];
  const float* ln1g   = (const float*)d_in[13];
  const float* ln1b   = (const float*)d_in[14];
  const float* fw1    = (const float*)d_in[15];
  const float* fb1    = (const float*)d_in[16];
  const float* fw2    = (const float*)d_in[17];
  const float* fb2    = (const float*)d_in[18];
  const float* ln2g   = (const float*)d_in[19];
  const float* ln2b   = (const float*)d_in[20];
  const float* ws_w   = (const float*)d_in[21];
  const float* ws_b   = (const float*)d_in[22];
  const float* b_s    = (const float*)d_in[23];
  const float* lam0   = (const float*)d_in[24];
  const float* mc_w1  = (const float*)d_in[25];
  const float* mc_b1  = (const float*)d_in[26];
  const float* mc_w2  = (const float*)d_in[27];
  const float* mc_b2  = (const float*)d_in[28];
  const float* g1w    = (const float*)d_in[29];
  const float* g1b    = (const float*)d_in[30];
  const float* g2w    = (const float*)d_in[31];
  const float* g2b    = (const float*)d_in[32];
  const float* cw1    = (const float*)d_in[33];
  const float* cb1    = (const float*)d_in[34];
  const float* cw2    = (const float*)d_in[35];
  const float* cb2    = (const float*)d_in[36];

  float*          nf  = (float*)d_ws;                                  // 64 KiB
  unsigned short* w16 = (unsigned short*)((char*)d_ws + 65536);        // 768 KiB

  wprep_kernel<<<8, 256, 0, stream>>>(wqkv, wo, fw1, fw2, w16);
  tx_kernel<<<NSENS*NB, 1024, 0, stream>>>(sens, c1w, c1b, bn1g, bn1b,
                                           c2w, c2b, bn2g, bn2b,
                                           nf, w16, bqkv, bo,
                                           ln1g, ln1b, fb1, fb2, ln2g, ln2b);
  head_kernel<<<NB, 128, 0, stream>>>(nf, ws_w, ws_b, b_s, lam0,
                                      mc_w1, mc_b1, mc_w2, mc_b2,
                                      g1w, g1b, g2w, g2b, cw1, cb1, cw2, cb2,
                                      (float*)d_out);
}